// Round 1
// baseline (5803.050 us; speedup 1.0000x reference)
//
#include <hip/hip_runtime.h>
#include <hip/hip_bf16.h>
#include <math.h>

#define BATCH 4
#define XL 128
#define YL 1024
#define DMODEL 512
#define NH 8
#define NLAYER 3
#define DFF 2048
#define MASK_ID 1024
#define EOS_TOK 1024
#define HD 64
#define SEQ 1153          // XL + 1 + YL
#define OV 1025
#define NEGBIG (-1e9f)

// ---------------- sinusoid helper ----------------
__device__ __forceinline__ float pe_val(int pos, int d) {
    int i2 = d & ~1;
    float dv = expf((float)i2 * (-9.210340371976184f / (float)DMODEL)); // -ln(10000)/D
    float ang = (float)pos * dv;
    return (d & 1) ? cosf(ang) : sinf(ang);
}

// ---------------- build h_input [B,S,D] ----------------
__global__ __launch_bounds__(256) void build_h_kernel(
    const int* __restrict__ x, const int* __restrict__ y, const int* __restrict__ y_mask,
    const float* __restrict__ emo_feature, const float* __restrict__ text_emb,
    const float* __restrict__ audio_emb, const float* __restrict__ type_emb,
    const float* __restrict__ emo_W, const float* __restrict__ emo_b,
    const float* __restrict__ alpha_text, const float* __restrict__ alpha_audio,
    float* __restrict__ hbuf)
{
    int bs = blockIdx.x;
    int b = bs / SEQ, s = bs % SEQ;
    float* out = hbuf + (size_t)bs * DMODEL;
    if (s == XL) {
        // emo row: emo_feature @ emo_W.T + emo_b + type_emb[1]
        const float* f = emo_feature + b * 768;
        for (int d = threadIdx.x; d < DMODEL; d += 256) {
            const float* w = emo_W + (size_t)d * 768;
            float acc = 0.f;
            for (int k = 0; k < 768; ++k) acc = fmaf(f[k], w[k], acc);
            out[d] = acc + emo_b[d] + type_emb[DMODEL + d];
        }
    } else if (s < XL) {
        int tok = x[b * XL + s];
        float at = alpha_text[0];
        for (int d = threadIdx.x; d < DMODEL; d += 256) {
            out[d] = text_emb[(size_t)tok * DMODEL + d] + type_emb[d] + at * pe_val(s, d);
        }
    } else {
        int r = s - XL - 1;
        int tok = y_mask[b * YL + r] ? MASK_ID : y[b * YL + r];
        float aa = alpha_audio[0];
        for (int d = threadIdx.x; d < DMODEL; d += 256) {
            out[d] = audio_emb[(size_t)tok * DMODEL + d] + type_emb[2 * DMODEL + d] + aa * pe_val(r, d);
        }
    }
}

// ---------------- f32 NT GEMM: C[m][n] = sum_k A[m][k]*B[n][k] + bias[n] ----------------
#define BM 64
#define BN 64
#define BK 16

__global__ __launch_bounds__(256) void gemm_nt_kernel(
    const float* __restrict__ A, const float* __restrict__ Bw,
    const float* __restrict__ bias, float* __restrict__ C,
    int M, int N, int K, int relu)
{
    __shared__ float As[BK][BM + 1];
    __shared__ float Bs[BK][BN + 1];
    int tid = threadIdx.x;
    int m0 = blockIdx.y * BM, n0 = blockIdx.x * BN;
    int lr = tid >> 2;          // 0..63 tile row for loads
    int lc = (tid & 3) << 2;    // 0,4,8,12 k-col for loads
    int tm = (tid & 15) << 2;   // 0..60 output row base
    int tn = (tid >> 4) << 2;   // 0..60 output col base
    float acc[4][4];
    #pragma unroll
    for (int i = 0; i < 4; ++i)
        #pragma unroll
        for (int j = 0; j < 4; ++j) acc[i][j] = 0.f;

    for (int k0 = 0; k0 < K; k0 += BK) {
        float4 av = make_float4(0.f, 0.f, 0.f, 0.f);
        float4 bv = make_float4(0.f, 0.f, 0.f, 0.f);
        int am = m0 + lr;
        if (am < M) av = *(const float4*)(A + (size_t)am * K + (k0 + lc));
        int bn = n0 + lr;
        if (bn < N) bv = *(const float4*)(Bw + (size_t)bn * K + (k0 + lc));
        __syncthreads();
        As[lc + 0][lr] = av.x; As[lc + 1][lr] = av.y; As[lc + 2][lr] = av.z; As[lc + 3][lr] = av.w;
        Bs[lc + 0][lr] = bv.x; Bs[lc + 1][lr] = bv.y; Bs[lc + 2][lr] = bv.z; Bs[lc + 3][lr] = bv.w;
        __syncthreads();
        #pragma unroll
        for (int kk = 0; kk < BK; ++kk) {
            float a0 = As[kk][tm + 0], a1 = As[kk][tm + 1], a2 = As[kk][tm + 2], a3 = As[kk][tm + 3];
            float b0 = Bs[kk][tn + 0], b1 = Bs[kk][tn + 1], b2 = Bs[kk][tn + 2], b3 = Bs[kk][tn + 3];
            acc[0][0] = fmaf(a0, b0, acc[0][0]); acc[0][1] = fmaf(a0, b1, acc[0][1]);
            acc[0][2] = fmaf(a0, b2, acc[0][2]); acc[0][3] = fmaf(a0, b3, acc[0][3]);
            acc[1][0] = fmaf(a1, b0, acc[1][0]); acc[1][1] = fmaf(a1, b1, acc[1][1]);
            acc[1][2] = fmaf(a1, b2, acc[1][2]); acc[1][3] = fmaf(a1, b3, acc[1][3]);
            acc[2][0] = fmaf(a2, b0, acc[2][0]); acc[2][1] = fmaf(a2, b1, acc[2][1]);
            acc[2][2] = fmaf(a2, b2, acc[2][2]); acc[2][3] = fmaf(a2, b3, acc[2][3]);
            acc[3][0] = fmaf(a3, b0, acc[3][0]); acc[3][1] = fmaf(a3, b1, acc[3][1]);
            acc[3][2] = fmaf(a3, b2, acc[3][2]); acc[3][3] = fmaf(a3, b3, acc[3][3]);
        }
    }
    #pragma unroll
    for (int i = 0; i < 4; ++i) {
        int m = m0 + tm + i;
        if (m >= M) continue;
        #pragma unroll
        for (int j = 0; j < 4; ++j) {
            int n = n0 + tn + j;
            if (n >= N) continue;
            float v = acc[i][j];
            if (bias) v += bias[n];
            if (relu) v = fmaxf(v, 0.f);
            C[(size_t)m * N + n] = v;
        }
    }
}

// ---------------- masked flash attention (f32) ----------------
// qkv layout [B,S,3*D]; q col = h*64+d, k col = 512+h*64+d, v col = 1024+h*64+d
// grid: (ceil(S/16), B*H), block 256 (4 waves, wave w owns q rows 4w..4w+3 of the tile)
__global__ __launch_bounds__(256) void attn_kernel(
    const float* __restrict__ qkv,
    const int* __restrict__ x1_lens, const int* __restrict__ x2_lens,
    const int* __restrict__ y1_lens, const int* __restrict__ y2_lens,
    const int* __restrict__ y_mask,
    float* __restrict__ obuf)
{
    __shared__ float Qs[16][HD];
    __shared__ float Ks[64][HD + 1];
    __shared__ float Vs[64][HD + 1];
    __shared__ float Ps[16][HD];

    int bh = blockIdx.y;
    int b = bh >> 3, h = bh & 7;
    int q0 = blockIdx.x * 16;
    int tid = threadIdx.x;
    int tx = tid & 63, ty = tid >> 6;

    int x1 = x1_lens[b];
    int xlen = x1 + 1 + x2_lens[b];
    int y1 = y1_lens[b];
    int ylen = y1 + 1 + y2_lens[b];

    // load Q tile
    for (int idx = tid; idx < 16 * HD; idx += 256) {
        int r = idx >> 6, d = idx & 63;
        int qr = q0 + r;
        Qs[r][d] = (qr < SEQ) ? qkv[(size_t)(b * SEQ + qr) * (3 * DMODEL) + h * HD + d] : 0.f;
    }

    // row types: 0=x1 1=x2/xpad 2=emo 3=y1 4=cls 5=y2 6=blocked
    int rt[4];
    #pragma unroll
    for (int j = 0; j < 4; ++j) {
        int qr = q0 + ty * 4 + j;
        int t;
        if (qr >= SEQ) t = 6;
        else if (qr < XL) t = (qr < x1) ? 0 : 1;
        else if (qr == XL) t = 2;
        else {
            int ry = qr - XL - 1;
            t = (ry < y1) ? 3 : (ry == y1) ? 4 : (ry < ylen) ? 5 : 6;
        }
        rt[j] = t;
    }

    float oacc[4] = {0.f, 0.f, 0.f, 0.f};
    float mrun[4] = {-INFINITY, -INFINITY, -INFINITY, -INFINITY};
    float lrun[4] = {0.f, 0.f, 0.f, 0.f};
    const float scale = 0.125f;   // 1/sqrt(64)

    const int NT = (SEQ + 63) / 64;   // 19
    for (int kt = 0; kt < NT; ++kt) {
        __syncthreads();
        for (int idx = tid; idx < 64 * HD; idx += 256) {
            int r = idx >> 6, d = idx & 63;
            int kr = kt * 64 + r;
            if (kr < SEQ) {
                size_t base = (size_t)(b * SEQ + kr) * (3 * DMODEL) + h * HD + d;
                Ks[r][d] = qkv[base + DMODEL];
                Vs[r][d] = qkv[base + 2 * DMODEL];
            } else {
                Ks[r][d] = 0.f;
                Vs[r][d] = 0.f;
            }
        }
        __syncthreads();

        int col = kt * 64 + tx;
        bool cvalid = col < SEQ;
        bool ym_c = false;
        if (cvalid && col > XL) ym_c = (y_mask[b * YL + (col - XL - 1)] != 0);
        bool a2c = (col == XL);
        bool ygt = (col > XL);
        bool aT0 = (col < x1);
        bool aT1 = (col >= x1) && (col < xlen);
        bool aT3 = aT0 || (ygt && col <= XL + y1);
        bool aT4 = (col < xlen) || a2c || (ygt && col <= XL + y1 + 1);
        bool aT5 = ((col < xlen) || a2c || (ygt && col <= XL + ylen)) && !ym_c;

        #pragma unroll
        for (int j = 0; j < 4; ++j) {
            int qlr = ty * 4 + j;
            float s = 0.f;
            for (int d = 0; d < HD; ++d)
                s = fmaf(Qs[qlr][d], Ks[tx][d], s);
            int rtj = rt[j];
            bool allow = (rtj == 0) ? aT0 :
                         (rtj == 1) ? aT1 :
                         (rtj == 2) ? a2c :
                         (rtj == 3) ? aT3 :
                         (rtj == 4) ? aT4 :
                         (rtj == 5) ? aT5 : false;
            float sc;
            if (!cvalid) sc = -INFINITY;
            else {
                sc = s * scale;
                if (!allow) sc += NEGBIG;   // matches reference's +(-1e9) absorption exactly
            }
            float tmax = sc;
            #pragma unroll
            for (int off = 32; off > 0; off >>= 1)
                tmax = fmaxf(tmax, __shfl_xor(tmax, off));
            float newm = fmaxf(mrun[j], tmax);
            float p = expf(sc - newm);      // -inf -> 0
            float tsum = p;
            #pragma unroll
            for (int off = 32; off > 0; off >>= 1)
                tsum += __shfl_xor(tsum, off);
            float corr = expf(mrun[j] - newm);
            lrun[j] = lrun[j] * corr + tsum;
            mrun[j] = newm;
            oacc[j] *= corr;
            Ps[qlr][tx] = p;                // wave-local rows; no cross-wave barrier needed
        }
        for (int k = 0; k < 64; ++k) {
            float vv = Vs[k][tx];
            #pragma unroll
            for (int j = 0; j < 4; ++j)
                oacc[j] = fmaf(Ps[ty * 4 + j][k], vv, oacc[j]);
        }
    }

    #pragma unroll
    for (int j = 0; j < 4; ++j) {
        int qr = q0 + ty * 4 + j;
        if (qr < SEQ)
            obuf[(size_t)(b * SEQ + qr) * DMODEL + h * HD + tx] = oacc[j] / lrun[j];
    }
}

// ---------------- residual add + LayerNorm (in place on hbuf) ----------------
__global__ __launch_bounds__(256) void add_ln_kernel(
    float* __restrict__ hbuf, const float* __restrict__ delta,
    const float* __restrict__ g, const float* __restrict__ beta)
{
    __shared__ float red[4];
    int row = blockIdx.x, t = threadIdx.x;
    float* hp = hbuf + (size_t)row * DMODEL;
    const float* dp = delta + (size_t)row * DMODEL;
    float v0 = hp[t] + dp[t];
    float v1 = hp[t + 256] + dp[t + 256];
    float s = v0 + v1;
    #pragma unroll
    for (int off = 32; off > 0; off >>= 1) s += __shfl_xor(s, off);
    if ((t & 63) == 0) red[t >> 6] = s;
    __syncthreads();
    float mu = (red[0] + red[1] + red[2] + red[3]) * (1.f / DMODEL);
    float d0 = v0 - mu, d1 = v1 - mu;
    float sq = d0 * d0 + d1 * d1;
    __syncthreads();
    #pragma unroll
    for (int off = 32; off > 0; off >>= 1) sq += __shfl_xor(sq, off);
    if ((t & 63) == 0) red[t >> 6] = sq;
    __syncthreads();
    float var = (red[0] + red[1] + red[2] + red[3]) * (1.f / DMODEL);
    float inv = 1.f / sqrtf(var + 1e-5f);
    hp[t] = d0 * inv * g[t] + beta[t];
    hp[t + 256] = d1 * inv * g[t + 256] + beta[t + 256];
}

// ---------------- CE + top-3 over masked positions ----------------
__global__ __launch_bounds__(256) void ce_kernel(
    const float* __restrict__ logits, const int* __restrict__ y,
    const int* __restrict__ y_mask, float* __restrict__ accum)
{
    int row = blockIdx.x;           // 0..4095
    int b = row >> 10, r = row & 1023;
    int msk = y_mask[b * YL + r];
    if (!msk) return;               // uniform across block
    const float* lp = logits + (size_t)row * OV;
    int tgt = y[b * YL + r];
    int t = threadIdx.x;
    __shared__ float red[4];

    float lmax = -INFINITY;
    for (int i = t; i < OV; i += 256) lmax = fmaxf(lmax, lp[i]);
    #pragma unroll
    for (int off = 32; off > 0; off >>= 1) lmax = fmaxf(lmax, __shfl_xor(lmax, off));
    if ((t & 63) == 0) red[t >> 6] = lmax;
    __syncthreads();
    lmax = fmaxf(fmaxf(red[0], red[1]), fmaxf(red[2], red[3]));
    __syncthreads();

    float lsum = 0.f;
    for (int i = t; i < OV; i += 256) lsum += expf(lp[i] - lmax);
    #pragma unroll
    for (int off = 32; off > 0; off >>= 1) lsum += __shfl_xor(lsum, off);
    if ((t & 63) == 0) red[t >> 6] = lsum;
    __syncthreads();
    lsum = red[0] + red[1] + red[2] + red[3];
    __syncthreads();

    float lt = lp[tgt];
    float cnt = 0.f;
    for (int i = t; i < OV; i += 256) {
        float v = lp[i];
        if (v > lt || (v == lt && i < tgt)) cnt += 1.f;
    }
    #pragma unroll
    for (int off = 32; off > 0; off >>= 1) cnt += __shfl_xor(cnt, off);
    if ((t & 63) == 0) red[t >> 6] = cnt;
    __syncthreads();
    cnt = red[0] + red[1] + red[2] + red[3];

    if (t == 0) {
        float ce = -(lt - lmax - logf(lsum));
        float inc = (tgt != EOS_TOK) ? 1.f : 0.f;
        float corr = (cnt < 2.5f) ? 1.f : 0.f;   // rank < 3 -> in top-3
        atomicAdd(&accum[0], ce);
        atomicAdd(&accum[1], 1.f);
        atomicAdd(&accum[2], corr * inc);
        atomicAdd(&accum[3], inc);
    }
}

__global__ void init_accum_kernel(float* accum) {
    if (threadIdx.x < 8) accum[threadIdx.x] = 0.f;
}

// ---------------- duration head + final outputs ----------------
__global__ __launch_bounds__(256) void finalize_kernel(
    const float* __restrict__ hbuf,
    const int* __restrict__ y1_lens, const int* __restrict__ y2_lens,
    const int* __restrict__ x2_lens,
    const float* __restrict__ dW1, const float* __restrict__ db1,
    const float* __restrict__ dW2, const float* __restrict__ db2,
    const float* __restrict__ dW3, const float* __restrict__ db3,
    const float* __restrict__ accum, float* __restrict__ out)
{
    __shared__ float h1[256];
    __shared__ float h2[128];
    __shared__ float preds[BATCH];
    int t = threadIdx.x;
    for (int b = 0; b < BATCH; ++b) {
        const float* cls = hbuf + (size_t)(b * SEQ + XL + 1 + y1_lens[b]) * DMODEL;
        {
            float acc = db1[t];
            const float* w = dW1 + (size_t)t * DMODEL;
            for (int k = 0; k < DMODEL; ++k) acc = fmaf(cls[k], w[k], acc);
            h1[t] = fmaxf(acc, 0.f);
        }
        __syncthreads();
        if (t < 128) {
            float acc = db2[t];
            const float* w = dW2 + (size_t)t * 256;
            for (int k = 0; k < 256; ++k) acc = fmaf(h1[k], w[k], acc);
            h2[t] = fmaxf(acc, 0.f);
        }
        __syncthreads();
        if (t == 0) {
            float acc = db3[0];
            for (int k = 0; k < 128; ++k) acc = fmaf(h2[k], dW3[k], acc);
            preds[b] = acc;
        }
        __syncthreads();
    }
    if (t == 0) {
        float dl = 0.f;
        for (int b = 0; b < BATCH; ++b) {
            float tgt = (float)y2_lens[b] / (float)x2_lens[b];
            float e = preds[b] - tgt;
            float ae = fabsf(e);
            dl += (ae <= 1.f) ? 0.5f * e * e : (ae - 0.5f);
        }
        dl *= (1.f / BATCH);
        float token_loss = accum[0] / accum[1];
        float acc_v = accum[2] / fmaxf(accum[3], 1.f);
        out[0] = token_loss + dl;
        out[1] = acc_v;
    }
}

// ---------------- orchestration ----------------
extern "C" void kernel_launch(void* const* d_in, const int* in_sizes, int n_in,
                              void* d_out, int out_size, void* d_ws, size_t ws_size,
                              hipStream_t stream)
{
    const int*   x           = (const int*)d_in[0];
    const int*   x1_lens     = (const int*)d_in[1];
    const int*   x2_lens     = (const int*)d_in[2];
    const int*   y           = (const int*)d_in[3];
    const int*   y1_lens     = (const int*)d_in[4];
    const int*   y2_lens     = (const int*)d_in[5];
    const int*   y_mask      = (const int*)d_in[6];
    const float* emo_feature = (const float*)d_in[7];
    const float* text_emb    = (const float*)d_in[8];
    const float* audio_emb   = (const float*)d_in[9];
    const float* type_emb    = (const float*)d_in[10];
    const float* emo_W       = (const float*)d_in[11];
    const float* emo_b       = (const float*)d_in[12];
    const float* alpha_text  = (const float*)d_in[13];
    const float* alpha_audio = (const float*)d_in[14];
    const float* Wqkv        = (const float*)d_in[15];
    const float* bqkv        = (const float*)d_in[16];
    const float* Wo          = (const float*)d_in[17];
    const float* bo          = (const float*)d_in[18];
    const float* ln1_g       = (const float*)d_in[19];
    const float* ln1_b       = (const float*)d_in[20];
    const float* ln2_g       = (const float*)d_in[21];
    const float* ln2_b       = (const float*)d_in[22];
    const float* W1          = (const float*)d_in[23];
    const float* b1          = (const float*)d_in[24];
    const float* W2          = (const float*)d_in[25];
    const float* b2          = (const float*)d_in[26];
    const float* predict_W   = (const float*)d_in[27];
    const float* dW1         = (const float*)d_in[28];
    const float* db1         = (const float*)d_in[29];
    const float* dW2         = (const float*)d_in[30];
    const float* db2         = (const float*)d_in[31];
    const float* dW3         = (const float*)d_in[32];
    const float* db3         = (const float*)d_in[33];

    float* ws = (float*)d_ws;
    const size_t ROWS = (size_t)BATCH * SEQ;        // 4612
    float* hbuf   = ws;                             // ROWS*512
    float* qkvbuf = hbuf + ROWS * DMODEL;           // ROWS*1536
    float* obuf   = qkvbuf + ROWS * 3 * DMODEL;     // ROWS*512
    float* delta  = obuf + ROWS * DMODEL;           // ROWS*512
    float* ff1    = delta + ROWS * DMODEL;          // ROWS*2048
    float* logits = ff1;                            // 4096*1025, alias: ff1 dead by then
    float* accum  = delta;                          // 8 floats, alias: delta dead by then

    build_h_kernel<<<BATCH * SEQ, 256, 0, stream>>>(
        x, y, y_mask, emo_feature, text_emb, audio_emb, type_emb,
        emo_W, emo_b, alpha_text, alpha_audio, hbuf);

    const int M = BATCH * SEQ;
    const int MG = (M + BM - 1) / BM;   // 73
    for (int l = 0; l < NLAYER; ++l) {
        gemm_nt_kernel<<<dim3((3 * DMODEL) / BN, MG), 256, 0, stream>>>(
            hbuf, Wqkv + (size_t)l * 3 * DMODEL * DMODEL, bqkv + l * 3 * DMODEL,
            qkvbuf, M, 3 * DMODEL, DMODEL, 0);
        attn_kernel<<<dim3((SEQ + 15) / 16, BATCH * NH), 256, 0, stream>>>(
            qkvbuf, x1_lens, x2_lens, y1_lens, y2_lens, y_mask, obuf);
        gemm_nt_kernel<<<dim3(DMODEL / BN, MG), 256, 0, stream>>>(
            obuf, Wo + (size_t)l * DMODEL * DMODEL, bo + l * DMODEL,
            delta, M, DMODEL, DMODEL, 0);
        add_ln_kernel<<<M, 256, 0, stream>>>(hbuf, delta, ln1_g + l * DMODEL, ln1_b + l * DMODEL);
        gemm_nt_kernel<<<dim3(DFF / BN, MG), 256, 0, stream>>>(
            hbuf, W1 + (size_t)l * DFF * DMODEL, b1 + l * DFF, ff1, M, DFF, DMODEL, 1);
        gemm_nt_kernel<<<dim3(DMODEL / BN, MG), 256, 0, stream>>>(
            ff1, W2 + (size_t)l * DMODEL * DFF, b2 + l * DMODEL, delta, M, DMODEL, DFF, 0);
        add_ln_kernel<<<M, 256, 0, stream>>>(hbuf, delta, ln2_g + l * DMODEL, ln2_b + l * DMODEL);
    }

    // logits for the y region: enc[:, XL+1:] @ predict_W.T  (per batch, rows contiguous)
    for (int b = 0; b < BATCH; ++b) {
        gemm_nt_kernel<<<dim3((OV + BN - 1) / BN, YL / BM), 256, 0, stream>>>(
            hbuf + (size_t)(b * SEQ + XL + 1) * DMODEL, predict_W, nullptr,
            logits + (size_t)b * YL * OV, YL, OV, DMODEL, 0);
    }
    init_accum_kernel<<<1, 64, 0, stream>>>(accum);
    ce_kernel<<<BATCH * YL, 256, 0, stream>>>(logits, y, y_mask, accum);
    finalize_kernel<<<1, 256, 0, stream>>>(hbuf, y1_lens, y2_lens, x2_lens,
        dW1, db1, dW2, db2, dW3, db3, accum, (float*)d_out);
}

// Round 2
// 940.635 us; speedup vs baseline: 6.1693x; 6.1693x over previous
//
#include <hip/hip_runtime.h>
#include <hip/hip_bf16.h>
#include <math.h>

#define BATCH 4
#define XL 128
#define YL 1024
#define DMODEL 512
#define NH 8
#define NLAYER 3
#define DFF 2048
#define MASK_ID 1024
#define EOS_TOK 1024
#define HD 64
#define SEQ 1153          // XL + 1 + YL
#define OV 1025
#define NEGBIG (-1e9f)

typedef unsigned short u16;
typedef short short8 __attribute__((ext_vector_type(8)));
typedef float f32x4 __attribute__((ext_vector_type(4)));

__device__ __forceinline__ u16 f2bf(float f) {
    union { float f; unsigned u; } v; v.f = f;
    unsigned r = v.u + 0x7fffu + ((v.u >> 16) & 1u);   // RNE
    return (u16)(r >> 16);
}
__device__ __forceinline__ float bf2f(u16 b) {
    union { unsigned u; float f; } v; v.u = ((unsigned)b) << 16;
    return v.f;
}

// ---------------- f32 -> bf16 convert (weights & misc), 4 elems/thread ----------------
__global__ __launch_bounds__(256) void cvt_kernel(const float* __restrict__ s,
                                                  u16* __restrict__ d, int n4) {
    for (int i = blockIdx.x * 256 + threadIdx.x; i < n4; i += gridDim.x * 256) {
        float4 v = ((const float4*)s)[i];
        ushort4 o;
        o.x = f2bf(v.x); o.y = f2bf(v.y); o.z = f2bf(v.z); o.w = f2bf(v.w);
        ((ushort4*)d)[i] = o;
    }
}

// ---------------- sinusoid helper ----------------
__device__ __forceinline__ float pe_val(int pos, int d) {
    int i2 = d & ~1;
    float dv = expf((float)i2 * (-9.210340371976184f / (float)DMODEL));
    float ang = (float)pos * dv;
    return (d & 1) ? cosf(ang) : sinf(ang);
}

// ---------------- build h_input [B,S,D] (f32 + bf16 shadow) ----------------
__global__ __launch_bounds__(256) void build_h_kernel(
    const int* __restrict__ x, const int* __restrict__ y, const int* __restrict__ y_mask,
    const float* __restrict__ emo_feature, const float* __restrict__ text_emb,
    const float* __restrict__ audio_emb, const float* __restrict__ type_emb,
    const float* __restrict__ emo_W, const float* __restrict__ emo_b,
    const float* __restrict__ alpha_text, const float* __restrict__ alpha_audio,
    float* __restrict__ hbuf, u16* __restrict__ hbuf_bf)
{
    int bs = blockIdx.x;
    int b = bs / SEQ, s = bs % SEQ;
    float* out = hbuf + (size_t)bs * DMODEL;
    u16* outb = hbuf_bf + (size_t)bs * DMODEL;
    if (s == XL) {
        const float* f = emo_feature + b * 768;
        for (int d = threadIdx.x; d < DMODEL; d += 256) {
            const float* w = emo_W + (size_t)d * 768;
            float acc = 0.f;
            for (int k = 0; k < 768; ++k) acc = fmaf(f[k], w[k], acc);
            float v = acc + emo_b[d] + type_emb[DMODEL + d];
            out[d] = v; outb[d] = f2bf(v);
        }
    } else if (s < XL) {
        int tok = x[b * XL + s];
        float at = alpha_text[0];
        for (int d = threadIdx.x; d < DMODEL; d += 256) {
            float v = text_emb[(size_t)tok * DMODEL + d] + type_emb[d] + at * pe_val(s, d);
            out[d] = v; outb[d] = f2bf(v);
        }
    } else {
        int r = s - XL - 1;
        int tok = y_mask[b * YL + r] ? MASK_ID : y[b * YL + r];
        float aa = alpha_audio[0];
        for (int d = threadIdx.x; d < DMODEL; d += 256) {
            float v = audio_emb[(size_t)tok * DMODEL + d] + type_emb[2 * DMODEL + d] + aa * pe_val(r, d);
            out[d] = v; outb[d] = f2bf(v);
        }
    }
}

// ---------------- bf16 MFMA NT GEMM: C[m][n] = sum_k A[m][k]*B[n][k] (+bias, relu) ----
// 128x128 tile, BK=32, 4 waves (2x2 of 64x64), m97 structure.
__global__ __launch_bounds__(256) void gemm_bf16_kernel(
    const u16* __restrict__ A, const u16* __restrict__ Bw,
    const float* __restrict__ bias,
    float* __restrict__ Cf, u16* __restrict__ Cb,
    int M, int N, int K, int relu)
{
    __shared__ u16 As[128 * 32];
    __shared__ u16 Bs[128 * 32];
    int tid = threadIdx.x;
    int w = tid >> 6, l = tid & 63;
    int m0 = blockIdx.y * 128, n0 = blockIdx.x * 128;
    int wm = (w >> 1) * 64, wn = (w & 1) * 64;

    f32x4 acc[4][4];
    #pragma unroll
    for (int i = 0; i < 4; ++i)
        #pragma unroll
        for (int j = 0; j < 4; ++j) acc[i][j] = (f32x4){0.f, 0.f, 0.f, 0.f};

    int srow0 = (w << 5) + (l >> 2);     // rows covered: chunk base 32w + sub
    int skp = (l & 3) << 3;              // k element offset 0/8/16/24

    for (int k0 = 0; k0 < K; k0 += 32) {
        #pragma unroll
        for (int c = 0; c < 2; ++c) {
            int row = srow0 + c * 16;
            int am = m0 + row; if (am >= M) am = M - 1;
            int bn = n0 + row; if (bn >= N) bn = N - 1;
            __builtin_amdgcn_global_load_lds(
                (const __attribute__((address_space(1))) void*)(A + (size_t)am * K + k0 + skp),
                (__attribute__((address_space(3))) void*)(As + ((w * 2 + c) << 9)), 16, 0, 0);
            __builtin_amdgcn_global_load_lds(
                (const __attribute__((address_space(1))) void*)(Bw + (size_t)bn * K + k0 + skp),
                (__attribute__((address_space(3))) void*)(Bs + ((w * 2 + c) << 9)), 16, 0, 0);
        }
        __syncthreads();
        short8 af[4], bfr[4];
        #pragma unroll
        for (int i = 0; i < 4; ++i) {
            af[i]  = *(const short8*)(As + (wm + i * 16 + (l & 15)) * 32 + ((l >> 4) << 3));
            bfr[i] = *(const short8*)(Bs + (wn + i * 16 + (l & 15)) * 32 + ((l >> 4) << 3));
        }
        #pragma unroll
        for (int i = 0; i < 4; ++i)
            #pragma unroll
            for (int j = 0; j < 4; ++j)
                acc[i][j] = __builtin_amdgcn_mfma_f32_16x16x32_bf16(af[i], bfr[j], acc[i][j], 0, 0, 0);
        __syncthreads();
    }

    #pragma unroll
    for (int i = 0; i < 4; ++i) {
        #pragma unroll
        for (int j = 0; j < 4; ++j) {
            #pragma unroll
            for (int jj = 0; jj < 4; ++jj) {
                int row = m0 + wm + i * 16 + ((l >> 4) << 2) + jj;
                int col = n0 + wn + j * 16 + (l & 15);
                if (row < M && col < N) {
                    float v = acc[i][j][jj];
                    if (bias) v += bias[col];
                    if (relu) v = fmaxf(v, 0.f);
                    if (Cf) Cf[(size_t)row * N + col] = v;
                    if (Cb) Cb[(size_t)row * N + col] = f2bf(v);
                }
            }
        }
    }
}

// ---------------- MFMA flash attention (bf16 in, f32 softmax/accum) ----------------
// grid (ceil(S/64), B*H), 256 thr = 4 waves, wave w owns q rows [q0+16w, q0+16w+16)
__global__ __launch_bounds__(256) void attn_mfma_kernel(
    const u16* __restrict__ qkv,
    const int* __restrict__ x1_lens, const int* __restrict__ x2_lens,
    const int* __restrict__ y1_lens, const int* __restrict__ y2_lens,
    const int* __restrict__ y_mask,
    u16* __restrict__ obuf)
{
    __shared__ u16 Ks[64 * 64];        // [kcol][d]  XOR-swizzled
    __shared__ u16 Vt[64 * 64];        // [d][kcol]  XOR-swizzled
    __shared__ u16 Ps[4][16 * 64];     // per-wave P [q][k] XOR-swizzled

    int tid = threadIdx.x;
    int w = tid >> 6, l = tid & 63;
    int bh = blockIdx.y;
    int b = bh >> 3, h = bh & 7;
    int q0 = blockIdx.x * 64;

    int x1 = x1_lens[b], xlen = x1 + 1 + x2_lens[b];
    int y1 = y1_lens[b], ylen = y1 + 1 + y2_lens[b];

    // Q fragments, scale 1/8 folded in (exact pow2)
    short8 qf[2];
    {
        int qr = q0 + w * 16 + (l & 15);
        int qrc = qr < SEQ ? qr : SEQ - 1;
        const u16* qp = qkv + (size_t)(b * SEQ + qrc) * 1536 + h * 64 + ((l >> 4) << 3);
        #pragma unroll
        for (int kb = 0; kb < 2; ++kb) {
            short8 raw = *(const short8*)(qp + kb * 32);
            short8 s8;
            #pragma unroll
            for (int e = 0; e < 8; ++e)
                s8[e] = (short)f2bf(bf2f((u16)raw[e]) * 0.125f);
            qf[kb] = s8;
        }
    }

    // row types for rows (l>>4)*4+j of this wave's tile
    // 0=x1 1=x2/xpad 2=emo 3=y1 4=cls 5=y2 6=blocked
    int rt[4];
    #pragma unroll
    for (int j = 0; j < 4; ++j) {
        int qrj = q0 + w * 16 + ((l >> 4) << 2) + j;
        int t;
        if (qrj >= SEQ) t = 6;
        else if (qrj < XL) t = (qrj < x1) ? 0 : 1;
        else if (qrj == XL) t = 2;
        else {
            int ry = qrj - XL - 1;
            t = (ry < y1) ? 3 : (ry == y1) ? 4 : (ry < ylen) ? 5 : 6;
        }
        rt[j] = t;
    }

    f32x4 oacc[4];
    #pragma unroll
    for (int db = 0; db < 4; ++db) oacc[db] = (f32x4){0.f, 0.f, 0.f, 0.f};
    float mrun[4] = {-INFINITY, -INFINITY, -INFINITY, -INFINITY};
    float lrun[4] = {0.f, 0.f, 0.f, 0.f};
    u16* Psw = &Ps[w][0];

    const int NKT = (SEQ + 63) / 64;   // 19
    for (int kt = 0; kt < NKT; ++kt) {
        __syncthreads();
        {   // stage K (row-major swizzled) and V^T (transposed swizzled)
            int r = tid >> 2, d0 = (tid & 3) << 4;
            int kr = kt * 64 + r;
            int krc = kr < SEQ ? kr : SEQ - 1;
            const u16* kp = qkv + (size_t)(b * SEQ + krc) * 1536 + 512 + h * 64 + d0;
            short8 ka = *(const short8*)kp;
            short8 kb8 = *(const short8*)(kp + 8);
            int ksw = (r & 7) << 3;
            *(short8*)&Ks[r * 64 + (d0 ^ ksw)] = ka;
            *(short8*)&Ks[r * 64 + ((d0 + 8) ^ ksw)] = kb8;
            const u16* vp = kp + 512;
            short8 va = *(const short8*)vp;
            short8 vb = *(const short8*)(vp + 8);
            #pragma unroll
            for (int e = 0; e < 8; ++e) {
                int d = d0 + e;
                Vt[d * 64 + (r ^ ((d & 7) << 3))] = (u16)va[e];
                int d2 = d0 + 8 + e;
                Vt[d2 * 64 + (r ^ ((d2 & 7) << 3))] = (u16)vb[e];
            }
        }
        __syncthreads();

        // QK^T: 4 col-blocks x (K=64 as 2 MFMAs)
        f32x4 sc[4];
        #pragma unroll
        for (int cb = 0; cb < 4; ++cb) {
            int krw = cb * 16 + (l & 15);
            int ksw = (krw & 7) << 3;
            short8 k0 = *(const short8*)&Ks[krw * 64 + ((((l >> 4) << 3)) ^ ksw)];
            short8 k1 = *(const short8*)&Ks[krw * 64 + ((32 + ((l >> 4) << 3)) ^ ksw)];
            f32x4 z = (f32x4){0.f, 0.f, 0.f, 0.f};
            z = __builtin_amdgcn_mfma_f32_16x16x32_bf16(qf[0], k0, z, 0, 0, 0);
            sc[cb] = __builtin_amdgcn_mfma_f32_16x16x32_bf16(qf[1], k1, z, 0, 0, 0);
        }

        // mask: col predicates per cb, row-type select per j
        int colbase = kt * 64;
        #pragma unroll
        for (int cb = 0; cb < 4; ++cb) {
            int col = colbase + cb * 16 + (l & 15);
            bool pad = (col >= SEQ);
            int ym_c = 0;
            if (col > XL && !pad) ym_c = y_mask[b * YL + col - XL - 1];
            bool a2c = (col == XL);
            bool ygt = (col > XL);
            bool aT0 = (col < x1);
            bool aT1 = (col >= x1) && (col < xlen);
            bool aT3 = aT0 || (ygt && col <= XL + y1);
            bool aT4 = (col < xlen) || a2c || (ygt && col <= XL + y1 + 1);
            bool aT5 = (((col < xlen) || a2c || (ygt && col <= XL + ylen)) && !ym_c);
            unsigned am = (aT0 ? 1u : 0u) | (aT1 ? 2u : 0u) | (a2c ? 4u : 0u) |
                          (aT3 ? 8u : 0u) | (aT4 ? 16u : 0u) | (aT5 ? 32u : 0u);
            #pragma unroll
            for (int j = 0; j < 4; ++j) {
                float s = sc[cb][j];
                s = ((am >> rt[j]) & 1u) ? s : NEGBIG;   // == ref's +(-1e9) absorption
                if (pad) s = -INFINITY;
                sc[cb][j] = s;
            }
        }

        // online softmax per q-row (rows live on 16-lane groups)
        #pragma unroll
        for (int j = 0; j < 4; ++j) {
            float tmax = fmaxf(fmaxf(sc[0][j], sc[1][j]), fmaxf(sc[2][j], sc[3][j]));
            tmax = fmaxf(tmax, __shfl_xor(tmax, 1));
            tmax = fmaxf(tmax, __shfl_xor(tmax, 2));
            tmax = fmaxf(tmax, __shfl_xor(tmax, 4));
            tmax = fmaxf(tmax, __shfl_xor(tmax, 8));
            float newm = fmaxf(mrun[j], tmax);
            float corr = expf(mrun[j] - newm);
            float p0 = expf(sc[0][j] - newm);
            float p1 = expf(sc[1][j] - newm);
            float p2 = expf(sc[2][j] - newm);
            float p3 = expf(sc[3][j] - newm);
            float ps = p0 + p1 + p2 + p3;
            ps += __shfl_xor(ps, 1); ps += __shfl_xor(ps, 2);
            ps += __shfl_xor(ps, 4); ps += __shfl_xor(ps, 8);
            lrun[j] = lrun[j] * corr + ps;
            mrun[j] = newm;
            #pragma unroll
            for (int db = 0; db < 4; ++db) oacc[db][j] *= corr;
            int prow = ((l >> 4) << 2) + j;
            int sw = (prow & 7) << 3;
            Psw[prow * 64 + ((0  + (l & 15)) ^ sw)] = f2bf(p0);
            Psw[prow * 64 + ((16 + (l & 15)) ^ sw)] = f2bf(p1);
            Psw[prow * 64 + ((32 + (l & 15)) ^ sw)] = f2bf(p2);
            Psw[prow * 64 + ((48 + (l & 15)) ^ sw)] = f2bf(p3);
        }

        // PV: O[16q x 64d] += P[16q x 64k] * V[64k x 64d]
        {
            int pr = l & 15, sw = (pr & 7) << 3;
            short8 pf0 = *(const short8*)&Psw[pr * 64 + ((((l >> 4) << 3)) ^ sw)];
            short8 pf1 = *(const short8*)&Psw[pr * 64 + ((32 + ((l >> 4) << 3)) ^ sw)];
            #pragma unroll
            for (int db = 0; db < 4; ++db) {
                int vr = db * 16 + (l & 15);
                int vsw = (vr & 7) << 3;
                short8 v0 = *(const short8*)&Vt[vr * 64 + ((((l >> 4) << 3)) ^ vsw)];
                short8 v1 = *(const short8*)&Vt[vr * 64 + ((32 + ((l >> 4) << 3)) ^ vsw)];
                oacc[db] = __builtin_amdgcn_mfma_f32_16x16x32_bf16(pf0, v0, oacc[db], 0, 0, 0);
                oacc[db] = __builtin_amdgcn_mfma_f32_16x16x32_bf16(pf1, v1, oacc[db], 0, 0, 0);
            }
        }
    }

    float rl[4];
    #pragma unroll
    for (int j = 0; j < 4; ++j) rl[j] = 1.f / lrun[j];
    #pragma unroll
    for (int db = 0; db < 4; ++db) {
        #pragma unroll
        for (int j = 0; j < 4; ++j) {
            int qrj = q0 + w * 16 + ((l >> 4) << 2) + j;
            if (qrj < SEQ)
                obuf[(size_t)(b * SEQ + qrj) * DMODEL + h * 64 + db * 16 + (l & 15)] =
                    f2bf(oacc[db][j] * rl[j]);
        }
    }
}

// ---------------- residual add + LayerNorm (f32 in-place + bf16 shadow) ----------------
__global__ __launch_bounds__(256) void add_ln_kernel(
    float* __restrict__ hbuf, u16* __restrict__ hbuf_bf, const float* __restrict__ delta,
    const float* __restrict__ g, const float* __restrict__ beta)
{
    __shared__ float red[4];
    int row = blockIdx.x, t = threadIdx.x;
    float* hp = hbuf + (size_t)row * DMODEL;
    u16* hb = hbuf_bf + (size_t)row * DMODEL;
    const float* dp = delta + (size_t)row * DMODEL;
    float v0 = hp[t] + dp[t];
    float v1 = hp[t + 256] + dp[t + 256];
    float s = v0 + v1;
    #pragma unroll
    for (int off = 32; off > 0; off >>= 1) s += __shfl_xor(s, off);
    if ((t & 63) == 0) red[t >> 6] = s;
    __syncthreads();
    float mu = (red[0] + red[1] + red[2] + red[3]) * (1.f / DMODEL);
    float d0 = v0 - mu, d1 = v1 - mu;
    float sq = d0 * d0 + d1 * d1;
    __syncthreads();
    #pragma unroll
    for (int off = 32; off > 0; off >>= 1) sq += __shfl_xor(sq, off);
    if ((t & 63) == 0) red[t >> 6] = sq;
    __syncthreads();
    float var = (red[0] + red[1] + red[2] + red[3]) * (1.f / DMODEL);
    float inv = 1.f / sqrtf(var + 1e-5f);
    float o0 = d0 * inv * g[t] + beta[t];
    float o1 = d1 * inv * g[t + 256] + beta[t + 256];
    hp[t] = o0; hp[t + 256] = o1;
    hb[t] = f2bf(o0); hb[t + 256] = f2bf(o1);
}

// ---------------- CE + top-3 over masked positions ----------------
__global__ __launch_bounds__(256) void ce_kernel(
    const float* __restrict__ logits, const int* __restrict__ y,
    const int* __restrict__ y_mask, float* __restrict__ accum)
{
    int row = blockIdx.x;           // 0..4095
    int b = row >> 10, r = row & 1023;
    int msk = y_mask[b * YL + r];
    if (!msk) return;
    const float* lp = logits + (size_t)(b * SEQ + XL + 1 + r) * OV;
    int tgt = y[b * YL + r];
    int t = threadIdx.x;
    __shared__ float red[4];

    float lmax = -INFINITY;
    for (int i = t; i < OV; i += 256) lmax = fmaxf(lmax, lp[i]);
    #pragma unroll
    for (int off = 32; off > 0; off >>= 1) lmax = fmaxf(lmax, __shfl_xor(lmax, off));
    if ((t & 63) == 0) red[t >> 6] = lmax;
    __syncthreads();
    lmax = fmaxf(fmaxf(red[0], red[1]), fmaxf(red[2], red[3]));
    __syncthreads();

    float lsum = 0.f;
    for (int i = t; i < OV; i += 256) lsum += expf(lp[i] - lmax);
    #pragma unroll
    for (int off = 32; off > 0; off >>= 1) lsum += __shfl_xor(lsum, off);
    if ((t & 63) == 0) red[t >> 6] = lsum;
    __syncthreads();
    lsum = red[0] + red[1] + red[2] + red[3];
    __syncthreads();

    float lt = lp[tgt];
    float cnt = 0.f;
    for (int i = t; i < OV; i += 256) {
        float v = lp[i];
        if (v > lt || (v == lt && i < tgt)) cnt += 1.f;
    }
    #pragma unroll
    for (int off = 32; off > 0; off >>= 1) cnt += __shfl_xor(cnt, off);
    if ((t & 63) == 0) red[t >> 6] = cnt;
    __syncthreads();
    cnt = red[0] + red[1] + red[2] + red[3];

    if (t == 0) {
        float ce = -(lt - lmax - logf(lsum));
        float inc = (tgt != EOS_TOK) ? 1.f : 0.f;
        float corr = (cnt < 2.5f) ? 1.f : 0.f;
        atomicAdd(&accum[0], ce);
        atomicAdd(&accum[1], 1.f);
        atomicAdd(&accum[2], corr * inc);
        atomicAdd(&accum[3], inc);
    }
}

__global__ void init_accum_kernel(float* accum) {
    if (threadIdx.x < 8) accum[threadIdx.x] = 0.f;
}

// ---------------- duration head + final outputs ----------------
__global__ __launch_bounds__(256) void finalize_kernel(
    const float* __restrict__ hbuf,
    const int* __restrict__ y1_lens, const int* __restrict__ y2_lens,
    const int* __restrict__ x2_lens,
    const float* __restrict__ dW1, const float* __restrict__ db1,
    const float* __restrict__ dW2, const float* __restrict__ db2,
    const float* __restrict__ dW3, const float* __restrict__ db3,
    const float* __restrict__ accum, float* __restrict__ out)
{
    __shared__ float h1[256];
    __shared__ float h2[128];
    __shared__ float preds[BATCH];
    int t = threadIdx.x;
    for (int b = 0; b < BATCH; ++b) {
        const float* cls = hbuf + (size_t)(b * SEQ + XL + 1 + y1_lens[b]) * DMODEL;
        {
            float acc = db1[t];
            const float* w = dW1 + (size_t)t * DMODEL;
            for (int k = 0; k < DMODEL; ++k) acc = fmaf(cls[k], w[k], acc);
            h1[t] = fmaxf(acc, 0.f);
        }
        __syncthreads();
        if (t < 128) {
            float acc = db2[t];
            const float* w = dW2 + (size_t)t * 256;
            for (int k = 0; k < 256; ++k) acc = fmaf(h1[k], w[k], acc);
            h2[t] = fmaxf(acc, 0.f);
        }
        __syncthreads();
        if (t == 0) {
            float acc = db3[0];
            for (int k = 0; k < 128; ++k) acc = fmaf(h2[k], dW3[k], acc);
            preds[b] = acc;
        }
        __syncthreads();
    }
    if (t == 0) {
        float dl = 0.f;
        for (int b = 0; b < BATCH; ++b) {
            float tgt = (float)y2_lens[b] / (float)x2_lens[b];
            float e = preds[b] - tgt;
            float ae = fabsf(e);
            dl += (ae <= 1.f) ? 0.5f * e * e : (ae - 0.5f);
        }
        dl *= (1.f / BATCH);
        float token_loss = accum[0] / accum[1];
        float acc_v = accum[2] / fmaxf(accum[3], 1.f);
        out[0] = token_loss + dl;
        out[1] = acc_v;
    }
}

// ---------------- orchestration ----------------
extern "C" void kernel_launch(void* const* d_in, const int* in_sizes, int n_in,
                              void* d_out, int out_size, void* d_ws, size_t ws_size,
                              hipStream_t stream)
{
    const int*   x           = (const int*)d_in[0];
    const int*   x1_lens     = (const int*)d_in[1];
    const int*   x2_lens     = (const int*)d_in[2];
    const int*   y           = (const int*)d_in[3];
    const int*   y1_lens     = (const int*)d_in[4];
    const int*   y2_lens     = (const int*)d_in[5];
    const int*   y_mask      = (const int*)d_in[6];
    const float* emo_feature = (const float*)d_in[7];
    const float* text_emb    = (const float*)d_in[8];
    const float* audio_emb   = (const float*)d_in[9];
    const float* type_emb    = (const float*)d_in[10];
    const float* emo_W       = (const float*)d_in[11];
    const float* emo_b       = (const float*)d_in[12];
    const float* alpha_text  = (const float*)d_in[13];
    const float* alpha_audio = (const float*)d_in[14];
    const float* Wqkv        = (const float*)d_in[15];
    const float* bqkv        = (const float*)d_in[16];
    const float* Wo          = (const float*)d_in[17];
    const float* bo          = (const float*)d_in[18];
    const float* ln1_g       = (const float*)d_in[19];
    const float* ln1_b       = (const float*)d_in[20];
    const float* ln2_g       = (const float*)d_in[21];
    const float* ln2_b       = (const float*)d_in[22];
    const float* W1          = (const float*)d_in[23];
    const float* b1          = (const float*)d_in[24];
    const float* W2          = (const float*)d_in[25];
    const float* b2          = (const float*)d_in[26];
    const float* predict_W   = (const float*)d_in[27];
    const float* dW1         = (const float*)d_in[28];
    const float* db1         = (const float*)d_in[29];
    const float* dW2         = (const float*)d_in[30];
    const float* db2         = (const float*)d_in[31];
    const float* dW3         = (const float*)d_in[32];
    const float* db3         = (const float*)d_in[33];

    const int M = BATCH * SEQ;                       // 4612
    char* p = (char*)d_ws;
    float* hbuf   = (float*)p; p += 9445376;         // M*512*4
    float* delta  = (float*)p; p += 9445376;
    char*  uni    = p;         p += 18909440;        // max(ff1_bf, logits)
    u16*   hbuf_bf = (u16*)p;  p += 4722688;
    u16*   qkv_bf  = (u16*)p;  p += 14168064;
    u16*   obuf_bf = (u16*)p;  p += 4722688;
    u16*   wbf     = (u16*)p;  p += 19923968;
    u16*   ff1_bf  = (u16*)uni;
    float* logits  = (float*)uni;
    float* accum   = delta;                          // dead region by CE time

    u16* wq_bf = wbf;                                // 3*1536*512
    u16* wo_bf = wq_bf + 2359296;                    // 3*512*512
    u16* w1_bf = wo_bf + 786432;                     // 3*2048*512
    u16* w2_bf = w1_bf + 3145728;                    // 3*512*2048
    u16* wp_bf = w2_bf + 3145728;                    // 1025*512

    // weight conversion (every launch; deterministic)
    cvt_kernel<<<512, 256, 0, stream>>>(Wqkv, wq_bf, 2359296 / 4);
    cvt_kernel<<<512, 256, 0, stream>>>(Wo, wo_bf, 786432 / 4);
    cvt_kernel<<<512, 256, 0, stream>>>(W1, w1_bf, 3145728 / 4);
    cvt_kernel<<<512, 256, 0, stream>>>(W2, w2_bf, 3145728 / 4);
    cvt_kernel<<<512, 256, 0, stream>>>(predict_W, wp_bf, 524800 / 4);

    build_h_kernel<<<M, 256, 0, stream>>>(
        x, y, y_mask, emo_feature, text_emb, audio_emb, type_emb,
        emo_W, emo_b, alpha_text, alpha_audio, hbuf, hbuf_bf);

    const int MG = (M + 127) / 128;   // 37
    for (int l = 0; l < NLAYER; ++l) {
        gemm_bf16_kernel<<<dim3(12, MG), 256, 0, stream>>>(
            hbuf_bf, wq_bf + (size_t)l * 1536 * 512, bqkv + l * 1536,
            nullptr, qkv_bf, M, 1536, 512, 0);
        attn_mfma_kernel<<<dim3((SEQ + 63) / 64, BATCH * NH), 256, 0, stream>>>(
            qkv_bf, x1_lens, x2_lens, y1_lens, y2_lens, y_mask, obuf_bf);
        gemm_bf16_kernel<<<dim3(4, MG), 256, 0, stream>>>(
            obuf_bf, wo_bf + (size_t)l * 512 * 512, bo + l * 512,
            delta, nullptr, M, 512, 512, 0);
        add_ln_kernel<<<M, 256, 0, stream>>>(hbuf, hbuf_bf, delta,
            ln1_g + l * DMODEL, ln1_b + l * DMODEL);
        gemm_bf16_kernel<<<dim3(16, MG), 256, 0, stream>>>(
            hbuf_bf, w1_bf + (size_t)l * 2048 * 512, b1 + l * 2048,
            nullptr, ff1_bf, M, 2048, 512, 1);
        gemm_bf16_kernel<<<dim3(4, MG), 256, 0, stream>>>(
            ff1_bf, w2_bf + (size_t)l * 512 * 2048, b2 + l * 512,
            delta, nullptr, M, 512, 2048, 0);
        add_ln_kernel<<<M, 256, 0, stream>>>(hbuf, hbuf_bf, delta,
            ln2_g + l * DMODEL, ln2_b + l * DMODEL);
    }

    // logits over ALL rows (CE reads only y rows): [M x 1025]
    gemm_bf16_kernel<<<dim3((OV + 127) / 128, MG), 256, 0, stream>>>(
        hbuf_bf, wp_bf, nullptr, logits, nullptr, M, OV, 512, 0);

    init_accum_kernel<<<1, 64, 0, stream>>>(accum);
    ce_kernel<<<BATCH * YL, 256, 0, stream>>>(logits, y, y_mask, accum);
    finalize_kernel<<<1, 256, 0, stream>>>(hbuf, y1_lens, y2_lens, x2_lens,
        dW1, db1, dW2, db2, dW3, db3, accum, (float*)d_out);
}

// Round 3
// 832.347 us; speedup vs baseline: 6.9719x; 1.1301x over previous
//
#include <hip/hip_runtime.h>
#include <hip/hip_bf16.h>
#include <math.h>

#define BATCH 4
#define XL 128
#define YL 1024
#define DMODEL 512
#define NH 8
#define NLAYER 3
#define DFF 2048
#define MASK_ID 1024
#define EOS_TOK 1024
#define HD 64
#define SEQ 1153          // XL + 1 + YL
#define OV 1025
#define NEGBIG (-1e9f)
#define QBLK 128

typedef unsigned short u16;
typedef short short8 __attribute__((ext_vector_type(8)));
typedef float f32x4 __attribute__((ext_vector_type(4)));

__device__ __forceinline__ u16 f2bf(float f) {
    union { float f; unsigned u; } v; v.f = f;
    unsigned r = v.u + 0x7fffu + ((v.u >> 16) & 1u);   // RNE
    return (u16)(r >> 16);
}
__device__ __forceinline__ float bf2f(u16 b) {
    union { unsigned u; float f; } v; v.u = ((unsigned)b) << 16;
    return v.f;
}

// ---------------- fused f32 -> bf16 convert for all 5 weight tensors ----------------
__global__ __launch_bounds__(256) void cvt5_kernel(
    const float* __restrict__ s0, u16* __restrict__ d0, int n0,
    const float* __restrict__ s1, u16* __restrict__ d1, int n1,
    const float* __restrict__ s2, u16* __restrict__ d2, int n2,
    const float* __restrict__ s3, u16* __restrict__ d3, int n3,
    const float* __restrict__ s4, u16* __restrict__ d4, int n4)
{
    int c0 = n0, c1 = c0 + n1, c2 = c1 + n2, c3 = c2 + n3, c4 = c3 + n4;
    for (int i = blockIdx.x * 256 + threadIdx.x; i < c4; i += gridDim.x * 256) {
        const float* s; u16* d; int j;
        if (i < c0)      { s = s0; d = d0; j = i; }
        else if (i < c1) { s = s1; d = d1; j = i - c0; }
        else if (i < c2) { s = s2; d = d2; j = i - c1; }
        else if (i < c3) { s = s3; d = d3; j = i - c2; }
        else             { s = s4; d = d4; j = i - c3; }
        float4 v = ((const float4*)s)[j];
        ushort4 o;
        o.x = f2bf(v.x); o.y = f2bf(v.y); o.z = f2bf(v.z); o.w = f2bf(v.w);
        ((ushort4*)d)[j] = o;
    }
}

// ---------------- sinusoid helper ----------------
__device__ __forceinline__ float pe_val(int pos, int d) {
    int i2 = d & ~1;
    float dv = expf((float)i2 * (-9.210340371976184f / (float)DMODEL));
    float ang = (float)pos * dv;
    return (d & 1) ? cosf(ang) : sinf(ang);
}

// ---------------- build h_input [B,S,D] (f32 + bf16 shadow) ----------------
__global__ __launch_bounds__(256) void build_h_kernel(
    const int* __restrict__ x, const int* __restrict__ y, const int* __restrict__ y_mask,
    const float* __restrict__ emo_feature, const float* __restrict__ text_emb,
    const float* __restrict__ audio_emb, const float* __restrict__ type_emb,
    const float* __restrict__ emo_W, const float* __restrict__ emo_b,
    const float* __restrict__ alpha_text, const float* __restrict__ alpha_audio,
    float* __restrict__ hbuf, u16* __restrict__ hbuf_bf)
{
    int bs = blockIdx.x;
    int b = bs / SEQ, s = bs % SEQ;
    float* out = hbuf + (size_t)bs * DMODEL;
    u16* outb = hbuf_bf + (size_t)bs * DMODEL;
    if (s == XL) {
        const float* f = emo_feature + b * 768;
        for (int d = threadIdx.x; d < DMODEL; d += 256) {
            const float* w = emo_W + (size_t)d * 768;
            float acc = 0.f;
            for (int k = 0; k < 768; ++k) acc = fmaf(f[k], w[k], acc);
            float v = acc + emo_b[d] + type_emb[DMODEL + d];
            out[d] = v; outb[d] = f2bf(v);
        }
    } else if (s < XL) {
        int tok = x[b * XL + s];
        float at = alpha_text[0];
        for (int d = threadIdx.x; d < DMODEL; d += 256) {
            float v = text_emb[(size_t)tok * DMODEL + d] + type_emb[d] + at * pe_val(s, d);
            out[d] = v; outb[d] = f2bf(v);
        }
    } else {
        int r = s - XL - 1;
        int tok = y_mask[b * YL + r] ? MASK_ID : y[b * YL + r];
        float aa = alpha_audio[0];
        for (int d = threadIdx.x; d < DMODEL; d += 256) {
            float v = audio_emb[(size_t)tok * DMODEL + d] + type_emb[2 * DMODEL + d] + aa * pe_val(r, d);
            out[d] = v; outb[d] = f2bf(v);
        }
    }
}

// ---------------- bf16 MFMA NT GEMM: C[m][n] = sum_k A[m][k]*B[n][k] (+bias, relu) ----
__global__ __launch_bounds__(256) void gemm_bf16_kernel(
    const u16* __restrict__ A, const u16* __restrict__ Bw,
    const float* __restrict__ bias,
    float* __restrict__ Cf, u16* __restrict__ Cb,
    int M, int N, int K, int relu)
{
    __shared__ u16 As[128 * 32];
    __shared__ u16 Bs[128 * 32];
    int tid = threadIdx.x;
    int w = tid >> 6, l = tid & 63;
    int m0 = blockIdx.y * 128, n0 = blockIdx.x * 128;
    int wm = (w >> 1) * 64, wn = (w & 1) * 64;

    f32x4 acc[4][4];
    #pragma unroll
    for (int i = 0; i < 4; ++i)
        #pragma unroll
        for (int j = 0; j < 4; ++j) acc[i][j] = (f32x4){0.f, 0.f, 0.f, 0.f};

    int srow0 = (w << 5) + (l >> 2);
    int skp = (l & 3) << 3;

    for (int k0 = 0; k0 < K; k0 += 32) {
        #pragma unroll
        for (int c = 0; c < 2; ++c) {
            int row = srow0 + c * 16;
            int am = m0 + row; if (am >= M) am = M - 1;
            int bn = n0 + row; if (bn >= N) bn = N - 1;
            __builtin_amdgcn_global_load_lds(
                (const __attribute__((address_space(1))) void*)(A + (size_t)am * K + k0 + skp),
                (__attribute__((address_space(3))) void*)(As + ((w * 2 + c) << 9)), 16, 0, 0);
            __builtin_amdgcn_global_load_lds(
                (const __attribute__((address_space(1))) void*)(Bw + (size_t)bn * K + k0 + skp),
                (__attribute__((address_space(3))) void*)(Bs + ((w * 2 + c) << 9)), 16, 0, 0);
        }
        __syncthreads();
        short8 af[4], bfr[4];
        #pragma unroll
        for (int i = 0; i < 4; ++i) {
            af[i]  = *(const short8*)(As + (wm + i * 16 + (l & 15)) * 32 + ((l >> 4) << 3));
            bfr[i] = *(const short8*)(Bs + (wn + i * 16 + (l & 15)) * 32 + ((l >> 4) << 3));
        }
        #pragma unroll
        for (int i = 0; i < 4; ++i)
            #pragma unroll
            for (int j = 0; j < 4; ++j)
                acc[i][j] = __builtin_amdgcn_mfma_f32_16x16x32_bf16(af[i], bfr[j], acc[i][j], 0, 0, 0);
        __syncthreads();
    }

    #pragma unroll
    for (int i = 0; i < 4; ++i) {
        #pragma unroll
        for (int j = 0; j < 4; ++j) {
            #pragma unroll
            for (int jj = 0; jj < 4; ++jj) {
                int row = m0 + wm + i * 16 + ((l >> 4) << 2) + jj;
                int col = n0 + wn + j * 16 + (l & 15);
                if (row < M && col < N) {
                    float v = acc[i][j][jj];
                    if (bias) v += bias[col];
                    if (relu) v = fmaxf(v, 0.f);
                    if (Cf) Cf[(size_t)row * N + col] = v;
                    if (Cb) Cb[(size_t)row * N + col] = f2bf(v);
                }
            }
        }
    }
}

// ---------------- MFMA flash attention, QBLK=128, mask-sparse k-loop ----------------
// grid (ceil(S/128), B*H), 256 thr = 4 waves, wave w owns q rows [q0+32w, q0+32w+32)
__global__ __launch_bounds__(256) void attn_mfma_kernel(
    const u16* __restrict__ qkv,
    const int* __restrict__ x1_lens, const int* __restrict__ x2_lens,
    const int* __restrict__ y1_lens, const int* __restrict__ y2_lens,
    const int* __restrict__ y_mask,
    u16* __restrict__ obuf)
{
    __shared__ u16 Ks[64 * 64];          // [k][d] XOR-swizzled
    __shared__ u16 Vt[64 * 64];          // [d][k] XOR-swizzled
    __shared__ u16 Ps[4][32 * 64];       // per-wave P [q][k] XOR-swizzled
    __shared__ unsigned char Am[1216];   // per-col 6-bit allow mask

    int tid = threadIdx.x;
    int w = tid >> 6, l = tid & 63;
    int bh = blockIdx.y;
    int b = bh >> 3, h = bh & 7;
    int q0 = blockIdx.x * QBLK;

    int x1 = x1_lens[b], xlen = x1 + 1 + x2_lens[b];
    int y1 = y1_lens[b], ylen = y1 + 1 + y2_lens[b];

    // ---- block-level kmax over ALIVE rows; early-exit fully-dead blocks ----
    int kmax = -1;
    if (q0 < XL) kmax = max(kmax, xlen - 1);                    // x rows (block 0)
    if (XL >= q0 && XL < q0 + QBLK) kmax = max(kmax, XL);       // emo row
    {
        int ry0 = max(0, q0 - XL - 1);
        int ry1 = min(YL - 1, q0 + QBLK - 2 - XL);
        if (ry0 <= ry1) {
            if (ry0 <= y1 - 1) kmax = max(kmax, XL + y1);              // y1 rows
            if (y1 >= ry0 && y1 <= ry1) kmax = max(kmax, XL + y1 + 1); // cls row
            int a = max(ry0, y1 + 1), bb = min(ry1, ylen - 1);
            if (a <= bb) kmax = max(kmax, XL + ylen);                  // y2 rows
        }
    }
    if (kmax < 0) return;          // all rows dead: outputs unread downstream
    int NKT = (kmax >> 6) + 1;

    // ---- precompute per-column allow-mask (bits: T0,T1,T2,T3,T4,T5) ----
    for (int c = tid; c < 1216; c += 256) {
        unsigned v = 0;
        if (c < SEQ) {
            int ym = 0;
            if (c > XL) ym = y_mask[b * YL + c - XL - 1];
            bool a2c = (c == XL);
            bool ygt = (c > XL);
            bool aT0 = (c < x1);
            bool aT1 = (c >= x1) && (c < xlen);
            bool aT3 = aT0 || (ygt && c <= XL + y1);
            bool aT4 = (c < xlen) || a2c || (ygt && c <= XL + y1 + 1);
            bool aT5 = (((c < xlen) || a2c || (ygt && c <= XL + ylen)) && !ym);
            v = (aT0 ? 1u : 0u) | (aT1 ? 2u : 0u) | (a2c ? 4u : 0u) |
                (aT3 ? 8u : 0u) | (aT4 ? 16u : 0u) | (aT5 ? 32u : 0u);
        }
        Am[c] = (unsigned char)v;
    }

    // ---- Q fragments (scale 1/8 folded in, exact pow2) ----
    short8 qf[2][2];
    #pragma unroll
    for (int qh = 0; qh < 2; ++qh) {
        int qr = q0 + w * 32 + qh * 16 + (l & 15);
        const u16* qp = qkv + (size_t)(b * SEQ + qr) * 1536 + h * 64 + ((l >> 4) << 3);
        #pragma unroll
        for (int kb = 0; kb < 2; ++kb) {
            short8 raw = *(const short8*)(qp + kb * 32);
            short8 s8;
            #pragma unroll
            for (int e = 0; e < 8; ++e)
                s8[e] = (short)f2bf(bf2f((u16)raw[e]) * 0.125f);
            qf[qh][kb] = s8;
        }
    }

    // ---- row types: 0=x1 1=x2 2=emo 3=y1 4=cls 5=y2 7=dead ----
    int rt[2][4];
    #pragma unroll
    for (int qh = 0; qh < 2; ++qh)
        #pragma unroll
        for (int j = 0; j < 4; ++j) {
            int qrj = q0 + w * 32 + qh * 16 + ((l >> 4) << 2) + j;
            int t;
            if (qrj < XL) t = (qrj < x1) ? 0 : 1;
            else if (qrj == XL) t = 2;
            else {
                int ry = qrj - XL - 1;
                t = (ry < y1) ? 3 : (ry == y1) ? 4 : (ry < ylen) ? 5 : 7;
            }
            rt[qh][j] = t;
        }

    f32x4 oacc[2][4];
    #pragma unroll
    for (int qh = 0; qh < 2; ++qh)
        #pragma unroll
        for (int db = 0; db < 4; ++db) oacc[qh][db] = (f32x4){0.f, 0.f, 0.f, 0.f};
    float mrun[2][4], lrun[2][4];
    #pragma unroll
    for (int qh = 0; qh < 2; ++qh)
        #pragma unroll
        for (int j = 0; j < 4; ++j) { mrun[qh][j] = -INFINITY; lrun[qh][j] = 0.f; }
    u16* Psw = &Ps[w][0];

    for (int kt = 0; kt < NKT; ++kt) {
        __syncthreads();
        {   // stage K rows (b128 swizzled writes)
            int r = tid >> 2, d0k = (tid & 3) << 4;
            int krc = min(kt * 64 + r, SEQ - 1);
            const u16* kp = qkv + (size_t)(b * SEQ + krc) * 1536 + 512 + h * 64 + d0k;
            short8 ka = *(const short8*)kp;
            short8 kb8 = *(const short8*)(kp + 8);
            int ksw = (r & 7) << 3;
            *(short8*)&Ks[r * 64 + (d0k ^ ksw)] = ka;
            *(short8*)&Ks[r * 64 + ((d0k + 8) ^ ksw)] = kb8;
        }
        {   // stage V^T via paired b32 writes (2 k per write)
            int rp = tid >> 3, o = tid & 7;
            int d0v = o * 8;
            int k0r = min(kt * 64 + 2 * rp, SEQ - 1);
            int k1r = min(kt * 64 + 2 * rp + 1, SEQ - 1);
            const u16* v0p = qkv + (size_t)(b * SEQ + k0r) * 1536 + 1024 + h * 64 + d0v;
            const u16* v1p = qkv + (size_t)(b * SEQ + k1r) * 1536 + 1024 + h * 64 + d0v;
            short8 va = *(const short8*)v0p;
            short8 vb = *(const short8*)v1p;
            #pragma unroll
            for (int e = 0; e < 8; ++e) {
                int d = d0v + e;
                unsigned val = (unsigned)(u16)va[e] | ((unsigned)(u16)vb[e] << 16);
                *(unsigned*)&Vt[d * 64 + ((2 * rp) ^ ((d & 7) << 3))] = val;
            }
        }
        __syncthreads();

        // per-col allow bytes for this tile
        unsigned amv[4];
        #pragma unroll
        for (int cb = 0; cb < 4; ++cb)
            amv[cb] = Am[kt * 64 + cb * 16 + (l & 15)];

        // QK^T
        f32x4 sc[2][4];
        #pragma unroll
        for (int cb = 0; cb < 4; ++cb) {
            int krw = cb * 16 + (l & 15);
            int ksw = (krw & 7) << 3;
            short8 k0 = *(const short8*)&Ks[krw * 64 + ((((l >> 4) << 3)) ^ ksw)];
            short8 k1 = *(const short8*)&Ks[krw * 64 + ((32 + ((l >> 4) << 3)) ^ ksw)];
            #pragma unroll
            for (int qh = 0; qh < 2; ++qh) {
                f32x4 z = (f32x4){0.f, 0.f, 0.f, 0.f};
                z = __builtin_amdgcn_mfma_f32_16x16x32_bf16(qf[qh][0], k0, z, 0, 0, 0);
                sc[qh][cb] = __builtin_amdgcn_mfma_f32_16x16x32_bf16(qf[qh][1], k1, z, 0, 0, 0);
            }
        }

        // mask + online softmax + P write
        #pragma unroll
        for (int qh = 0; qh < 2; ++qh) {
            #pragma unroll
            for (int j = 0; j < 4; ++j) {
                int rtj = rt[qh][j];
                float s0 = ((amv[0] >> rtj) & 1u) ? sc[qh][0][j] : NEGBIG;
                float s1 = ((amv[1] >> rtj) & 1u) ? sc[qh][1][j] : NEGBIG;
                float s2 = ((amv[2] >> rtj) & 1u) ? sc[qh][2][j] : NEGBIG;
                float s3 = ((amv[3] >> rtj) & 1u) ? sc[qh][3][j] : NEGBIG;
                float tmax = fmaxf(fmaxf(s0, s1), fmaxf(s2, s3));
                tmax = fmaxf(tmax, __shfl_xor(tmax, 1));
                tmax = fmaxf(tmax, __shfl_xor(tmax, 2));
                tmax = fmaxf(tmax, __shfl_xor(tmax, 4));
                tmax = fmaxf(tmax, __shfl_xor(tmax, 8));
                float newm = fmaxf(mrun[qh][j], tmax);
                float corr = __expf(mrun[qh][j] - newm);
                float p0 = __expf(s0 - newm);
                float p1 = __expf(s1 - newm);
                float p2 = __expf(s2 - newm);
                float p3 = __expf(s3 - newm);
                float ps = p0 + p1 + p2 + p3;
                ps += __shfl_xor(ps, 1); ps += __shfl_xor(ps, 2);
                ps += __shfl_xor(ps, 4); ps += __shfl_xor(ps, 8);
                lrun[qh][j] = lrun[qh][j] * corr + ps;
                mrun[qh][j] = newm;
                #pragma unroll
                for (int db = 0; db < 4; ++db) oacc[qh][db][j] *= corr;
                int lr = qh * 16 + ((l >> 4) << 2) + j;
                int sw = (lr & 7) << 3;
                Psw[lr * 64 + ((0  + (l & 15)) ^ sw)] = f2bf(p0);
                Psw[lr * 64 + ((16 + (l & 15)) ^ sw)] = f2bf(p1);
                Psw[lr * 64 + ((32 + (l & 15)) ^ sw)] = f2bf(p2);
                Psw[lr * 64 + ((48 + (l & 15)) ^ sw)] = f2bf(p3);
            }
        }

        // PV
        short8 pf[2][2];
        #pragma unroll
        for (int qh = 0; qh < 2; ++qh) {
            int pr = qh * 16 + (l & 15);
            int sw = (pr & 7) << 3;
            pf[qh][0] = *(const short8*)&Psw[pr * 64 + ((((l >> 4) << 3)) ^ sw)];
            pf[qh][1] = *(const short8*)&Psw[pr * 64 + ((32 + ((l >> 4) << 3)) ^ sw)];
        }
        #pragma unroll
        for (int db = 0; db < 4; ++db) {
            int vr = db * 16 + (l & 15);
            int vsw = (vr & 7) << 3;
            short8 v0 = *(const short8*)&Vt[vr * 64 + ((((l >> 4) << 3)) ^ vsw)];
            short8 v1 = *(const short8*)&Vt[vr * 64 + ((32 + ((l >> 4) << 3)) ^ vsw)];
            #pragma unroll
            for (int qh = 0; qh < 2; ++qh) {
                oacc[qh][db] = __builtin_amdgcn_mfma_f32_16x16x32_bf16(pf[qh][0], v0, oacc[qh][db], 0, 0, 0);
                oacc[qh][db] = __builtin_amdgcn_mfma_f32_16x16x32_bf16(pf[qh][1], v1, oacc[qh][db], 0, 0, 0);
            }
        }
    }

    #pragma unroll
    for (int qh = 0; qh < 2; ++qh) {
        float rl[4];
        #pragma unroll
        for (int j = 0; j < 4; ++j) rl[j] = 1.f / lrun[qh][j];
        #pragma unroll
        for (int db = 0; db < 4; ++db) {
            #pragma unroll
            for (int j = 0; j < 4; ++j) {
                int qrj = q0 + w * 32 + qh * 16 + ((l >> 4) << 2) + j;
                obuf[(size_t)(b * SEQ + qrj) * DMODEL + h * 64 + db * 16 + (l & 15)] =
                    f2bf(oacc[qh][db][j] * rl[j]);
            }
        }
    }
}

// ---------------- residual add + LayerNorm (f32 in-place + bf16 shadow) ----------------
__global__ __launch_bounds__(256) void add_ln_kernel(
    float* __restrict__ hbuf, u16* __restrict__ hbuf_bf, const float* __restrict__ delta,
    const float* __restrict__ g, const float* __restrict__ beta)
{
    __shared__ float red[4];
    int row = blockIdx.x, t = threadIdx.x;
    float* hp = hbuf + (size_t)row * DMODEL;
    u16* hb = hbuf_bf + (size_t)row * DMODEL;
    const float* dp = delta + (size_t)row * DMODEL;
    float v0 = hp[t] + dp[t];
    float v1 = hp[t + 256] + dp[t + 256];
    float s = v0 + v1;
    #pragma unroll
    for (int off = 32; off > 0; off >>= 1) s += __shfl_xor(s, off);
    if ((t & 63) == 0) red[t >> 6] = s;
    __syncthreads();
    float mu = (red[0] + red[1] + red[2] + red[3]) * (1.f / DMODEL);
    float d0 = v0 - mu, d1 = v1 - mu;
    float sq = d0 * d0 + d1 * d1;
    __syncthreads();
    #pragma unroll
    for (int off = 32; off > 0; off >>= 1) sq += __shfl_xor(sq, off);
    if ((t & 63) == 0) red[t >> 6] = sq;
    __syncthreads();
    float var = (red[0] + red[1] + red[2] + red[3]) * (1.f / DMODEL);
    float inv = 1.f / sqrtf(var + 1e-5f);
    float o0 = d0 * inv * g[t] + beta[t];
    float o1 = d1 * inv * g[t + 256] + beta[t + 256];
    hp[t] = o0; hp[t + 256] = o1;
    hb[t] = f2bf(o0); hb[t + 256] = f2bf(o1);
}

// ---------------- CE + top-3 over masked positions ----------------
__global__ __launch_bounds__(256) void ce_kernel(
    const float* __restrict__ logits, const int* __restrict__ y,
    const int* __restrict__ y_mask, float* __restrict__ accum)
{
    int row = blockIdx.x;
    int b = row >> 10, r = row & 1023;
    int msk = y_mask[b * YL + r];
    if (!msk) return;
    const float* lp = logits + (size_t)(b * SEQ + XL + 1 + r) * OV;
    int tgt = y[b * YL + r];
    int t = threadIdx.x;
    __shared__ float red[4];

    float lmax = -INFINITY;
    for (int i = t; i < OV; i += 256) lmax = fmaxf(lmax, lp[i]);
    #pragma unroll
    for (int off = 32; off > 0; off >>= 1) lmax = fmaxf(lmax, __shfl_xor(lmax, off));
    if ((t & 63) == 0) red[t >> 6] = lmax;
    __syncthreads();
    lmax = fmaxf(fmaxf(red[0], red[1]), fmaxf(red[2], red[3]));
    __syncthreads();

    float lsum = 0.f;
    for (int i = t; i < OV; i += 256) lsum += expf(lp[i] - lmax);
    #pragma unroll
    for (int off = 32; off > 0; off >>= 1) lsum += __shfl_xor(lsum, off);
    if ((t & 63) == 0) red[t >> 6] = lsum;
    __syncthreads();
    lsum = red[0] + red[1] + red[2] + red[3];
    __syncthreads();

    float lt = lp[tgt];
    float cnt = 0.f;
    for (int i = t; i < OV; i += 256) {
        float v = lp[i];
        if (v > lt || (v == lt && i < tgt)) cnt += 1.f;
    }
    #pragma unroll
    for (int off = 32; off > 0; off >>= 1) cnt += __shfl_xor(cnt, off);
    if ((t & 63) == 0) red[t >> 6] = cnt;
    __syncthreads();
    cnt = red[0] + red[1] + red[2] + red[3];

    if (t == 0) {
        float ce = -(lt - lmax - logf(lsum));
        float inc = (tgt != EOS_TOK) ? 1.f : 0.f;
        float corr = (cnt < 2.5f) ? 1.f : 0.f;
        atomicAdd(&accum[0], ce);
        atomicAdd(&accum[1], 1.f);
        atomicAdd(&accum[2], corr * inc);
        atomicAdd(&accum[3], inc);
    }
}

__global__ void init_accum_kernel(float* accum) {
    if (threadIdx.x < 8) accum[threadIdx.x] = 0.f;
}

// ---------------- duration head + final outputs ----------------
__global__ __launch_bounds__(256) void finalize_kernel(
    const float* __restrict__ hbuf,
    const int* __restrict__ y1_lens, const int* __restrict__ y2_lens,
    const int* __restrict__ x2_lens,
    const float* __restrict__ dW1, const float* __restrict__ db1,
    const float* __restrict__ dW2, const float* __restrict__ db2,
    const float* __restrict__ dW3, const float* __restrict__ db3,
    const float* __restrict__ accum, float* __restrict__ out)
{
    __shared__ float h1[256];
    __shared__ float h2[128];
    __shared__ float preds[BATCH];
    int t = threadIdx.x;
    for (int b = 0; b < BATCH; ++b) {
        const float* cls = hbuf + (size_t)(b * SEQ + XL + 1 + y1_lens[b]) * DMODEL;
        {
            float acc = db1[t];
            const float* w = dW1 + (size_t)t * DMODEL;
            for (int k = 0; k < DMODEL; ++k) acc = fmaf(cls[k], w[k], acc);
            h1[t] = fmaxf(acc, 0.f);
        }
        __syncthreads();
        if (t < 128) {
            float acc = db2[t];
            const float* w = dW2 + (size_t)t * 256;
            for (int k = 0; k < 256; ++k) acc = fmaf(h1[k], w[k], acc);
            h2[t] = fmaxf(acc, 0.f);
        }
        __syncthreads();
        if (t == 0) {
            float acc = db3[0];
            for (int k = 0; k < 128; ++k) acc = fmaf(h2[k], dW3[k], acc);
            preds[b] = acc;
        }
        __syncthreads();
    }
    if (t == 0) {
        float dl = 0.f;
        for (int b = 0; b < BATCH; ++b) {
            float tgt = (float)y2_lens[b] / (float)x2_lens[b];
            float e = preds[b] - tgt;
            float ae = fabsf(e);
            dl += (ae <= 1.f) ? 0.5f * e * e : (ae - 0.5f);
        }
        dl *= (1.f / BATCH);
        float token_loss = accum[0] / accum[1];
        float acc_v = accum[2] / fmaxf(accum[3], 1.f);
        out[0] = token_loss + dl;
        out[1] = acc_v;
    }
}

// ---------------- orchestration ----------------
extern "C" void kernel_launch(void* const* d_in, const int* in_sizes, int n_in,
                              void* d_out, int out_size, void* d_ws, size_t ws_size,
                              hipStream_t stream)
{
    const int*   x           = (const int*)d_in[0];
    const int*   x1_lens     = (const int*)d_in[1];
    const int*   x2_lens     = (const int*)d_in[2];
    const int*   y           = (const int*)d_in[3];
    const int*   y1_lens     = (const int*)d_in[4];
    const int*   y2_lens     = (const int*)d_in[5];
    const int*   y_mask      = (const int*)d_in[6];
    const float* emo_feature = (const float*)d_in[7];
    const float* text_emb    = (const float*)d_in[8];
    const float* audio_emb   = (const float*)d_in[9];
    const float* type_emb    = (const float*)d_in[10];
    const float* emo_W       = (const float*)d_in[11];
    const float* emo_b       = (const float*)d_in[12];
    const float* alpha_text  = (const float*)d_in[13];
    const float* alpha_audio = (const float*)d_in[14];
    const float* Wqkv        = (const float*)d_in[15];
    const float* bqkv        = (const float*)d_in[16];
    const float* Wo          = (const float*)d_in[17];
    const float* bo          = (const float*)d_in[18];
    const float* ln1_g       = (const float*)d_in[19];
    const float* ln1_b       = (const float*)d_in[20];
    const float* ln2_g       = (const float*)d_in[21];
    const float* ln2_b       = (const float*)d_in[22];
    const float* W1          = (const float*)d_in[23];
    const float* b1          = (const float*)d_in[24];
    const float* W2          = (const float*)d_in[25];
    const float* b2          = (const float*)d_in[26];
    const float* predict_W   = (const float*)d_in[27];
    const float* dW1         = (const float*)d_in[28];
    const float* db1         = (const float*)d_in[29];
    const float* dW2         = (const float*)d_in[30];
    const float* db2         = (const float*)d_in[31];
    const float* dW3         = (const float*)d_in[32];
    const float* db3         = (const float*)d_in[33];

    const int M = BATCH * SEQ;                       // 4612
    char* p = (char*)d_ws;
    float* hbuf   = (float*)p; p += 9445376;         // M*512*4
    float* delta  = (float*)p; p += 9445376;
    char*  uni    = p;         p += 18909440;        // max(ff1_bf, logits)
    u16*   hbuf_bf = (u16*)p;  p += 4722688;
    u16*   qkv_bf  = (u16*)p;  p += 14168064;
    u16*   obuf_bf = (u16*)p;  p += 4722688;
    u16*   wbf     = (u16*)p;  p += 19923968;
    u16*   ff1_bf  = (u16*)uni;
    float* logits  = (float*)uni;
    float* accum   = delta;                          // dead region by CE time

    u16* wq_bf = wbf;                                // 3*1536*512
    u16* wo_bf = wq_bf + 2359296;                    // 3*512*512
    u16* w1_bf = wo_bf + 786432;                     // 3*2048*512
    u16* w2_bf = w1_bf + 3145728;                    // 3*512*2048
    u16* wp_bf = w2_bf + 3145728;                    // 1025*512

    cvt5_kernel<<<1024, 256, 0, stream>>>(
        Wqkv, wq_bf, 2359296 / 4,
        Wo, wo_bf, 786432 / 4,
        W1, w1_bf, 3145728 / 4,
        W2, w2_bf, 3145728 / 4,
        predict_W, wp_bf, 524800 / 4);

    build_h_kernel<<<M, 256, 0, stream>>>(
        x, y, y_mask, emo_feature, text_emb, audio_emb, type_emb,
        emo_W, emo_b, alpha_text, alpha_audio, hbuf, hbuf_bf);

    const int MG = (M + 127) / 128;   // 37
    for (int l = 0; l < NLAYER; ++l) {
        gemm_bf16_kernel<<<dim3(12, MG), 256, 0, stream>>>(
            hbuf_bf, wq_bf + (size_t)l * 1536 * 512, bqkv + l * 1536,
            nullptr, qkv_bf, M, 1536, 512, 0);
        attn_mfma_kernel<<<dim3((SEQ + QBLK - 1) / QBLK, BATCH * NH), 256, 0, stream>>>(
            qkv_bf, x1_lens, x2_lens, y1_lens, y2_lens, y_mask, obuf_bf);
        gemm_bf16_kernel<<<dim3(4, MG), 256, 0, stream>>>(
            obuf_bf, wo_bf + (size_t)l * 512 * 512, bo + l * 512,
            delta, nullptr, M, 512, 512, 0);
        add_ln_kernel<<<M, 256, 0, stream>>>(hbuf, hbuf_bf, delta,
            ln1_g + l * DMODEL, ln1_b + l * DMODEL);
        gemm_bf16_kernel<<<dim3(16, MG), 256, 0, stream>>>(
            hbuf_bf, w1_bf + (size_t)l * 2048 * 512, b1 + l * 2048,
            nullptr, ff1_bf, M, 2048, 512, 1);
        gemm_bf16_kernel<<<dim3(4, MG), 256, 0, stream>>>(
            ff1_bf, w2_bf + (size_t)l * 512 * 2048, b2 + l * 512,
            delta, nullptr, M, 512, 2048, 0);
        add_ln_kernel<<<M, 256, 0, stream>>>(hbuf, hbuf_bf, delta,
            ln2_g + l * DMODEL, ln2_b + l * DMODEL);
    }

    gemm_bf16_kernel<<<dim3((OV + 127) / 128, MG), 256, 0, stream>>>(
        hbuf_bf, wp_bf, nullptr, logits, nullptr, M, OV, 512, 0);

    init_accum_kernel<<<1, 64, 0, stream>>>(accum);
    ce_kernel<<<BATCH * YL, 256, 0, stream>>>(logits, y, y_mask, accum);
    finalize_kernel<<<1, 256, 0, stream>>>(hbuf, y1_lens, y2_lens, x2_lens,
        dW1, db1, dW2, db2, dW3, db3, accum, (float*)d_out);
}

// Round 4
// 762.958 us; speedup vs baseline: 7.6060x; 1.0909x over previous
//
#include <hip/hip_runtime.h>
#include <hip/hip_bf16.h>
#include <math.h>

#define BATCH 4
#define XL 128
#define YL 1024
#define DMODEL 512
#define NH 8
#define NLAYER 3
#define DFF 2048
#define MASK_ID 1024
#define EOS_TOK 1024
#define HD 64
#define SEQ 1153          // XL + 1 + YL
#define OV 1025
#define NEGBIG (-1e9f)
#define QBLK 128
#define CCAP 2432         // max compacted masked rows (4*598 < 2432 = 19*128)

typedef unsigned short u16;
typedef short short8 __attribute__((ext_vector_type(8)));
typedef float f32x4 __attribute__((ext_vector_type(4)));

__device__ __forceinline__ u16 f2bf(float f) {
    union { float f; unsigned u; } v; v.f = f;
    unsigned r = v.u + 0x7fffu + ((v.u >> 16) & 1u);   // RNE
    return (u16)(r >> 16);
}
__device__ __forceinline__ float bf2f(u16 b) {
    union { unsigned u; float f; } v; v.u = ((unsigned)b) << 16;
    return v.f;
}

// ---------------- fused f32 -> bf16 convert for all 5 weight tensors ----------------
__global__ __launch_bounds__(256) void cvt5_kernel(
    const float* __restrict__ s0, u16* __restrict__ d0, int n0,
    const float* __restrict__ s1, u16* __restrict__ d1, int n1,
    const float* __restrict__ s2, u16* __restrict__ d2, int n2,
    const float* __restrict__ s3, u16* __restrict__ d3, int n3,
    const float* __restrict__ s4, u16* __restrict__ d4, int n4)
{
    int c0 = n0, c1 = c0 + n1, c2 = c1 + n2, c3 = c2 + n3, c4 = c3 + n4;
    for (int i = blockIdx.x * 256 + threadIdx.x; i < c4; i += gridDim.x * 256) {
        const float* s; u16* d; int j;
        if (i < c0)      { s = s0; d = d0; j = i; }
        else if (i < c1) { s = s1; d = d1; j = i - c0; }
        else if (i < c2) { s = s2; d = d2; j = i - c1; }
        else if (i < c3) { s = s3; d = d3; j = i - c2; }
        else             { s = s4; d = d4; j = i - c3; }
        float4 v = ((const float4*)s)[j];
        ushort4 o;
        o.x = f2bf(v.x); o.y = f2bf(v.y); o.z = f2bf(v.z); o.w = f2bf(v.w);
        ((ushort4*)d)[j] = o;
    }
}

// ---------------- sinusoid helper ----------------
__device__ __forceinline__ float pe_val(int pos, int d) {
    int i2 = d & ~1;
    float dv = expf((float)i2 * (-9.210340371976184f / (float)DMODEL));
    float ang = (float)pos * dv;
    return (d & 1) ? cosf(ang) : sinf(ang);
}

// ---------------- build h_input [B,S,D] (f32 + bf16 shadow) ----------------
__global__ __launch_bounds__(256) void build_h_kernel(
    const int* __restrict__ x, const int* __restrict__ y, const int* __restrict__ y_mask,
    const float* __restrict__ emo_feature, const float* __restrict__ text_emb,
    const float* __restrict__ audio_emb, const float* __restrict__ type_emb,
    const float* __restrict__ emo_W, const float* __restrict__ emo_b,
    const float* __restrict__ alpha_text, const float* __restrict__ alpha_audio,
    float* __restrict__ hbuf, u16* __restrict__ hbuf_bf)
{
    int bs = blockIdx.x;
    int b = bs / SEQ, s = bs % SEQ;
    float* out = hbuf + (size_t)bs * DMODEL;
    u16* outb = hbuf_bf + (size_t)bs * DMODEL;
    if (s == XL) {
        const float* f = emo_feature + b * 768;
        for (int d = threadIdx.x; d < DMODEL; d += 256) {
            const float* w = emo_W + (size_t)d * 768;
            float acc = 0.f;
            for (int k = 0; k < 768; ++k) acc = fmaf(f[k], w[k], acc);
            float v = acc + emo_b[d] + type_emb[DMODEL + d];
            out[d] = v; outb[d] = f2bf(v);
        }
    } else if (s < XL) {
        int tok = x[b * XL + s];
        float at = alpha_text[0];
        for (int d = threadIdx.x; d < DMODEL; d += 256) {
            float v = text_emb[(size_t)tok * DMODEL + d] + type_emb[d] + at * pe_val(s, d);
            out[d] = v; outb[d] = f2bf(v);
        }
    } else {
        int r = s - XL - 1;
        int tok = y_mask[b * YL + r] ? MASK_ID : y[b * YL + r];
        float aa = alpha_audio[0];
        for (int d = threadIdx.x; d < DMODEL; d += 256) {
            float v = audio_emb[(size_t)tok * DMODEL + d] + type_emb[2 * DMODEL + d] + aa * pe_val(r, d);
            out[d] = v; outb[d] = f2bf(v);
        }
    }
}

// ---------------- bf16 MFMA NT GEMM: C[m][n] = sum_k A[m][k]*B[n][k] (+bias, relu) ----
__global__ __launch_bounds__(256) void gemm_bf16_kernel(
    const u16* __restrict__ A, const u16* __restrict__ Bw,
    const float* __restrict__ bias,
    float* __restrict__ Cf, u16* __restrict__ Cb,
    int M, int N, int K, int relu)
{
    __shared__ u16 As[128 * 32];
    __shared__ u16 Bs[128 * 32];
    int tid = threadIdx.x;
    int w = tid >> 6, l = tid & 63;
    int m0 = blockIdx.y * 128, n0 = blockIdx.x * 128;
    int wm = (w >> 1) * 64, wn = (w & 1) * 64;

    f32x4 acc[4][4];
    #pragma unroll
    for (int i = 0; i < 4; ++i)
        #pragma unroll
        for (int j = 0; j < 4; ++j) acc[i][j] = (f32x4){0.f, 0.f, 0.f, 0.f};

    int srow0 = (w << 5) + (l >> 2);
    int skp = (l & 3) << 3;

    for (int k0 = 0; k0 < K; k0 += 32) {
        #pragma unroll
        for (int c = 0; c < 2; ++c) {
            int row = srow0 + c * 16;
            int am = m0 + row; if (am >= M) am = M - 1;
            int bn = n0 + row; if (bn >= N) bn = N - 1;
            __builtin_amdgcn_global_load_lds(
                (const __attribute__((address_space(1))) void*)(A + (size_t)am * K + k0 + skp),
                (__attribute__((address_space(3))) void*)(As + ((w * 2 + c) << 9)), 16, 0, 0);
            __builtin_amdgcn_global_load_lds(
                (const __attribute__((address_space(1))) void*)(Bw + (size_t)bn * K + k0 + skp),
                (__attribute__((address_space(3))) void*)(Bs + ((w * 2 + c) << 9)), 16, 0, 0);
        }
        __syncthreads();
        short8 af[4], bfr[4];
        #pragma unroll
        for (int i = 0; i < 4; ++i) {
            af[i]  = *(const short8*)(As + (wm + i * 16 + (l & 15)) * 32 + ((l >> 4) << 3));
            bfr[i] = *(const short8*)(Bs + (wn + i * 16 + (l & 15)) * 32 + ((l >> 4) << 3));
        }
        #pragma unroll
        for (int i = 0; i < 4; ++i)
            #pragma unroll
            for (int j = 0; j < 4; ++j)
                acc[i][j] = __builtin_amdgcn_mfma_f32_16x16x32_bf16(af[i], bfr[j], acc[i][j], 0, 0, 0);
        __syncthreads();
    }

    #pragma unroll
    for (int i = 0; i < 4; ++i) {
        #pragma unroll
        for (int j = 0; j < 4; ++j) {
            #pragma unroll
            for (int jj = 0; jj < 4; ++jj) {
                int row = m0 + wm + i * 16 + ((l >> 4) << 2) + jj;
                int col = n0 + wn + j * 16 + (l & 15);
                if (row < M && col < N) {
                    float v = acc[i][j][jj];
                    if (bias) v += bias[col];
                    if (relu) v = fmaxf(v, 0.f);
                    if (Cf) Cf[(size_t)row * N + col] = v;
                    if (Cb) Cb[(size_t)row * N + col] = f2bf(v);
                }
            }
        }
    }
}

// ---- dynamic-M variant (M in device memory, f32 out, no bias/relu) ----
__global__ __launch_bounds__(256) void gemm_bf16_dynm_kernel(
    const u16* __restrict__ A, const u16* __restrict__ Bw,
    const int* __restrict__ Mp, float* __restrict__ Cf, int N, int K)
{
    int M = *Mp;
    int m0 = blockIdx.y * 128;
    if (m0 >= M) return;
    __shared__ u16 As[128 * 32];
    __shared__ u16 Bs[128 * 32];
    int tid = threadIdx.x;
    int w = tid >> 6, l = tid & 63;
    int n0 = blockIdx.x * 128;
    int wm = (w >> 1) * 64, wn = (w & 1) * 64;

    f32x4 acc[4][4];
    #pragma unroll
    for (int i = 0; i < 4; ++i)
        #pragma unroll
        for (int j = 0; j < 4; ++j) acc[i][j] = (f32x4){0.f, 0.f, 0.f, 0.f};

    int srow0 = (w << 5) + (l >> 2);
    int skp = (l & 3) << 3;

    for (int k0 = 0; k0 < K; k0 += 32) {
        #pragma unroll
        for (int c = 0; c < 2; ++c) {
            int row = srow0 + c * 16;
            int am = m0 + row; if (am >= M) am = M - 1;
            int bn = n0 + row; if (bn >= N) bn = N - 1;
            __builtin_amdgcn_global_load_lds(
                (const __attribute__((address_space(1))) void*)(A + (size_t)am * K + k0 + skp),
                (__attribute__((address_space(3))) void*)(As + ((w * 2 + c) << 9)), 16, 0, 0);
            __builtin_amdgcn_global_load_lds(
                (const __attribute__((address_space(1))) void*)(Bw + (size_t)bn * K + k0 + skp),
                (__attribute__((address_space(3))) void*)(Bs + ((w * 2 + c) << 9)), 16, 0, 0);
        }
        __syncthreads();
        short8 af[4], bfr[4];
        #pragma unroll
        for (int i = 0; i < 4; ++i) {
            af[i]  = *(const short8*)(As + (wm + i * 16 + (l & 15)) * 32 + ((l >> 4) << 3));
            bfr[i] = *(const short8*)(Bs + (wn + i * 16 + (l & 15)) * 32 + ((l >> 4) << 3));
        }
        #pragma unroll
        for (int i = 0; i < 4; ++i)
            #pragma unroll
            for (int j = 0; j < 4; ++j)
                acc[i][j] = __builtin_amdgcn_mfma_f32_16x16x32_bf16(af[i], bfr[j], acc[i][j], 0, 0, 0);
        __syncthreads();
    }

    #pragma unroll
    for (int i = 0; i < 4; ++i) {
        #pragma unroll
        for (int j = 0; j < 4; ++j) {
            #pragma unroll
            for (int jj = 0; jj < 4; ++jj) {
                int row = m0 + wm + i * 16 + ((l >> 4) << 2) + jj;
                int col = n0 + wn + j * 16 + (l & 15);
                if (row < M && col < N)
                    Cf[(size_t)row * N + col] = acc[i][j][jj];
            }
        }
    }
}

// ---------------- MFMA flash attention, QBLK=128, mask-sparse k-loop ----------------
__global__ __launch_bounds__(256) void attn_mfma_kernel(
    const u16* __restrict__ qkv,
    const int* __restrict__ x1_lens, const int* __restrict__ x2_lens,
    const int* __restrict__ y1_lens, const int* __restrict__ y2_lens,
    const int* __restrict__ y_mask,
    u16* __restrict__ obuf)
{
    __shared__ u16 Ks[64 * 64];
    __shared__ u16 Vt[64 * 64];
    __shared__ u16 Ps[4][32 * 64];
    __shared__ unsigned char Am[1216];

    int tid = threadIdx.x;
    int w = tid >> 6, l = tid & 63;
    int bh = blockIdx.y;
    int b = bh >> 3, h = bh & 7;
    int q0 = blockIdx.x * QBLK;

    int x1 = x1_lens[b], xlen = x1 + 1 + x2_lens[b];
    int y1 = y1_lens[b], ylen = y1 + 1 + y2_lens[b];

    int kmax = -1;
    if (q0 < XL) kmax = max(kmax, xlen - 1);
    if (XL >= q0 && XL < q0 + QBLK) kmax = max(kmax, XL);
    {
        int ry0 = max(0, q0 - XL - 1);
        int ry1 = min(YL - 1, q0 + QBLK - 2 - XL);
        if (ry0 <= ry1) {
            if (ry0 <= y1 - 1) kmax = max(kmax, XL + y1);
            if (y1 >= ry0 && y1 <= ry1) kmax = max(kmax, XL + y1 + 1);
            int a = max(ry0, y1 + 1), bb = min(ry1, ylen - 1);
            if (a <= bb) kmax = max(kmax, XL + ylen);
        }
    }
    if (kmax < 0) return;
    int NKT = (kmax >> 6) + 1;

    for (int c = tid; c < 1216; c += 256) {
        unsigned v = 0;
        if (c < SEQ) {
            int ym = 0;
            if (c > XL) ym = y_mask[b * YL + c - XL - 1];
            bool a2c = (c == XL);
            bool ygt = (c > XL);
            bool aT0 = (c < x1);
            bool aT1 = (c >= x1) && (c < xlen);
            bool aT3 = aT0 || (ygt && c <= XL + y1);
            bool aT4 = (c < xlen) || a2c || (ygt && c <= XL + y1 + 1);
            bool aT5 = (((c < xlen) || a2c || (ygt && c <= XL + ylen)) && !ym);
            v = (aT0 ? 1u : 0u) | (aT1 ? 2u : 0u) | (a2c ? 4u : 0u) |
                (aT3 ? 8u : 0u) | (aT4 ? 16u : 0u) | (aT5 ? 32u : 0u);
        }
        Am[c] = (unsigned char)v;
    }

    short8 qf[2][2];
    #pragma unroll
    for (int qh = 0; qh < 2; ++qh) {
        int qr = q0 + w * 32 + qh * 16 + (l & 15);
        const u16* qp = qkv + (size_t)(b * SEQ + qr) * 1536 + h * 64 + ((l >> 4) << 3);
        #pragma unroll
        for (int kb = 0; kb < 2; ++kb) {
            short8 raw = *(const short8*)(qp + kb * 32);
            short8 s8;
            #pragma unroll
            for (int e = 0; e < 8; ++e)
                s8[e] = (short)f2bf(bf2f((u16)raw[e]) * 0.125f);
            qf[qh][kb] = s8;
        }
    }

    int rt[2][4];
    #pragma unroll
    for (int qh = 0; qh < 2; ++qh)
        #pragma unroll
        for (int j = 0; j < 4; ++j) {
            int qrj = q0 + w * 32 + qh * 16 + ((l >> 4) << 2) + j;
            int t;
            if (qrj < XL) t = (qrj < x1) ? 0 : 1;
            else if (qrj == XL) t = 2;
            else {
                int ry = qrj - XL - 1;
                t = (ry < y1) ? 3 : (ry == y1) ? 4 : (ry < ylen) ? 5 : 7;
            }
            rt[qh][j] = t;
        }

    f32x4 oacc[2][4];
    #pragma unroll
    for (int qh = 0; qh < 2; ++qh)
        #pragma unroll
        for (int db = 0; db < 4; ++db) oacc[qh][db] = (f32x4){0.f, 0.f, 0.f, 0.f};
    float mrun[2][4], lrun[2][4];
    #pragma unroll
    for (int qh = 0; qh < 2; ++qh)
        #pragma unroll
        for (int j = 0; j < 4; ++j) { mrun[qh][j] = -INFINITY; lrun[qh][j] = 0.f; }
    u16* Psw = &Ps[w][0];

    for (int kt = 0; kt < NKT; ++kt) {
        __syncthreads();
        {
            int r = tid >> 2, d0k = (tid & 3) << 4;
            int krc = min(kt * 64 + r, SEQ - 1);
            const u16* kp = qkv + (size_t)(b * SEQ + krc) * 1536 + 512 + h * 64 + d0k;
            short8 ka = *(const short8*)kp;
            short8 kb8 = *(const short8*)(kp + 8);
            int ksw = (r & 7) << 3;
            *(short8*)&Ks[r * 64 + (d0k ^ ksw)] = ka;
            *(short8*)&Ks[r * 64 + ((d0k + 8) ^ ksw)] = kb8;
        }
        {
            int rp = tid >> 3, o = tid & 7;
            int d0v = o * 8;
            int k0r = min(kt * 64 + 2 * rp, SEQ - 1);
            int k1r = min(kt * 64 + 2 * rp + 1, SEQ - 1);
            const u16* v0p = qkv + (size_t)(b * SEQ + k0r) * 1536 + 1024 + h * 64 + d0v;
            const u16* v1p = qkv + (size_t)(b * SEQ + k1r) * 1536 + 1024 + h * 64 + d0v;
            short8 va = *(const short8*)v0p;
            short8 vb = *(const short8*)v1p;
            #pragma unroll
            for (int e = 0; e < 8; ++e) {
                int d = d0v + e;
                unsigned val = (unsigned)(u16)va[e] | ((unsigned)(u16)vb[e] << 16);
                *(unsigned*)&Vt[d * 64 + ((2 * rp) ^ ((d & 7) << 3))] = val;
            }
        }
        __syncthreads();

        unsigned amv[4];
        #pragma unroll
        for (int cb = 0; cb < 4; ++cb)
            amv[cb] = Am[kt * 64 + cb * 16 + (l & 15)];

        f32x4 sc[2][4];
        #pragma unroll
        for (int cb = 0; cb < 4; ++cb) {
            int krw = cb * 16 + (l & 15);
            int ksw = (krw & 7) << 3;
            short8 k0 = *(const short8*)&Ks[krw * 64 + ((((l >> 4) << 3)) ^ ksw)];
            short8 k1 = *(const short8*)&Ks[krw * 64 + ((32 + ((l >> 4) << 3)) ^ ksw)];
            #pragma unroll
            for (int qh = 0; qh < 2; ++qh) {
                f32x4 z = (f32x4){0.f, 0.f, 0.f, 0.f};
                z = __builtin_amdgcn_mfma_f32_16x16x32_bf16(qf[qh][0], k0, z, 0, 0, 0);
                sc[qh][cb] = __builtin_amdgcn_mfma_f32_16x16x32_bf16(qf[qh][1], k1, z, 0, 0, 0);
            }
        }

        #pragma unroll
        for (int qh = 0; qh < 2; ++qh) {
            #pragma unroll
            for (int j = 0; j < 4; ++j) {
                int rtj = rt[qh][j];
                float s0 = ((amv[0] >> rtj) & 1u) ? sc[qh][0][j] : NEGBIG;
                float s1 = ((amv[1] >> rtj) & 1u) ? sc[qh][1][j] : NEGBIG;
                float s2 = ((amv[2] >> rtj) & 1u) ? sc[qh][2][j] : NEGBIG;
                float s3 = ((amv[3] >> rtj) & 1u) ? sc[qh][3][j] : NEGBIG;
                float tmax = fmaxf(fmaxf(s0, s1), fmaxf(s2, s3));
                tmax = fmaxf(tmax, __shfl_xor(tmax, 1));
                tmax = fmaxf(tmax, __shfl_xor(tmax, 2));
                tmax = fmaxf(tmax, __shfl_xor(tmax, 4));
                tmax = fmaxf(tmax, __shfl_xor(tmax, 8));
                float newm = fmaxf(mrun[qh][j], tmax);
                float corr = __expf(mrun[qh][j] - newm);
                float p0 = __expf(s0 - newm);
                float p1 = __expf(s1 - newm);
                float p2 = __expf(s2 - newm);
                float p3 = __expf(s3 - newm);
                float ps = p0 + p1 + p2 + p3;
                ps += __shfl_xor(ps, 1); ps += __shfl_xor(ps, 2);
                ps += __shfl_xor(ps, 4); ps += __shfl_xor(ps, 8);
                lrun[qh][j] = lrun[qh][j] * corr + ps;
                mrun[qh][j] = newm;
                #pragma unroll
                for (int db = 0; db < 4; ++db) oacc[qh][db][j] *= corr;
                int lr = qh * 16 + ((l >> 4) << 2) + j;
                int sw = (lr & 7) << 3;
                Psw[lr * 64 + ((0  + (l & 15)) ^ sw)] = f2bf(p0);
                Psw[lr * 64 + ((16 + (l & 15)) ^ sw)] = f2bf(p1);
                Psw[lr * 64 + ((32 + (l & 15)) ^ sw)] = f2bf(p2);
                Psw[lr * 64 + ((48 + (l & 15)) ^ sw)] = f2bf(p3);
            }
        }

        short8 pf[2][2];
        #pragma unroll
        for (int qh = 0; qh < 2; ++qh) {
            int pr = qh * 16 + (l & 15);
            int sw = (pr & 7) << 3;
            pf[qh][0] = *(const short8*)&Psw[pr * 64 + ((((l >> 4) << 3)) ^ sw)];
            pf[qh][1] = *(const short8*)&Psw[pr * 64 + ((32 + ((l >> 4) << 3)) ^ sw)];
        }
        #pragma unroll
        for (int db = 0; db < 4; ++db) {
            int vr = db * 16 + (l & 15);
            int vsw = (vr & 7) << 3;
            short8 v0 = *(const short8*)&Vt[vr * 64 + ((((l >> 4) << 3)) ^ vsw)];
            short8 v1 = *(const short8*)&Vt[vr * 64 + ((32 + ((l >> 4) << 3)) ^ vsw)];
            #pragma unroll
            for (int qh = 0; qh < 2; ++qh) {
                oacc[qh][db] = __builtin_amdgcn_mfma_f32_16x16x32_bf16(pf[qh][0], v0, oacc[qh][db], 0, 0, 0);
                oacc[qh][db] = __builtin_amdgcn_mfma_f32_16x16x32_bf16(pf[qh][1], v1, oacc[qh][db], 0, 0, 0);
            }
        }
    }

    #pragma unroll
    for (int qh = 0; qh < 2; ++qh) {
        float rl[4];
        #pragma unroll
        for (int j = 0; j < 4; ++j) rl[j] = 1.f / lrun[qh][j];
        #pragma unroll
        for (int db = 0; db < 4; ++db) {
            #pragma unroll
            for (int j = 0; j < 4; ++j) {
                int qrj = q0 + w * 32 + qh * 16 + ((l >> 4) << 2) + j;
                obuf[(size_t)(b * SEQ + qrj) * DMODEL + h * 64 + db * 16 + (l & 15)] =
                    f2bf(oacc[qh][db][j] * rl[j]);
            }
        }
    }
}

// ---------------- residual add + LayerNorm ----------------
__global__ __launch_bounds__(256) void add_ln_kernel(
    float* __restrict__ hbuf, u16* __restrict__ hbuf_bf, const float* __restrict__ delta,
    const float* __restrict__ g, const float* __restrict__ beta)
{
    __shared__ float red[4];
    int row = blockIdx.x, t = threadIdx.x;
    float* hp = hbuf + (size_t)row * DMODEL;
    u16* hb = hbuf_bf + (size_t)row * DMODEL;
    const float* dp = delta + (size_t)row * DMODEL;
    float v0 = hp[t] + dp[t];
    float v1 = hp[t + 256] + dp[t + 256];
    float s = v0 + v1;
    #pragma unroll
    for (int off = 32; off > 0; off >>= 1) s += __shfl_xor(s, off);
    if ((t & 63) == 0) red[t >> 6] = s;
    __syncthreads();
    float mu = (red[0] + red[1] + red[2] + red[3]) * (1.f / DMODEL);
    float d0 = v0 - mu, d1 = v1 - mu;
    float sq = d0 * d0 + d1 * d1;
    __syncthreads();
    #pragma unroll
    for (int off = 32; off > 0; off >>= 1) sq += __shfl_xor(sq, off);
    if ((t & 63) == 0) red[t >> 6] = sq;
    __syncthreads();
    float var = (red[0] + red[1] + red[2] + red[3]) * (1.f / DMODEL);
    float inv = 1.f / sqrtf(var + 1e-5f);
    float o0 = d0 * inv * g[t] + beta[t];
    float o1 = d1 * inv * g[t + 256] + beta[t + 256];
    hp[t] = o0; hp[t + 256] = o1;
    hb[t] = f2bf(o0); hb[t + 256] = f2bf(o1);
}

// ---------------- compaction of masked rows ----------------
__global__ __launch_bounds__(256) void init_accum_kernel(float* accum) {
    if (threadIdx.x < 8) accum[threadIdx.x] = 0.f;
}

__global__ __launch_bounds__(256) void compact_kernel(
    const int* __restrict__ y_mask, int* __restrict__ cnt, int* __restrict__ cmap)
{
    int i = blockIdx.x * 256 + threadIdx.x;
    if (i < BATCH * YL && y_mask[i]) {
        int pos = atomicAdd(cnt, 1);
        cmap[pos] = i;
    }
}

__global__ __launch_bounds__(256) void copy_rows_kernel(
    const int* __restrict__ cnt, const int* __restrict__ cmap,
    const u16* __restrict__ hbuf_bf, const int* __restrict__ y,
    u16* __restrict__ cbuf, int* __restrict__ ctgt)
{
    int i = blockIdx.x;
    if (i >= *cnt) return;
    int g = cmap[i];
    int b = g >> 10, r = g & 1023;
    const u16* src = hbuf_bf + (size_t)(b * SEQ + XL + 1 + r) * DMODEL;
    u16* dst = cbuf + (size_t)i * DMODEL;
    int t = threadIdx.x;
    ((ushort2*)dst)[t] = ((const ushort2*)src)[t];
    if (t == 0) ctgt[i] = y[g];
}

// ---------------- CE + top-3 over compacted rows ----------------
__global__ __launch_bounds__(256) void ce_kernel(
    const int* __restrict__ cnt, const float* __restrict__ logits,
    const int* __restrict__ ctgt, float* __restrict__ accum)
{
    int row = blockIdx.x;
    if (row >= *cnt) return;
    const float* lp = logits + (size_t)row * OV;
    int tgt = ctgt[row];
    int t = threadIdx.x;
    __shared__ float red[4];

    float lmax = -INFINITY;
    for (int i = t; i < OV; i += 256) lmax = fmaxf(lmax, lp[i]);
    #pragma unroll
    for (int off = 32; off > 0; off >>= 1) lmax = fmaxf(lmax, __shfl_xor(lmax, off));
    if ((t & 63) == 0) red[t >> 6] = lmax;
    __syncthreads();
    lmax = fmaxf(fmaxf(red[0], red[1]), fmaxf(red[2], red[3]));
    __syncthreads();

    float lsum = 0.f;
    for (int i = t; i < OV; i += 256) lsum += expf(lp[i] - lmax);
    #pragma unroll
    for (int off = 32; off > 0; off >>= 1) lsum += __shfl_xor(lsum, off);
    if ((t & 63) == 0) red[t >> 6] = lsum;
    __syncthreads();
    lsum = red[0] + red[1] + red[2] + red[3];
    __syncthreads();

    float lt = lp[tgt];
    float cntr = 0.f;
    for (int i = t; i < OV; i += 256) {
        float v = lp[i];
        if (v > lt || (v == lt && i < tgt)) cntr += 1.f;
    }
    #pragma unroll
    for (int off = 32; off > 0; off >>= 1) cntr += __shfl_xor(cntr, off);
    if ((t & 63) == 0) red[t >> 6] = cntr;
    __syncthreads();
    cntr = red[0] + red[1] + red[2] + red[3];

    if (t == 0) {
        float ce = -(lt - lmax - logf(lsum));
        float inc = (tgt != EOS_TOK) ? 1.f : 0.f;
        float corr = (cntr < 2.5f) ? 1.f : 0.f;
        atomicAdd(&accum[0], ce);
        atomicAdd(&accum[1], 1.f);
        atomicAdd(&accum[2], corr * inc);
        atomicAdd(&accum[3], inc);
    }
}

// ---------------- duration head: stage 1 (h1 = relu(cls@dW1.T+db1)) ----------------
// grid 32: block g -> b = g>>3, chunk = g&7 (32 rows each); 8 threads per row
__global__ __launch_bounds__(256) void dur1_kernel(
    const float* __restrict__ hbuf, const int* __restrict__ y1_lens,
    const float* __restrict__ dW1, const float* __restrict__ db1,
    float* __restrict__ h1buf)
{
    __shared__ float cls[DMODEL];
    int g = blockIdx.x;
    int b = g >> 3, c = g & 7;
    int t = threadIdx.x;
    const float* cp = hbuf + (size_t)(b * SEQ + XL + 1 + y1_lens[b]) * DMODEL;
    cls[t] = cp[t]; cls[t + 256] = cp[t + 256];
    __syncthreads();
    int row = c * 32 + (t >> 3);
    int ln = t & 7;
    const float* w = dW1 + (size_t)row * DMODEL + ln * 64;
    const float* cv = cls + ln * 64;
    float acc = 0.f;
    #pragma unroll 8
    for (int k = 0; k < 64; ++k) acc = fmaf(cv[k], w[k], acc);
    acc += __shfl_xor(acc, 1); acc += __shfl_xor(acc, 2); acc += __shfl_xor(acc, 4);
    if (ln == 0) h1buf[b * 256 + row] = fmaxf(acc + db1[row], 0.f);
}

// ---------------- duration head: stage 2 (h2, pred) ----------------
// grid 4 (one per batch)
__global__ __launch_bounds__(256) void dur2_kernel(
    const float* __restrict__ h1buf,
    const float* __restrict__ dW2, const float* __restrict__ db2,
    const float* __restrict__ dW3, const float* __restrict__ db3,
    float* __restrict__ preds)
{
    __shared__ float h1s[256];
    __shared__ float h2s[128];
    int b = blockIdx.x;
    int t = threadIdx.x;
    h1s[t] = h1buf[b * 256 + t];
    __syncthreads();
    if (t < 128) {
        float acc = db2[t];
        const float* w = dW2 + (size_t)t * 256;
        for (int k = 0; k < 256; ++k) acc = fmaf(h1s[k], w[k], acc);
        h2s[t] = fmaxf(acc, 0.f);
    }
    __syncthreads();
    if (t < 64) {
        float v = h2s[t] * dW3[t] + h2s[t + 64] * dW3[t + 64];
        #pragma unroll
        for (int off = 32; off > 0; off >>= 1) v += __shfl_xor(v, off);
        if (t == 0) preds[b] = v + db3[0];
    }
}

// ---------------- final scalar combine ----------------
__global__ __launch_bounds__(64) void final_kernel(
    const float* __restrict__ accum, const float* __restrict__ preds,
    const int* __restrict__ y2_lens, const int* __restrict__ x2_lens,
    float* __restrict__ out)
{
    if (threadIdx.x == 0) {
        float dl = 0.f;
        for (int b = 0; b < BATCH; ++b) {
            float tgt = (float)y2_lens[b] / (float)x2_lens[b];
            float e = preds[b] - tgt;
            float ae = fabsf(e);
            dl += (ae <= 1.f) ? 0.5f * e * e : (ae - 0.5f);
        }
        dl *= (1.f / BATCH);
        float token_loss = accum[0] / accum[1];
        float acc_v = accum[2] / fmaxf(accum[3], 1.f);
        out[0] = token_loss + dl;
        out[1] = acc_v;
    }
}

// ---------------- orchestration ----------------
extern "C" void kernel_launch(void* const* d_in, const int* in_sizes, int n_in,
                              void* d_out, int out_size, void* d_ws, size_t ws_size,
                              hipStream_t stream)
{
    const int*   x           = (const int*)d_in[0];
    const int*   x1_lens     = (const int*)d_in[1];
    const int*   x2_lens     = (const int*)d_in[2];
    const int*   y           = (const int*)d_in[3];
    const int*   y1_lens     = (const int*)d_in[4];
    const int*   y2_lens     = (const int*)d_in[5];
    const int*   y_mask      = (const int*)d_in[6];
    const float* emo_feature = (const float*)d_in[7];
    const float* text_emb    = (const float*)d_in[8];
    const float* audio_emb   = (const float*)d_in[9];
    const float* type_emb    = (const float*)d_in[10];
    const float* emo_W       = (const float*)d_in[11];
    const float* emo_b       = (const float*)d_in[12];
    const float* alpha_text  = (const float*)d_in[13];
    const float* alpha_audio = (const float*)d_in[14];
    const float* Wqkv        = (const float*)d_in[15];
    const float* bqkv        = (const float*)d_in[16];
    const float* Wo          = (const float*)d_in[17];
    const float* bo          = (const float*)d_in[18];
    const float* ln1_g       = (const float*)d_in[19];
    const float* ln1_b       = (const float*)d_in[20];
    const float* ln2_g       = (const float*)d_in[21];
    const float* ln2_b       = (const float*)d_in[22];
    const float* W1          = (const float*)d_in[23];
    const float* b1          = (const float*)d_in[24];
    const float* W2          = (const float*)d_in[25];
    const float* b2          = (const float*)d_in[26];
    const float* predict_W   = (const float*)d_in[27];
    const float* dW1         = (const float*)d_in[28];
    const float* db1         = (const float*)d_in[29];
    const float* dW2         = (const float*)d_in[30];
    const float* db2         = (const float*)d_in[31];
    const float* dW3         = (const float*)d_in[32];
    const float* db3         = (const float*)d_in[33];

    const int M = BATCH * SEQ;                       // 4612
    char* p = (char*)d_ws;
    float* hbuf   = (float*)p; p += 9445376;         // M*512*4
    float* delta  = (float*)p; p += 9445376;
    char*  uni    = p;         p += 18909440;        // max(ff1_bf, logits)
    u16*   hbuf_bf = (u16*)p;  p += 4722688;
    u16*   qkv_bf  = (u16*)p;  p += 14168064;
    u16*   obuf_bf = (u16*)p;  p += 4722688;
    u16*   wbf     = (u16*)p;  p += 19923968;
    u16*   cbuf    = (u16*)p;  p += (size_t)CCAP * DMODEL * 2;   // compacted rows
    u16*   ff1_bf  = (u16*)uni;
    float* logits  = (float*)uni;

    // small scratch carved from delta (dead after last add_ln)
    float* accum  = delta;                   // [0..3] ce sums, [4] cnt(int), [5..7] pad
    int*   cnt    = (int*)(delta + 4);
    float* preds  = delta + 8;               // [8..11]
    int*   cmap   = (int*)(delta + 16);      // CCAP ints
    int*   ctgt   = cmap + CCAP;             // CCAP ints
    float* h1buf  = (float*)(ctgt + CCAP);   // 4*256 floats

    u16* wq_bf = wbf;                                // 3*1536*512
    u16* wo_bf = wq_bf + 2359296;                    // 3*512*512
    u16* w1_bf = wo_bf + 786432;                     // 3*2048*512
    u16* w2_bf = w1_bf + 3145728;                    // 3*512*2048
    u16* wp_bf = w2_bf + 3145728;                    // 1025*512

    cvt5_kernel<<<1024, 256, 0, stream>>>(
        Wqkv, wq_bf, 2359296 / 4,
        Wo, wo_bf, 786432 / 4,
        W1, w1_bf, 3145728 / 4,
        W2, w2_bf, 3145728 / 4,
        predict_W, wp_bf, 524800 / 4);

    build_h_kernel<<<M, 256, 0, stream>>>(
        x, y, y_mask, emo_feature, text_emb, audio_emb, type_emb,
        emo_W, emo_b, alpha_text, alpha_audio, hbuf, hbuf_bf);

    const int MG = (M + 127) / 128;   // 37
    for (int l = 0; l < NLAYER; ++l) {
        gemm_bf16_kernel<<<dim3(12, MG), 256, 0, stream>>>(
            hbuf_bf, wq_bf + (size_t)l * 1536 * 512, bqkv + l * 1536,
            nullptr, qkv_bf, M, 1536, 512, 0);
        attn_mfma_kernel<<<dim3((SEQ + QBLK - 1) / QBLK, BATCH * NH), 256, 0, stream>>>(
            qkv_bf, x1_lens, x2_lens, y1_lens, y2_lens, y_mask, obuf_bf);
        gemm_bf16_kernel<<<dim3(4, MG), 256, 0, stream>>>(
            obuf_bf, wo_bf + (size_t)l * 512 * 512, bo + l * 512,
            delta, nullptr, M, 512, 512, 0);
        add_ln_kernel<<<M, 256, 0, stream>>>(hbuf, hbuf_bf, delta,
            ln1_g + l * DMODEL, ln1_b + l * DMODEL);
        gemm_bf16_kernel<<<dim3(16, MG), 256, 0, stream>>>(
            hbuf_bf, w1_bf + (size_t)l * 2048 * 512, b1 + l * 2048,
            nullptr, ff1_bf, M, 2048, 512, 1);
        gemm_bf16_kernel<<<dim3(4, MG), 256, 0, stream>>>(
            ff1_bf, w2_bf + (size_t)l * 512 * 2048, b2 + l * 512,
            delta, nullptr, M, 512, 2048, 0);
        add_ln_kernel<<<M, 256, 0, stream>>>(hbuf, hbuf_bf, delta,
            ln2_g + l * DMODEL, ln2_b + l * DMODEL);
    }

    // --- masked-row compaction + logits over compacted rows only ---
    init_accum_kernel<<<1, 64, 0, stream>>>(accum);
    compact_kernel<<<(BATCH * YL) / 256, 256, 0, stream>>>(y_mask, cnt, cmap);
    copy_rows_kernel<<<CCAP, 256, 0, stream>>>(cnt, cmap, hbuf_bf, y, cbuf, ctgt);
    gemm_bf16_dynm_kernel<<<dim3((OV + 127) / 128, CCAP / 128), 256, 0, stream>>>(
        cbuf, wp_bf, cnt, logits, OV, 512);
    ce_kernel<<<CCAP, 256, 0, stream>>>(cnt, logits, ctgt, accum);

    // --- duration head (parallelized) ---
    dur1_kernel<<<32, 256, 0, stream>>>(hbuf, y1_lens, dW1, db1, h1buf);
    dur2_kernel<<<4, 256, 0, stream>>>(h1buf, dW2, db2, dW3, db3, preds);
    final_kernel<<<1, 64, 0, stream>>>(accum, preds, y2_lens, x2_lens, (float*)d_out);
}

// Round 5
// 731.960 us; speedup vs baseline: 7.9281x; 1.0423x over previous
//
#include <hip/hip_runtime.h>
#include <hip/hip_bf16.h>
#include <math.h>

#define BATCH 4
#define XL 128
#define YL 1024
#define DMODEL 512
#define NH 8
#define NLAYER 3
#define DFF 2048
#define MASK_ID 1024
#define EOS_TOK 1024
#define HD 64
#define SEQ 1153          // XL + 1 + YL
#define OV 1025
#define NEGBIG (-1e9f)
#define QBLK 128
#define CCAP 2432         // max compacted masked rows

typedef unsigned short u16;
typedef short short8 __attribute__((ext_vector_type(8)));
typedef float f32x4 __attribute__((ext_vector_type(4)));

__device__ __forceinline__ u16 f2bf(float f) {
    union { float f; unsigned u; } v; v.f = f;
    unsigned r = v.u + 0x7fffu + ((v.u >> 16) & 1u);   // RNE
    return (u16)(r >> 16);
}
__device__ __forceinline__ float bf2f(u16 b) {
    union { unsigned u; float f; } v; v.u = ((unsigned)b) << 16;
    return v.f;
}

// ---------------- fused f32 -> bf16 convert for all 5 weight tensors ----------------
__global__ __launch_bounds__(256) void cvt5_kernel(
    const float* __restrict__ s0, u16* __restrict__ d0, int n0,
    const float* __restrict__ s1, u16* __restrict__ d1, int n1,
    const float* __restrict__ s2, u16* __restrict__ d2, int n2,
    const float* __restrict__ s3, u16* __restrict__ d3, int n3,
    const float* __restrict__ s4, u16* __restrict__ d4, int n4)
{
    int c0 = n0, c1 = c0 + n1, c2 = c1 + n2, c3 = c2 + n3, c4 = c3 + n4;
    for (int i = blockIdx.x * 256 + threadIdx.x; i < c4; i += gridDim.x * 256) {
        const float* s; u16* d; int j;
        if (i < c0)      { s = s0; d = d0; j = i; }
        else if (i < c1) { s = s1; d = d1; j = i - c0; }
        else if (i < c2) { s = s2; d = d2; j = i - c1; }
        else if (i < c3) { s = s3; d = d3; j = i - c2; }
        else             { s = s4; d = d4; j = i - c3; }
        float4 v = ((const float4*)s)[j];
        ushort4 o;
        o.x = f2bf(v.x); o.y = f2bf(v.y); o.z = f2bf(v.z); o.w = f2bf(v.w);
        ((ushort4*)d)[j] = o;
    }
}

// ---------------- emo rows: emo_feature @ emo_W.T + emo_b + type_emb[1] ----------------
// grid 32: b = blockIdx>>3, 64-output chunk = blockIdx&7; 4 lanes per output
__global__ __launch_bounds__(256) void emo_kernel(
    const float* __restrict__ emo_feature, const float* __restrict__ emo_W,
    const float* __restrict__ emo_b, const float* __restrict__ type_emb,
    float* __restrict__ hbuf, u16* __restrict__ hbuf_bf)
{
    int b = blockIdx.x >> 3, c = blockIdx.x & 7;
    int t = threadIdx.x;
    int osub = t >> 2, ln = t & 3;
    int d = c * 64 + osub;
    const float* f = emo_feature + b * 768 + ln * 192;
    const float* w = emo_W + (size_t)d * 768 + ln * 192;
    float acc = 0.f;
    #pragma unroll 4
    for (int k = 0; k < 192; ++k) acc = fmaf(f[k], w[k], acc);
    acc += __shfl_xor(acc, 1);
    acc += __shfl_xor(acc, 2);
    if (ln == 0) {
        float v = acc + emo_b[d] + type_emb[DMODEL + d];
        hbuf[(size_t)(b * SEQ + XL) * DMODEL + d] = v;
        hbuf_bf[(size_t)(b * SEQ + XL) * DMODEL + d] = f2bf(v);
    }
}

// ---------------- build h_input (x & y rows), wave-per-row, 8 d per lane ----------------
// grid 1153 blocks * 4 waves = 4612 rows
__global__ __launch_bounds__(256) void build_h_kernel(
    const int* __restrict__ x, const int* __restrict__ y, const int* __restrict__ y_mask,
    const float* __restrict__ text_emb, const float* __restrict__ audio_emb,
    const float* __restrict__ type_emb,
    const float* __restrict__ alpha_text, const float* __restrict__ alpha_audio,
    float* __restrict__ hbuf, u16* __restrict__ hbuf_bf)
{
    int row = blockIdx.x * 4 + (threadIdx.x >> 6);
    int l = threadIdx.x & 63;
    int b = row / SEQ, s = row % SEQ;
    if (s == XL) return;                       // emo_kernel owns this row
    int d0 = l * 8;

    const float* emb; const float* te; float alpha; int pos;
    if (s < XL) {
        int tok = x[b * XL + s];
        emb = text_emb + (size_t)tok * DMODEL;
        te = type_emb; alpha = alpha_text[0]; pos = s;
    } else {
        int r = s - XL - 1;
        int tok = y_mask[b * YL + r] ? MASK_ID : y[b * YL + r];
        emb = audio_emb + (size_t)tok * DMODEL;
        te = type_emb + 2 * DMODEL; alpha = alpha_audio[0]; pos = r;
    }

    float4 e0 = *(const float4*)(emb + d0);
    float4 e1 = *(const float4*)(emb + d0 + 4);
    float4 t0 = *(const float4*)(te + d0);
    float4 t1 = *(const float4*)(te + d0 + 4);
    float v[8] = {e0.x + t0.x, e0.y + t0.y, e0.z + t0.z, e0.w + t0.w,
                  e1.x + t1.x, e1.y + t1.y, e1.z + t1.z, e1.w + t1.w};
    float fp = (float)pos;
    #pragma unroll
    for (int p = 0; p < 4; ++p) {
        int d = d0 + 2 * p;
        float div = __expf((float)d * (-9.210340371976184f / (float)DMODEL));
        float sn, cs;
        __sincosf(fp * div, &sn, &cs);
        v[2 * p]     += alpha * sn;
        v[2 * p + 1] += alpha * cs;
    }

    float* hp = hbuf + (size_t)row * DMODEL + d0;
    *(float4*)hp       = make_float4(v[0], v[1], v[2], v[3]);
    *(float4*)(hp + 4) = make_float4(v[4], v[5], v[6], v[7]);
    short8 sv;
    #pragma unroll
    for (int e = 0; e < 8; ++e) sv[e] = (short)f2bf(v[e]);
    *(short8*)(hbuf_bf + (size_t)row * DMODEL + d0) = sv;
}

// ---------------- bf16 MFMA NT GEMM: C[m][n] = sum_k A[m][k]*B[n][k] (+bias, relu) ----
__global__ __launch_bounds__(256) void gemm_bf16_kernel(
    const u16* __restrict__ A, const u16* __restrict__ Bw,
    const float* __restrict__ bias,
    float* __restrict__ Cf, u16* __restrict__ Cb,
    int M, int N, int K, int relu)
{
    __shared__ u16 As[128 * 32];
    __shared__ u16 Bs[128 * 32];
    int tid = threadIdx.x;
    int w = tid >> 6, l = tid & 63;
    int m0 = blockIdx.y * 128, n0 = blockIdx.x * 128;
    int wm = (w >> 1) * 64, wn = (w & 1) * 64;

    f32x4 acc[4][4];
    #pragma unroll
    for (int i = 0; i < 4; ++i)
        #pragma unroll
        for (int j = 0; j < 4; ++j) acc[i][j] = (f32x4){0.f, 0.f, 0.f, 0.f};

    int srow0 = (w << 5) + (l >> 2);
    int skp = (l & 3) << 3;

    for (int k0 = 0; k0 < K; k0 += 32) {
        #pragma unroll
        for (int c = 0; c < 2; ++c) {
            int row = srow0 + c * 16;
            int am = m0 + row; if (am >= M) am = M - 1;
            int bn = n0 + row; if (bn >= N) bn = N - 1;
            __builtin_amdgcn_global_load_lds(
                (const __attribute__((address_space(1))) void*)(A + (size_t)am * K + k0 + skp),
                (__attribute__((address_space(3))) void*)(As + ((w * 2 + c) << 9)), 16, 0, 0);
            __builtin_amdgcn_global_load_lds(
                (const __attribute__((address_space(1))) void*)(Bw + (size_t)bn * K + k0 + skp),
                (__attribute__((address_space(3))) void*)(Bs + ((w * 2 + c) << 9)), 16, 0, 0);
        }
        __syncthreads();
        short8 af[4], bfr[4];
        #pragma unroll
        for (int i = 0; i < 4; ++i) {
            af[i]  = *(const short8*)(As + (wm + i * 16 + (l & 15)) * 32 + ((l >> 4) << 3));
            bfr[i] = *(const short8*)(Bs + (wn + i * 16 + (l & 15)) * 32 + ((l >> 4) << 3));
        }
        #pragma unroll
        for (int i = 0; i < 4; ++i)
            #pragma unroll
            for (int j = 0; j < 4; ++j)
                acc[i][j] = __builtin_amdgcn_mfma_f32_16x16x32_bf16(af[i], bfr[j], acc[i][j], 0, 0, 0);
        __syncthreads();
    }

    #pragma unroll
    for (int i = 0; i < 4; ++i) {
        #pragma unroll
        for (int j = 0; j < 4; ++j) {
            #pragma unroll
            for (int jj = 0; jj < 4; ++jj) {
                int row = m0 + wm + i * 16 + ((l >> 4) << 2) + jj;
                int col = n0 + wn + j * 16 + (l & 15);
                if (row < M && col < N) {
                    float v = acc[i][j][jj];
                    if (bias) v += bias[col];
                    if (relu) v = fmaxf(v, 0.f);
                    if (Cf) Cf[(size_t)row * N + col] = v;
                    if (Cb) Cb[(size_t)row * N + col] = f2bf(v);
                }
            }
        }
    }
}

// ---- dynamic-M variant (M in device memory, f32 out, no bias/relu) ----
__global__ __launch_bounds__(256) void gemm_bf16_dynm_kernel(
    const u16* __restrict__ A, const u16* __restrict__ Bw,
    const int* __restrict__ Mp, float* __restrict__ Cf, int N, int K)
{
    int M = *Mp;
    int m0 = blockIdx.y * 128;
    if (m0 >= M) return;
    __shared__ u16 As[128 * 32];
    __shared__ u16 Bs[128 * 32];
    int tid = threadIdx.x;
    int w = tid >> 6, l = tid & 63;
    int n0 = blockIdx.x * 128;
    int wm = (w >> 1) * 64, wn = (w & 1) * 64;

    f32x4 acc[4][4];
    #pragma unroll
    for (int i = 0; i < 4; ++i)
        #pragma unroll
        for (int j = 0; j < 4; ++j) acc[i][j] = (f32x4){0.f, 0.f, 0.f, 0.f};

    int srow0 = (w << 5) + (l >> 2);
    int skp = (l & 3) << 3;

    for (int k0 = 0; k0 < K; k0 += 32) {
        #pragma unroll
        for (int c = 0; c < 2; ++c) {
            int row = srow0 + c * 16;
            int am = m0 + row; if (am >= M) am = M - 1;
            int bn = n0 + row; if (bn >= N) bn = N - 1;
            __builtin_amdgcn_global_load_lds(
                (const __attribute__((address_space(1))) void*)(A + (size_t)am * K + k0 + skp),
                (__attribute__((address_space(3))) void*)(As + ((w * 2 + c) << 9)), 16, 0, 0);
            __builtin_amdgcn_global_load_lds(
                (const __attribute__((address_space(1))) void*)(Bw + (size_t)bn * K + k0 + skp),
                (__attribute__((address_space(3))) void*)(Bs + ((w * 2 + c) << 9)), 16, 0, 0);
        }
        __syncthreads();
        short8 af[4], bfr[4];
        #pragma unroll
        for (int i = 0; i < 4; ++i) {
            af[i]  = *(const short8*)(As + (wm + i * 16 + (l & 15)) * 32 + ((l >> 4) << 3));
            bfr[i] = *(const short8*)(Bs + (wn + i * 16 + (l & 15)) * 32 + ((l >> 4) << 3));
        }
        #pragma unroll
        for (int i = 0; i < 4; ++i)
            #pragma unroll
            for (int j = 0; j < 4; ++j)
                acc[i][j] = __builtin_amdgcn_mfma_f32_16x16x32_bf16(af[i], bfr[j], acc[i][j], 0, 0, 0);
        __syncthreads();
    }

    #pragma unroll
    for (int i = 0; i < 4; ++i) {
        #pragma unroll
        for (int j = 0; j < 4; ++j) {
            #pragma unroll
            for (int jj = 0; jj < 4; ++jj) {
                int row = m0 + wm + i * 16 + ((l >> 4) << 2) + jj;
                int col = n0 + wn + j * 16 + (l & 15);
                if (row < M && col < N)
                    Cf[(size_t)row * N + col] = acc[i][j][jj];
            }
        }
    }
}

// ---------------- MFMA flash attention, QBLK=128, mask-sparse k-loop ----------------
__global__ __launch_bounds__(256) void attn_mfma_kernel(
    const u16* __restrict__ qkv,
    const int* __restrict__ x1_lens, const int* __restrict__ x2_lens,
    const int* __restrict__ y1_lens, const int* __restrict__ y2_lens,
    const int* __restrict__ y_mask,
    u16* __restrict__ obuf)
{
    __shared__ u16 Ks[64 * 64];
    __shared__ u16 Vt[64 * 64];
    __shared__ u16 Ps[4][32 * 64];
    __shared__ unsigned char Am[1216];

    int tid = threadIdx.x;
    int w = tid >> 6, l = tid & 63;
    int bh = blockIdx.y;
    int b = bh >> 3, h = bh & 7;
    int q0 = blockIdx.x * QBLK;

    int x1 = x1_lens[b], xlen = x1 + 1 + x2_lens[b];
    int y1 = y1_lens[b], ylen = y1 + 1 + y2_lens[b];

    int kmax = -1;
    if (q0 < XL) kmax = max(kmax, xlen - 1);
    if (XL >= q0 && XL < q0 + QBLK) kmax = max(kmax, XL);
    {
        int ry0 = max(0, q0 - XL - 1);
        int ry1 = min(YL - 1, q0 + QBLK - 2 - XL);
        if (ry0 <= ry1) {
            if (ry0 <= y1 - 1) kmax = max(kmax, XL + y1);
            if (y1 >= ry0 && y1 <= ry1) kmax = max(kmax, XL + y1 + 1);
            int a = max(ry0, y1 + 1), bb = min(ry1, ylen - 1);
            if (a <= bb) kmax = max(kmax, XL + ylen);
        }
    }
    if (kmax < 0) return;
    int NKT = (kmax >> 6) + 1;

    for (int c = tid; c < 1216; c += 256) {
        unsigned v = 0;
        if (c < SEQ) {
            int ym = 0;
            if (c > XL) ym = y_mask[b * YL + c - XL - 1];
            bool a2c = (c == XL);
            bool ygt = (c > XL);
            bool aT0 = (c < x1);
            bool aT1 = (c >= x1) && (c < xlen);
            bool aT3 = aT0 || (ygt && c <= XL + y1);
            bool aT4 = (c < xlen) || a2c || (ygt && c <= XL + y1 + 1);
            bool aT5 = (((c < xlen) || a2c || (ygt && c <= XL + ylen)) && !ym);
            v = (aT0 ? 1u : 0u) | (aT1 ? 2u : 0u) | (a2c ? 4u : 0u) |
                (aT3 ? 8u : 0u) | (aT4 ? 16u : 0u) | (aT5 ? 32u : 0u);
        }
        Am[c] = (unsigned char)v;
    }

    short8 qf[2][2];
    #pragma unroll
    for (int qh = 0; qh < 2; ++qh) {
        int qr = q0 + w * 32 + qh * 16 + (l & 15);
        const u16* qp = qkv + (size_t)(b * SEQ + qr) * 1536 + h * 64 + ((l >> 4) << 3);
        #pragma unroll
        for (int kb = 0; kb < 2; ++kb) {
            short8 raw = *(const short8*)(qp + kb * 32);
            short8 s8;
            #pragma unroll
            for (int e = 0; e < 8; ++e)
                s8[e] = (short)f2bf(bf2f((u16)raw[e]) * 0.125f);
            qf[qh][kb] = s8;
        }
    }

    int rt[2][4];
    #pragma unroll
    for (int qh = 0; qh < 2; ++qh)
        #pragma unroll
        for (int j = 0; j < 4; ++j) {
            int qrj = q0 + w * 32 + qh * 16 + ((l >> 4) << 2) + j;
            int t;
            if (qrj < XL) t = (qrj < x1) ? 0 : 1;
            else if (qrj == XL) t = 2;
            else {
                int ry = qrj - XL - 1;
                t = (ry < y1) ? 3 : (ry == y1) ? 4 : (ry < ylen) ? 5 : 7;
            }
            rt[qh][j] = t;
        }

    f32x4 oacc[2][4];
    #pragma unroll
    for (int qh = 0; qh < 2; ++qh)
        #pragma unroll
        for (int db = 0; db < 4; ++db) oacc[qh][db] = (f32x4){0.f, 0.f, 0.f, 0.f};
    float mrun[2][4], lrun[2][4];
    #pragma unroll
    for (int qh = 0; qh < 2; ++qh)
        #pragma unroll
        for (int j = 0; j < 4; ++j) { mrun[qh][j] = -INFINITY; lrun[qh][j] = 0.f; }
    u16* Psw = &Ps[w][0];

    for (int kt = 0; kt < NKT; ++kt) {
        __syncthreads();
        {
            int r = tid >> 2, d0k = (tid & 3) << 4;
            int krc = min(kt * 64 + r, SEQ - 1);
            const u16* kp = qkv + (size_t)(b * SEQ + krc) * 1536 + 512 + h * 64 + d0k;
            short8 ka = *(const short8*)kp;
            short8 kb8 = *(const short8*)(kp + 8);
            int ksw = (r & 7) << 3;
            *(short8*)&Ks[r * 64 + (d0k ^ ksw)] = ka;
            *(short8*)&Ks[r * 64 + ((d0k + 8) ^ ksw)] = kb8;
        }
        {
            int rp = tid >> 3, o = tid & 7;
            int d0v = o * 8;
            int k0r = min(kt * 64 + 2 * rp, SEQ - 1);
            int k1r = min(kt * 64 + 2 * rp + 1, SEQ - 1);
            const u16* v0p = qkv + (size_t)(b * SEQ + k0r) * 1536 + 1024 + h * 64 + d0v;
            const u16* v1p = qkv + (size_t)(b * SEQ + k1r) * 1536 + 1024 + h * 64 + d0v;
            short8 va = *(const short8*)v0p;
            short8 vb = *(const short8*)v1p;
            #pragma unroll
            for (int e = 0; e < 8; ++e) {
                int d = d0v + e;
                unsigned val = (unsigned)(u16)va[e] | ((unsigned)(u16)vb[e] << 16);
                *(unsigned*)&Vt[d * 64 + ((2 * rp) ^ ((d & 7) << 3))] = val;
            }
        }
        __syncthreads();

        unsigned amv[4];
        #pragma unroll
        for (int cb = 0; cb < 4; ++cb)
            amv[cb] = Am[kt * 64 + cb * 16 + (l & 15)];

        f32x4 sc[2][4];
        #pragma unroll
        for (int cb = 0; cb < 4; ++cb) {
            int krw = cb * 16 + (l & 15);
            int ksw = (krw & 7) << 3;
            short8 k0 = *(const short8*)&Ks[krw * 64 + ((((l >> 4) << 3)) ^ ksw)];
            short8 k1 = *(const short8*)&Ks[krw * 64 + ((32 + ((l >> 4) << 3)) ^ ksw)];
            #pragma unroll
            for (int qh = 0; qh < 2; ++qh) {
                f32x4 z = (f32x4){0.f, 0.f, 0.f, 0.f};
                z = __builtin_amdgcn_mfma_f32_16x16x32_bf16(qf[qh][0], k0, z, 0, 0, 0);
                sc[qh][cb] = __builtin_amdgcn_mfma_f32_16x16x32_bf16(qf[qh][1], k1, z, 0, 0, 0);
            }
        }

        #pragma unroll
        for (int qh = 0; qh < 2; ++qh) {
            #pragma unroll
            for (int j = 0; j < 4; ++j) {
                int rtj = rt[qh][j];
                float s0 = ((amv[0] >> rtj) & 1u) ? sc[qh][0][j] : NEGBIG;
                float s1 = ((amv[1] >> rtj) & 1u) ? sc[qh][1][j] : NEGBIG;
                float s2 = ((amv[2] >> rtj) & 1u) ? sc[qh][2][j] : NEGBIG;
                float s3 = ((amv[3] >> rtj) & 1u) ? sc[qh][3][j] : NEGBIG;
                float tmax = fmaxf(fmaxf(s0, s1), fmaxf(s2, s3));
                tmax = fmaxf(tmax, __shfl_xor(tmax, 1));
                tmax = fmaxf(tmax, __shfl_xor(tmax, 2));
                tmax = fmaxf(tmax, __shfl_xor(tmax, 4));
                tmax = fmaxf(tmax, __shfl_xor(tmax, 8));
                float newm = fmaxf(mrun[qh][j], tmax);
                float corr = __expf(mrun[qh][j] - newm);
                float p0 = __expf(s0 - newm);
                float p1 = __expf(s1 - newm);
                float p2 = __expf(s2 - newm);
                float p3 = __expf(s3 - newm);
                float ps = p0 + p1 + p2 + p3;
                ps += __shfl_xor(ps, 1); ps += __shfl_xor(ps, 2);
                ps += __shfl_xor(ps, 4); ps += __shfl_xor(ps, 8);
                lrun[qh][j] = lrun[qh][j] * corr + ps;
                mrun[qh][j] = newm;
                #pragma unroll
                for (int db = 0; db < 4; ++db) oacc[qh][db][j] *= corr;
                int lr = qh * 16 + ((l >> 4) << 2) + j;
                int sw = (lr & 7) << 3;
                Psw[lr * 64 + ((0  + (l & 15)) ^ sw)] = f2bf(p0);
                Psw[lr * 64 + ((16 + (l & 15)) ^ sw)] = f2bf(p1);
                Psw[lr * 64 + ((32 + (l & 15)) ^ sw)] = f2bf(p2);
                Psw[lr * 64 + ((48 + (l & 15)) ^ sw)] = f2bf(p3);
            }
        }

        short8 pf[2][2];
        #pragma unroll
        for (int qh = 0; qh < 2; ++qh) {
            int pr = qh * 16 + (l & 15);
            int sw = (pr & 7) << 3;
            pf[qh][0] = *(const short8*)&Psw[pr * 64 + ((((l >> 4) << 3)) ^ sw)];
            pf[qh][1] = *(const short8*)&Psw[pr * 64 + ((32 + ((l >> 4) << 3)) ^ sw)];
        }
        #pragma unroll
        for (int db = 0; db < 4; ++db) {
            int vr = db * 16 + (l & 15);
            int vsw = (vr & 7) << 3;
            short8 v0 = *(const short8*)&Vt[vr * 64 + ((((l >> 4) << 3)) ^ vsw)];
            short8 v1 = *(const short8*)&Vt[vr * 64 + ((32 + ((l >> 4) << 3)) ^ vsw)];
            #pragma unroll
            for (int qh = 0; qh < 2; ++qh) {
                oacc[qh][db] = __builtin_amdgcn_mfma_f32_16x16x32_bf16(pf[qh][0], v0, oacc[qh][db], 0, 0, 0);
                oacc[qh][db] = __builtin_amdgcn_mfma_f32_16x16x32_bf16(pf[qh][1], v1, oacc[qh][db], 0, 0, 0);
            }
        }
    }

    #pragma unroll
    for (int qh = 0; qh < 2; ++qh) {
        float rl[4];
        #pragma unroll
        for (int j = 0; j < 4; ++j) rl[j] = 1.f / lrun[qh][j];
        #pragma unroll
        for (int db = 0; db < 4; ++db) {
            #pragma unroll
            for (int j = 0; j < 4; ++j) {
                int qrj = q0 + w * 32 + qh * 16 + ((l >> 4) << 2) + j;
                obuf[(size_t)(b * SEQ + qrj) * DMODEL + h * 64 + db * 16 + (l & 15)] =
                    f2bf(oacc[qh][db][j] * rl[j]);
            }
        }
    }
}

// ---------------- residual add + LayerNorm, wave-per-row (4 rows/block) ----------------
__global__ __launch_bounds__(256) void add_ln_kernel(
    float* __restrict__ hbuf, u16* __restrict__ hbuf_bf, const float* __restrict__ delta,
    const float* __restrict__ g, const float* __restrict__ beta)
{
    int row = blockIdx.x * 4 + (threadIdx.x >> 6);
    int l = threadIdx.x & 63;
    int d0 = l * 8;
    float* hp = hbuf + (size_t)row * DMODEL + d0;
    const float* dp = delta + (size_t)row * DMODEL + d0;
    float4 a0 = *(const float4*)hp, a1 = *(const float4*)(hp + 4);
    float4 b0 = *(const float4*)dp, b1 = *(const float4*)(dp + 4);
    float v[8] = {a0.x + b0.x, a0.y + b0.y, a0.z + b0.z, a0.w + b0.w,
                  a1.x + b1.x, a1.y + b1.y, a1.z + b1.z, a1.w + b1.w};
    float s = 0.f;
    #pragma unroll
    for (int e = 0; e < 8; ++e) s += v[e];
    #pragma unroll
    for (int off = 32; off > 0; off >>= 1) s += __shfl_xor(s, off);
    float mu = s * (1.f / DMODEL);
    float sq = 0.f;
    #pragma unroll
    for (int e = 0; e < 8; ++e) { v[e] -= mu; sq += v[e] * v[e]; }
    #pragma unroll
    for (int off = 32; off > 0; off >>= 1) sq += __shfl_xor(sq, off);
    float inv = 1.f / sqrtf(sq * (1.f / DMODEL) + 1e-5f);
    float4 g0 = *(const float4*)(g + d0), g1 = *(const float4*)(g + d0 + 4);
    float4 be0 = *(const float4*)(beta + d0), be1 = *(const float4*)(beta + d0 + 4);
    float o[8];
    o[0] = v[0] * inv * g0.x + be0.x; o[1] = v[1] * inv * g0.y + be0.y;
    o[2] = v[2] * inv * g0.z + be0.z; o[3] = v[3] * inv * g0.w + be0.w;
    o[4] = v[4] * inv * g1.x + be1.x; o[5] = v[5] * inv * g1.y + be1.y;
    o[6] = v[6] * inv * g1.z + be1.z; o[7] = v[7] * inv * g1.w + be1.w;
    *(float4*)hp       = make_float4(o[0], o[1], o[2], o[3]);
    *(float4*)(hp + 4) = make_float4(o[4], o[5], o[6], o[7]);
    short8 sv;
    #pragma unroll
    for (int e = 0; e < 8; ++e) sv[e] = (short)f2bf(o[e]);
    *(short8*)(hbuf_bf + (size_t)row * DMODEL + d0) = sv;
}

// ---------------- compaction of masked rows ----------------
__global__ __launch_bounds__(256) void init_accum_kernel(float* accum) {
    if (threadIdx.x < 8) accum[threadIdx.x] = 0.f;
}

__global__ __launch_bounds__(256) void compact_kernel(
    const int* __restrict__ y_mask, int* __restrict__ cnt, int* __restrict__ cmap)
{
    int i = blockIdx.x * 256 + threadIdx.x;
    if (i < BATCH * YL && y_mask[i]) {
        int pos = atomicAdd(cnt, 1);
        cmap[pos] = i;
    }
}

__global__ __launch_bounds__(256) void copy_rows_kernel(
    const int* __restrict__ cnt, const int* __restrict__ cmap,
    const u16* __restrict__ hbuf_bf, const int* __restrict__ y,
    u16* __restrict__ cbuf, int* __restrict__ ctgt)
{
    int i = blockIdx.x;
    if (i >= *cnt) return;
    int g = cmap[i];
    int b = g >> 10, r = g & 1023;
    const u16* src = hbuf_bf + (size_t)(b * SEQ + XL + 1 + r) * DMODEL;
    u16* dst = cbuf + (size_t)i * DMODEL;
    int t = threadIdx.x;
    ((ushort2*)dst)[t] = ((const ushort2*)src)[t];
    if (t == 0) ctgt[i] = y[g];
}

// ---------------- CE + top-3 over compacted rows ----------------
__global__ __launch_bounds__(256) void ce_kernel(
    const int* __restrict__ cnt, const float* __restrict__ logits,
    const int* __restrict__ ctgt, float* __restrict__ accum)
{
    int row = blockIdx.x;
    if (row >= *cnt) return;
    const float* lp = logits + (size_t)row * OV;
    int tgt = ctgt[row];
    int t = threadIdx.x;
    __shared__ float red[4];

    float lmax = -INFINITY;
    for (int i = t; i < OV; i += 256) lmax = fmaxf(lmax, lp[i]);
    #pragma unroll
    for (int off = 32; off > 0; off >>= 1) lmax = fmaxf(lmax, __shfl_xor(lmax, off));
    if ((t & 63) == 0) red[t >> 6] = lmax;
    __syncthreads();
    lmax = fmaxf(fmaxf(red[0], red[1]), fmaxf(red[2], red[3]));
    __syncthreads();

    float lsum = 0.f;
    for (int i = t; i < OV; i += 256) lsum += expf(lp[i] - lmax);
    #pragma unroll
    for (int off = 32; off > 0; off >>= 1) lsum += __shfl_xor(lsum, off);
    if ((t & 63) == 0) red[t >> 6] = lsum;
    __syncthreads();
    lsum = red[0] + red[1] + red[2] + red[3];
    __syncthreads();

    float lt = lp[tgt];
    float cntr = 0.f;
    for (int i = t; i < OV; i += 256) {
        float v = lp[i];
        if (v > lt || (v == lt && i < tgt)) cntr += 1.f;
    }
    #pragma unroll
    for (int off = 32; off > 0; off >>= 1) cntr += __shfl_xor(cntr, off);
    if ((t & 63) == 0) red[t >> 6] = cntr;
    __syncthreads();
    cntr = red[0] + red[1] + red[2] + red[3];

    if (t == 0) {
        float ce = -(lt - lmax - logf(lsum));
        float inc = (tgt != EOS_TOK) ? 1.f : 0.f;
        float corr = (cntr < 2.5f) ? 1.f : 0.f;
        atomicAdd(&accum[0], ce);
        atomicAdd(&accum[1], 1.f);
        atomicAdd(&accum[2], corr * inc);
        atomicAdd(&accum[3], inc);
    }
}

// ---------------- duration head ----------------
__global__ __launch_bounds__(256) void dur1_kernel(
    const float* __restrict__ hbuf, const int* __restrict__ y1_lens,
    const float* __restrict__ dW1, const float* __restrict__ db1,
    float* __restrict__ h1buf)
{
    __shared__ float cls[DMODEL];
    int g = blockIdx.x;
    int b = g >> 3, c = g & 7;
    int t = threadIdx.x;
    const float* cp = hbuf + (size_t)(b * SEQ + XL + 1 + y1_lens[b]) * DMODEL;
    cls[t] = cp[t]; cls[t + 256] = cp[t + 256];
    __syncthreads();
    int row = c * 32 + (t >> 3);
    int ln = t & 7;
    const float* w = dW1 + (size_t)row * DMODEL + ln * 64;
    const float* cv = cls + ln * 64;
    float acc = 0.f;
    #pragma unroll 8
    for (int k = 0; k < 64; ++k) acc = fmaf(cv[k], w[k], acc);
    acc += __shfl_xor(acc, 1); acc += __shfl_xor(acc, 2); acc += __shfl_xor(acc, 4);
    if (ln == 0) h1buf[b * 256 + row] = fmaxf(acc + db1[row], 0.f);
}

__global__ __launch_bounds__(256) void dur2_kernel(
    const float* __restrict__ h1buf,
    const float* __restrict__ dW2, const float* __restrict__ db2,
    const float* __restrict__ dW3, const float* __restrict__ db3,
    float* __restrict__ preds)
{
    __shared__ float h1s[256];
    __shared__ float h2s[128];
    int b = blockIdx.x;
    int t = threadIdx.x;
    h1s[t] = h1buf[b * 256 + t];
    __syncthreads();
    if (t < 128) {
        float acc = db2[t];
        const float* w = dW2 + (size_t)t * 256;
        for (int k = 0; k < 256; ++k) acc = fmaf(h1s[k], w[k], acc);
        h2s[t] = fmaxf(acc, 0.f);
    }
    __syncthreads();
    if (t < 64) {
        float v = h2s[t] * dW3[t] + h2s[t + 64] * dW3[t + 64];
        #pragma unroll
        for (int off = 32; off > 0; off >>= 1) v += __shfl_xor(v, off);
        if (t == 0) preds[b] = v + db3[0];
    }
}

__global__ __launch_bounds__(64) void final_kernel(
    const float* __restrict__ accum, const float* __restrict__ preds,
    const int* __restrict__ y2_lens, const int* __restrict__ x2_lens,
    float* __restrict__ out)
{
    if (threadIdx.x == 0) {
        float dl = 0.f;
        for (int b = 0; b < BATCH; ++b) {
            float tgt = (float)y2_lens[b] / (float)x2_lens[b];
            float e = preds[b] - tgt;
            float ae = fabsf(e);
            dl += (ae <= 1.f) ? 0.5f * e * e : (ae - 0.5f);
        }
        dl *= (1.f / BATCH);
        float token_loss = accum[0] / accum[1];
        float acc_v = accum[2] / fmaxf(accum[3], 1.f);
        out[0] = token_loss + dl;
        out[1] = acc_v;
    }
}

// ---------------- orchestration ----------------
extern "C" void kernel_launch(void* const* d_in, const int* in_sizes, int n_in,
                              void* d_out, int out_size, void* d_ws, size_t ws_size,
                              hipStream_t stream)
{
    const int*   x           = (const int*)d_in[0];
    const int*   x1_lens     = (const int*)d_in[1];
    const int*   x2_lens     = (const int*)d_in[2];
    const int*   y           = (const int*)d_in[3];
    const int*   y1_lens     = (const int*)d_in[4];
    const int*   y2_lens     = (const int*)d_in[5];
    const int*   y_mask      = (const int*)d_in[6];
    const float* emo_feature = (const float*)d_in[7];
    const float* text_emb    = (const float*)d_in[8];
    const float* audio_emb   = (const float*)d_in[9];
    const float* type_emb    = (const float*)d_in[10];
    const float* emo_W       = (const float*)d_in[11];
    const float* emo_b       = (const float*)d_in[12];
    const float* alpha_text  = (const float*)d_in[13];
    const float* alpha_audio = (const float*)d_in[14];
    const float* Wqkv        = (const float*)d_in[15];
    const float* bqkv        = (const float*)d_in[16];
    const float* Wo          = (const float*)d_in[17];
    const float* bo          = (const float*)d_in[18];
    const float* ln1_g       = (const float*)d_in[19];
    const float* ln1_b       = (const float*)d_in[20];
    const float* ln2_g       = (const float*)d_in[21];
    const float* ln2_b       = (const float*)d_in[22];
    const float* W1          = (const float*)d_in[23];
    const float* b1          = (const float*)d_in[24];
    const float* W2          = (const float*)d_in[25];
    const float* b2          = (const float*)d_in[26];
    const float* predict_W   = (const float*)d_in[27];
    const float* dW1         = (const float*)d_in[28];
    const float* db1         = (const float*)d_in[29];
    const float* dW2         = (const float*)d_in[30];
    const float* db2         = (const float*)d_in[31];
    const float* dW3         = (const float*)d_in[32];
    const float* db3         = (const float*)d_in[33];

    const int M = BATCH * SEQ;                       // 4612
    char* p = (char*)d_ws;
    float* hbuf   = (float*)p; p += 9445376;         // M*512*4
    float* delta  = (float*)p; p += 9445376;
    char*  uni    = p;         p += 18909440;        // max(ff1_bf, logits)
    u16*   hbuf_bf = (u16*)p;  p += 4722688;
    u16*   qkv_bf  = (u16*)p;  p += 14168064;
    u16*   obuf_bf = (u16*)p;  p += 4722688;
    u16*   wbf     = (u16*)p;  p += 19923968;
    u16*   cbuf    = (u16*)p;  p += (size_t)CCAP * DMODEL * 2;   // compacted rows
    u16*   ff1_bf  = (u16*)uni;
    float* logits  = (float*)uni;

    float* accum  = delta;
    int*   cnt    = (int*)(delta + 4);
    float* preds  = delta + 8;
    int*   cmap   = (int*)(delta + 16);
    int*   ctgt   = cmap + CCAP;
    float* h1buf  = (float*)(ctgt + CCAP);

    u16* wq_bf = wbf;                                // 3*1536*512
    u16* wo_bf = wq_bf + 2359296;                    // 3*512*512
    u16* w1_bf = wo_bf + 786432;                     // 3*2048*512
    u16* w2_bf = w1_bf + 3145728;                    // 3*512*2048
    u16* wp_bf = w2_bf + 3145728;                    // 1025*512

    cvt5_kernel<<<1024, 256, 0, stream>>>(
        Wqkv, wq_bf, 2359296 / 4,
        Wo, wo_bf, 786432 / 4,
        W1, w1_bf, 3145728 / 4,
        W2, w2_bf, 3145728 / 4,
        predict_W, wp_bf, 524800 / 4);

    emo_kernel<<<32, 256, 0, stream>>>(emo_feature, emo_W, emo_b, type_emb, hbuf, hbuf_bf);
    build_h_kernel<<<M / 4, 256, 0, stream>>>(
        x, y, y_mask, text_emb, audio_emb, type_emb,
        alpha_text, alpha_audio, hbuf, hbuf_bf);

    const int MG = (M + 127) / 128;   // 37
    for (int l = 0; l < NLAYER; ++l) {
        gemm_bf16_kernel<<<dim3(12, MG), 256, 0, stream>>>(
            hbuf_bf, wq_bf + (size_t)l * 1536 * 512, bqkv + l * 1536,
            nullptr, qkv_bf, M, 1536, 512, 0);
        attn_mfma_kernel<<<dim3((SEQ + QBLK - 1) / QBLK, BATCH * NH), 256, 0, stream>>>(
            qkv_bf, x1_lens, x2_lens, y1_lens, y2_lens, y_mask, obuf_bf);
        gemm_bf16_kernel<<<dim3(4, MG), 256, 0, stream>>>(
            obuf_bf, wo_bf + (size_t)l * 512 * 512, bo + l * 512,
            delta, nullptr, M, 512, 512, 0);
        add_ln_kernel<<<M / 4, 256, 0, stream>>>(hbuf, hbuf_bf, delta,
            ln1_g + l * DMODEL, ln1_b + l * DMODEL);
        gemm_bf16_kernel<<<dim3(16, MG), 256, 0, stream>>>(
            hbuf_bf, w1_bf + (size_t)l * 2048 * 512, b1 + l * 2048,
            nullptr, ff1_bf, M, 2048, 512, 1);
        gemm_bf16_kernel<<<dim3(4, MG), 256, 0, stream>>>(
            ff1_bf, w2_bf + (size_t)l * 512 * 2048, b2 + l * 512,
            delta, nullptr, M, 512, 2048, 0);
        add_ln_kernel<<<M / 4, 256, 0, stream>>>(hbuf, hbuf_bf, delta,
            ln2_g + l * DMODEL, ln2_b + l * DMODEL);
    }

    init_accum_kernel<<<1, 64, 0, stream>>>(accum);
    compact_kernel<<<(BATCH * YL) / 256, 256, 0, stream>>>(y_mask, cnt, cmap);
    copy_rows_kernel<<<CCAP, 256, 0, stream>>>(cnt, cmap, hbuf_bf, y, cbuf, ctgt);
    gemm_bf16_dynm_kernel<<<dim3((OV + 127) / 128, CCAP / 128), 256, 0, stream>>>(
        cbuf, wp_bf, cnt, logits, OV, 512);
    ce_kernel<<<CCAP, 256, 0, stream>>>(cnt, logits, ctgt, accum);

    dur1_kernel<<<32, 256, 0, stream>>>(hbuf, y1_lens, dW1, db1, h1buf);
    dur2_kernel<<<4, 256, 0, stream>>>(h1buf, dW2, db2, dW3, db3, preds);
    final_kernel<<<1, 64, 0, stream>>>(accum, preds, y2_lens, x2_lens, (float*)d_out);
}

// Round 6
// 610.805 us; speedup vs baseline: 9.5007x; 1.1984x over previous
//
#include <hip/hip_runtime.h>
#include <hip/hip_bf16.h>
#include <math.h>

#define BATCH 4
#define XL 128
#define YL 1024
#define DMODEL 512
#define NH 8
#define NLAYER 3
#define DFF 2048
#define MASK_ID 1024
#define EOS_TOK 1024
#define HD 64
#define SEQ 1153          // XL + 1 + YL
#define OV 1025
#define NEGBIG (-1e9f)
#define QBLK 128
#define CCAP 2432         // max compacted masked rows

typedef unsigned short u16;
typedef short short8 __attribute__((ext_vector_type(8)));
typedef float f32x4 __attribute__((ext_vector_type(4)));

__device__ __forceinline__ u16 f2bf(float f) {
    union { float f; unsigned u; } v; v.f = f;
    unsigned r = v.u + 0x7fffu + ((v.u >> 16) & 1u);   // RNE
    return (u16)(r >> 16);
}
__device__ __forceinline__ float bf2f(u16 b) {
    union { unsigned u; float f; } v; v.u = ((unsigned)b) << 16;
    return v.f;
}

// ---------------- fused f32 -> bf16 convert for all 5 weight tensors ----------------
__global__ __launch_bounds__(256) void cvt5_kernel(
    const float* __restrict__ s0, u16* __restrict__ d0, int n0,
    const float* __restrict__ s1, u16* __restrict__ d1, int n1,
    const float* __restrict__ s2, u16* __restrict__ d2, int n2,
    const float* __restrict__ s3, u16* __restrict__ d3, int n3,
    const float* __restrict__ s4, u16* __restrict__ d4, int n4)
{
    int c0 = n0, c1 = c0 + n1, c2 = c1 + n2, c3 = c2 + n3, c4 = c3 + n4;
    for (int i = blockIdx.x * 256 + threadIdx.x; i < c4; i += gridDim.x * 256) {
        const float* s; u16* d; int j;
        if (i < c0)      { s = s0; d = d0; j = i; }
        else if (i < c1) { s = s1; d = d1; j = i - c0; }
        else if (i < c2) { s = s2; d = d2; j = i - c1; }
        else if (i < c3) { s = s3; d = d3; j = i - c2; }
        else             { s = s4; d = d4; j = i - c3; }
        float4 v = ((const float4*)s)[j];
        ushort4 o;
        o.x = f2bf(v.x); o.y = f2bf(v.y); o.z = f2bf(v.z); o.w = f2bf(v.w);
        ((ushort4*)d)[j] = o;
    }
}

// ---------------- emo rows ----------------
__global__ __launch_bounds__(256) void emo_kernel(
    const float* __restrict__ emo_feature, const float* __restrict__ emo_W,
    const float* __restrict__ emo_b, const float* __restrict__ type_emb,
    float* __restrict__ hbuf, u16* __restrict__ hbuf_bf)
{
    int b = blockIdx.x >> 3, c = blockIdx.x & 7;
    int t = threadIdx.x;
    int osub = t >> 2, ln = t & 3;
    int d = c * 64 + osub;
    const float* f = emo_feature + b * 768 + ln * 192;
    const float* w = emo_W + (size_t)d * 768 + ln * 192;
    float acc = 0.f;
    #pragma unroll 4
    for (int k = 0; k < 192; ++k) acc = fmaf(f[k], w[k], acc);
    acc += __shfl_xor(acc, 1);
    acc += __shfl_xor(acc, 2);
    if (ln == 0) {
        float v = acc + emo_b[d] + type_emb[DMODEL + d];
        hbuf[(size_t)(b * SEQ + XL) * DMODEL + d] = v;
        hbuf_bf[(size_t)(b * SEQ + XL) * DMODEL + d] = f2bf(v);
    }
}

// ---------------- build h_input (x & y rows), wave-per-row ----------------
__global__ __launch_bounds__(256) void build_h_kernel(
    const int* __restrict__ x, const int* __restrict__ y, const int* __restrict__ y_mask,
    const float* __restrict__ text_emb, const float* __restrict__ audio_emb,
    const float* __restrict__ type_emb,
    const float* __restrict__ alpha_text, const float* __restrict__ alpha_audio,
    float* __restrict__ hbuf, u16* __restrict__ hbuf_bf)
{
    int row = blockIdx.x * 4 + (threadIdx.x >> 6);
    int l = threadIdx.x & 63;
    int b = row / SEQ, s = row % SEQ;
    if (s == XL) return;
    int d0 = l * 8;

    const float* emb; const float* te; float alpha; int pos;
    if (s < XL) {
        int tok = x[b * XL + s];
        emb = text_emb + (size_t)tok * DMODEL;
        te = type_emb; alpha = alpha_text[0]; pos = s;
    } else {
        int r = s - XL - 1;
        int tok = y_mask[b * YL + r] ? MASK_ID : y[b * YL + r];
        emb = audio_emb + (size_t)tok * DMODEL;
        te = type_emb + 2 * DMODEL; alpha = alpha_audio[0]; pos = r;
    }

    float4 e0 = *(const float4*)(emb + d0);
    float4 e1 = *(const float4*)(emb + d0 + 4);
    float4 t0 = *(const float4*)(te + d0);
    float4 t1 = *(const float4*)(te + d0 + 4);
    float v[8] = {e0.x + t0.x, e0.y + t0.y, e0.z + t0.z, e0.w + t0.w,
                  e1.x + t1.x, e1.y + t1.y, e1.z + t1.z, e1.w + t1.w};
    float fp = (float)pos;
    #pragma unroll
    for (int p = 0; p < 4; ++p) {
        int d = d0 + 2 * p;
        float div = __expf((float)d * (-9.210340371976184f / (float)DMODEL));
        float sn, cs;
        __sincosf(fp * div, &sn, &cs);
        v[2 * p]     += alpha * sn;
        v[2 * p + 1] += alpha * cs;
    }

    float* hp = hbuf + (size_t)row * DMODEL + d0;
    *(float4*)hp       = make_float4(v[0], v[1], v[2], v[3]);
    *(float4*)(hp + 4) = make_float4(v[4], v[5], v[6], v[7]);
    short8 sv;
    #pragma unroll
    for (int e = 0; e < 8; ++e) sv[e] = (short)f2bf(v[e]);
    *(short8*)(hbuf_bf + (size_t)row * DMODEL + d0) = sv;
}

// ---------------- bf16 MFMA NT GEMM (full-K): bias/relu, f32 and/or bf16 out ----------
__global__ __launch_bounds__(256) void gemm_bf16_kernel(
    const u16* __restrict__ A, const u16* __restrict__ Bw,
    const float* __restrict__ bias,
    float* __restrict__ Cf, u16* __restrict__ Cb,
    int M, int N, int K, int relu)
{
    __shared__ u16 As[128 * 32];
    __shared__ u16 Bs[128 * 32];
    int tid = threadIdx.x;
    int w = tid >> 6, l = tid & 63;
    int m0 = blockIdx.y * 128, n0 = blockIdx.x * 128;
    int wm = (w >> 1) * 64, wn = (w & 1) * 64;

    f32x4 acc[4][4];
    #pragma unroll
    for (int i = 0; i < 4; ++i)
        #pragma unroll
        for (int j = 0; j < 4; ++j) acc[i][j] = (f32x4){0.f, 0.f, 0.f, 0.f};

    int srow0 = (w << 5) + (l >> 2);
    int skp = (l & 3) << 3;

    for (int k0 = 0; k0 < K; k0 += 32) {
        #pragma unroll
        for (int c = 0; c < 2; ++c) {
            int row = srow0 + c * 16;
            int am = m0 + row; if (am >= M) am = M - 1;
            int bn = n0 + row; if (bn >= N) bn = N - 1;
            __builtin_amdgcn_global_load_lds(
                (const __attribute__((address_space(1))) void*)(A + (size_t)am * K + k0 + skp),
                (__attribute__((address_space(3))) void*)(As + ((w * 2 + c) << 9)), 16, 0, 0);
            __builtin_amdgcn_global_load_lds(
                (const __attribute__((address_space(1))) void*)(Bw + (size_t)bn * K + k0 + skp),
                (__attribute__((address_space(3))) void*)(Bs + ((w * 2 + c) << 9)), 16, 0, 0);
        }
        __syncthreads();
        short8 af[4], bfr[4];
        #pragma unroll
        for (int i = 0; i < 4; ++i) {
            af[i]  = *(const short8*)(As + (wm + i * 16 + (l & 15)) * 32 + ((l >> 4) << 3));
            bfr[i] = *(const short8*)(Bs + (wn + i * 16 + (l & 15)) * 32 + ((l >> 4) << 3));
        }
        #pragma unroll
        for (int i = 0; i < 4; ++i)
            #pragma unroll
            for (int j = 0; j < 4; ++j)
                acc[i][j] = __builtin_amdgcn_mfma_f32_16x16x32_bf16(af[i], bfr[j], acc[i][j], 0, 0, 0);
        __syncthreads();
    }

    #pragma unroll
    for (int i = 0; i < 4; ++i) {
        #pragma unroll
        for (int j = 0; j < 4; ++j) {
            #pragma unroll
            for (int jj = 0; jj < 4; ++jj) {
                int row = m0 + wm + i * 16 + ((l >> 4) << 2) + jj;
                int col = n0 + wn + j * 16 + (l & 15);
                if (row < M && col < N) {
                    float v = acc[i][j][jj];
                    if (bias) v += bias[col];
                    if (relu) v = fmaxf(v, 0.f);
                    if (Cf) Cf[(size_t)row * N + col] = v;
                    if (Cb) Cb[(size_t)row * N + col] = f2bf(v);
                }
            }
        }
    }
}

// ---- split-K variant: blockIdx.z picks K-range [z*klen, min(+klen,K)) and partial buf ----
__global__ __launch_bounds__(256) void gemm_bf16_splitk_kernel(
    const u16* __restrict__ A, const u16* __restrict__ Bw,
    float* __restrict__ P0, float* __restrict__ P1, float* __restrict__ P2,
    int M, int N, int K, int klen)
{
    __shared__ u16 As[128 * 32];
    __shared__ u16 Bs[128 * 32];
    int tid = threadIdx.x;
    int w = tid >> 6, l = tid & 63;
    int z = blockIdx.z;
    float* Cp = (z == 0) ? P0 : (z == 1) ? P1 : P2;
    int kbeg = z * klen;
    int kend = min(kbeg + klen, K);
    int m0 = blockIdx.y * 128, n0 = blockIdx.x * 128;
    int wm = (w >> 1) * 64, wn = (w & 1) * 64;

    f32x4 acc[4][4];
    #pragma unroll
    for (int i = 0; i < 4; ++i)
        #pragma unroll
        for (int j = 0; j < 4; ++j) acc[i][j] = (f32x4){0.f, 0.f, 0.f, 0.f};

    int srow0 = (w << 5) + (l >> 2);
    int skp = (l & 3) << 3;

    for (int k0 = kbeg; k0 < kend; k0 += 32) {
        #pragma unroll
        for (int c = 0; c < 2; ++c) {
            int row = srow0 + c * 16;
            int am = m0 + row; if (am >= M) am = M - 1;
            int bn = n0 + row; if (bn >= N) bn = N - 1;
            __builtin_amdgcn_global_load_lds(
                (const __attribute__((address_space(1))) void*)(A + (size_t)am * K + k0 + skp),
                (__attribute__((address_space(3))) void*)(As + ((w * 2 + c) << 9)), 16, 0, 0);
            __builtin_amdgcn_global_load_lds(
                (const __attribute__((address_space(1))) void*)(Bw + (size_t)bn * K + k0 + skp),
                (__attribute__((address_space(3))) void*)(Bs + ((w * 2 + c) << 9)), 16, 0, 0);
        }
        __syncthreads();
        short8 af[4], bfr[4];
        #pragma unroll
        for (int i = 0; i < 4; ++i) {
            af[i]  = *(const short8*)(As + (wm + i * 16 + (l & 15)) * 32 + ((l >> 4) << 3));
            bfr[i] = *(const short8*)(Bs + (wn + i * 16 + (l & 15)) * 32 + ((l >> 4) << 3));
        }
        #pragma unroll
        for (int i = 0; i < 4; ++i)
            #pragma unroll
            for (int j = 0; j < 4; ++j)
                acc[i][j] = __builtin_amdgcn_mfma_f32_16x16x32_bf16(af[i], bfr[j], acc[i][j], 0, 0, 0);
        __syncthreads();
    }

    #pragma unroll
    for (int i = 0; i < 4; ++i) {
        #pragma unroll
        for (int j = 0; j < 4; ++j) {
            #pragma unroll
            for (int jj = 0; jj < 4; ++jj) {
                int row = m0 + wm + i * 16 + ((l >> 4) << 2) + jj;
                int col = n0 + wn + j * 16 + (l & 15);
                if (row < M && col < N)
                    Cp[(size_t)row * N + col] = acc[i][j][jj];
            }
        }
    }
}

// ---- split-K + dynamic-M (logits) ----
__global__ __launch_bounds__(256) void gemm_bf16_splitk_dynm_kernel(
    const u16* __restrict__ A, const u16* __restrict__ Bw,
    const int* __restrict__ Mp,
    float* __restrict__ P0, float* __restrict__ P1,
    int N, int K, int klen)
{
    int M = *Mp;
    int m0 = blockIdx.y * 128;
    if (m0 >= M) return;
    __shared__ u16 As[128 * 32];
    __shared__ u16 Bs[128 * 32];
    int tid = threadIdx.x;
    int w = tid >> 6, l = tid & 63;
    int z = blockIdx.z;
    float* Cp = (z == 0) ? P0 : P1;
    int kbeg = z * klen;
    int kend = min(kbeg + klen, K);
    int n0 = blockIdx.x * 128;
    int wm = (w >> 1) * 64, wn = (w & 1) * 64;

    f32x4 acc[4][4];
    #pragma unroll
    for (int i = 0; i < 4; ++i)
        #pragma unroll
        for (int j = 0; j < 4; ++j) acc[i][j] = (f32x4){0.f, 0.f, 0.f, 0.f};

    int srow0 = (w << 5) + (l >> 2);
    int skp = (l & 3) << 3;

    for (int k0 = kbeg; k0 < kend; k0 += 32) {
        #pragma unroll
        for (int c = 0; c < 2; ++c) {
            int row = srow0 + c * 16;
            int am = m0 + row; if (am >= M) am = M - 1;
            int bn = n0 + row; if (bn >= N) bn = N - 1;
            __builtin_amdgcn_global_load_lds(
                (const __attribute__((address_space(1))) void*)(A + (size_t)am * K + k0 + skp),
                (__attribute__((address_space(3))) void*)(As + ((w * 2 + c) << 9)), 16, 0, 0);
            __builtin_amdgcn_global_load_lds(
                (const __attribute__((address_space(1))) void*)(Bw + (size_t)bn * K + k0 + skp),
                (__attribute__((address_space(3))) void*)(Bs + ((w * 2 + c) << 9)), 16, 0, 0);
        }
        __syncthreads();
        short8 af[4], bfr[4];
        #pragma unroll
        for (int i = 0; i < 4; ++i) {
            af[i]  = *(const short8*)(As + (wm + i * 16 + (l & 15)) * 32 + ((l >> 4) << 3));
            bfr[i] = *(const short8*)(Bs + (wn + i * 16 + (l & 15)) * 32 + ((l >> 4) << 3));
        }
        #pragma unroll
        for (int i = 0; i < 4; ++i)
            #pragma unroll
            for (int j = 0; j < 4; ++j)
                acc[i][j] = __builtin_amdgcn_mfma_f32_16x16x32_bf16(af[i], bfr[j], acc[i][j], 0, 0, 0);
        __syncthreads();
    }

    #pragma unroll
    for (int i = 0; i < 4; ++i) {
        #pragma unroll
        for (int j = 0; j < 4; ++j) {
            #pragma unroll
            for (int jj = 0; jj < 4; ++jj) {
                int row = m0 + wm + i * 16 + ((l >> 4) << 2) + jj;
                int col = n0 + wn + j * 16 + (l & 15);
                if (row < M && col < N)
                    Cp[(size_t)row * N + col] = acc[i][j][jj];
            }
        }
    }
}

// ---------------- MFMA flash attention, QBLK=128, mask-sparse k-loop ----------------
__global__ __launch_bounds__(256) void attn_mfma_kernel(
    const u16* __restrict__ qkv,
    const int* __restrict__ x1_lens, const int* __restrict__ x2_lens,
    const int* __restrict__ y1_lens, const int* __restrict__ y2_lens,
    const int* __restrict__ y_mask,
    u16* __restrict__ obuf)
{
    __shared__ u16 Ks[64 * 64];
    __shared__ u16 Vt[64 * 64];
    __shared__ u16 Ps[4][32 * 64];
    __shared__ unsigned char Am[1216];

    int tid = threadIdx.x;
    int w = tid >> 6, l = tid & 63;
    int bh = blockIdx.y;
    int b = bh >> 3, h = bh & 7;
    int q0 = blockIdx.x * QBLK;

    int x1 = x1_lens[b], xlen = x1 + 1 + x2_lens[b];
    int y1 = y1_lens[b], ylen = y1 + 1 + y2_lens[b];

    int kmax = -1;
    if (q0 < XL) kmax = max(kmax, xlen - 1);
    if (XL >= q0 && XL < q0 + QBLK) kmax = max(kmax, XL);
    {
        int ry0 = max(0, q0 - XL - 1);
        int ry1 = min(YL - 1, q0 + QBLK - 2 - XL);
        if (ry0 <= ry1) {
            if (ry0 <= y1 - 1) kmax = max(kmax, XL + y1);
            if (y1 >= ry0 && y1 <= ry1) kmax = max(kmax, XL + y1 + 1);
            int a = max(ry0, y1 + 1), bb = min(ry1, ylen - 1);
            if (a <= bb) kmax = max(kmax, XL + ylen);
        }
    }
    if (kmax < 0) return;
    int NKT = (kmax >> 6) + 1;

    for (int c = tid; c < 1216; c += 256) {
        unsigned v = 0;
        if (c < SEQ) {
            int ym = 0;
            if (c > XL) ym = y_mask[b * YL + c - XL - 1];
            bool a2c = (c == XL);
            bool ygt = (c > XL);
            bool aT0 = (c < x1);
            bool aT1 = (c >= x1) && (c < xlen);
            bool aT3 = aT0 || (ygt && c <= XL + y1);
            bool aT4 = (c < xlen) || a2c || (ygt && c <= XL + y1 + 1);
            bool aT5 = (((c < xlen) || a2c || (ygt && c <= XL + ylen)) && !ym);
            v = (aT0 ? 1u : 0u) | (aT1 ? 2u : 0u) | (a2c ? 4u : 0u) |
                (aT3 ? 8u : 0u) | (aT4 ? 16u : 0u) | (aT5 ? 32u : 0u);
        }
        Am[c] = (unsigned char)v;
    }

    short8 qf[2][2];
    #pragma unroll
    for (int qh = 0; qh < 2; ++qh) {
        int qr = q0 + w * 32 + qh * 16 + (l & 15);
        const u16* qp = qkv + (size_t)(b * SEQ + qr) * 1536 + h * 64 + ((l >> 4) << 3);
        #pragma unroll
        for (int kb = 0; kb < 2; ++kb) {
            short8 raw = *(const short8*)(qp + kb * 32);
            short8 s8;
            #pragma unroll
            for (int e = 0; e < 8; ++e)
                s8[e] = (short)f2bf(bf2f((u16)raw[e]) * 0.125f);
            qf[qh][kb] = s8;
        }
    }

    int rt[2][4];
    #pragma unroll
    for (int qh = 0; qh < 2; ++qh)
        #pragma unroll
        for (int j = 0; j < 4; ++j) {
            int qrj = q0 + w * 32 + qh * 16 + ((l >> 4) << 2) + j;
            int t;
            if (qrj < XL) t = (qrj < x1) ? 0 : 1;
            else if (qrj == XL) t = 2;
            else {
                int ry = qrj - XL - 1;
                t = (ry < y1) ? 3 : (ry == y1) ? 4 : (ry < ylen) ? 5 : 7;
            }
            rt[qh][j] = t;
        }

    f32x4 oacc[2][4];
    #pragma unroll
    for (int qh = 0; qh < 2; ++qh)
        #pragma unroll
        for (int db = 0; db < 4; ++db) oacc[qh][db] = (f32x4){0.f, 0.f, 0.f, 0.f};
    float mrun[2][4], lrun[2][4];
    #pragma unroll
    for (int qh = 0; qh < 2; ++qh)
        #pragma unroll
        for (int j = 0; j < 4; ++j) { mrun[qh][j] = -INFINITY; lrun[qh][j] = 0.f; }
    u16* Psw = &Ps[w][0];

    for (int kt = 0; kt < NKT; ++kt) {
        __syncthreads();
        {
            int r = tid >> 2, d0k = (tid & 3) << 4;
            int krc = min(kt * 64 + r, SEQ - 1);
            const u16* kp = qkv + (size_t)(b * SEQ + krc) * 1536 + 512 + h * 64 + d0k;
            short8 ka = *(const short8*)kp;
            short8 kb8 = *(const short8*)(kp + 8);
            int ksw = (r & 7) << 3;
            *(short8*)&Ks[r * 64 + (d0k ^ ksw)] = ka;
            *(short8*)&Ks[r * 64 + ((d0k + 8) ^ ksw)] = kb8;
        }
        {
            int rp = tid >> 3, o = tid & 7;
            int d0v = o * 8;
            int k0r = min(kt * 64 + 2 * rp, SEQ - 1);
            int k1r = min(kt * 64 + 2 * rp + 1, SEQ - 1);
            const u16* v0p = qkv + (size_t)(b * SEQ + k0r) * 1536 + 1024 + h * 64 + d0v;
            const u16* v1p = qkv + (size_t)(b * SEQ + k1r) * 1536 + 1024 + h * 64 + d0v;
            short8 va = *(const short8*)v0p;
            short8 vb = *(const short8*)v1p;
            #pragma unroll
            for (int e = 0; e < 8; ++e) {
                int d = d0v + e;
                unsigned val = (unsigned)(u16)va[e] | ((unsigned)(u16)vb[e] << 16);
                *(unsigned*)&Vt[d * 64 + ((2 * rp) ^ ((d & 7) << 3))] = val;
            }
        }
        __syncthreads();

        unsigned amv[4];
        #pragma unroll
        for (int cb = 0; cb < 4; ++cb)
            amv[cb] = Am[kt * 64 + cb * 16 + (l & 15)];

        f32x4 sc[2][4];
        #pragma unroll
        for (int cb = 0; cb < 4; ++cb) {
            int krw = cb * 16 + (l & 15);
            int ksw = (krw & 7) << 3;
            short8 k0 = *(const short8*)&Ks[krw * 64 + ((((l >> 4) << 3)) ^ ksw)];
            short8 k1 = *(const short8*)&Ks[krw * 64 + ((32 + ((l >> 4) << 3)) ^ ksw)];
            #pragma unroll
            for (int qh = 0; qh < 2; ++qh) {
                f32x4 z = (f32x4){0.f, 0.f, 0.f, 0.f};
                z = __builtin_amdgcn_mfma_f32_16x16x32_bf16(qf[qh][0], k0, z, 0, 0, 0);
                sc[qh][cb] = __builtin_amdgcn_mfma_f32_16x16x32_bf16(qf[qh][1], k1, z, 0, 0, 0);
            }
        }

        #pragma unroll
        for (int qh = 0; qh < 2; ++qh) {
            #pragma unroll
            for (int j = 0; j < 4; ++j) {
                int rtj = rt[qh][j];
                float s0 = ((amv[0] >> rtj) & 1u) ? sc[qh][0][j] : NEGBIG;
                float s1 = ((amv[1] >> rtj) & 1u) ? sc[qh][1][j] : NEGBIG;
                float s2 = ((amv[2] >> rtj) & 1u) ? sc[qh][2][j] : NEGBIG;
                float s3 = ((amv[3] >> rtj) & 1u) ? sc[qh][3][j] : NEGBIG;
                float tmax = fmaxf(fmaxf(s0, s1), fmaxf(s2, s3));
                tmax = fmaxf(tmax, __shfl_xor(tmax, 1));
                tmax = fmaxf(tmax, __shfl_xor(tmax, 2));
                tmax = fmaxf(tmax, __shfl_xor(tmax, 4));
                tmax = fmaxf(tmax, __shfl_xor(tmax, 8));
                float newm = fmaxf(mrun[qh][j], tmax);
                float corr = __expf(mrun[qh][j] - newm);
                float p0 = __expf(s0 - newm);
                float p1 = __expf(s1 - newm);
                float p2 = __expf(s2 - newm);
                float p3 = __expf(s3 - newm);
                float ps = p0 + p1 + p2 + p3;
                ps += __shfl_xor(ps, 1); ps += __shfl_xor(ps, 2);
                ps += __shfl_xor(ps, 4); ps += __shfl_xor(ps, 8);
                lrun[qh][j] = lrun[qh][j] * corr + ps;
                mrun[qh][j] = newm;
                #pragma unroll
                for (int db = 0; db < 4; ++db) oacc[qh][db][j] *= corr;
                int lr = qh * 16 + ((l >> 4) << 2) + j;
                int sw = (lr & 7) << 3;
                Psw[lr * 64 + ((0  + (l & 15)) ^ sw)] = f2bf(p0);
                Psw[lr * 64 + ((16 + (l & 15)) ^ sw)] = f2bf(p1);
                Psw[lr * 64 + ((32 + (l & 15)) ^ sw)] = f2bf(p2);
                Psw[lr * 64 + ((48 + (l & 15)) ^ sw)] = f2bf(p3);
            }
        }

        short8 pf[2][2];
        #pragma unroll
        for (int qh = 0; qh < 2; ++qh) {
            int pr = qh * 16 + (l & 15);
            int sw = (pr & 7) << 3;
            pf[qh][0] = *(const short8*)&Psw[pr * 64 + ((((l >> 4) << 3)) ^ sw)];
            pf[qh][1] = *(const short8*)&Psw[pr * 64 + ((32 + ((l >> 4) << 3)) ^ sw)];
        }
        #pragma unroll
        for (int db = 0; db < 4; ++db) {
            int vr = db * 16 + (l & 15);
            int vsw = (vr & 7) << 3;
            short8 v0 = *(const short8*)&Vt[vr * 64 + ((((l >> 4) << 3)) ^ vsw)];
            short8 v1 = *(const short8*)&Vt[vr * 64 + ((32 + ((l >> 4) << 3)) ^ vsw)];
            #pragma unroll
            for (int qh = 0; qh < 2; ++qh) {
                oacc[qh][db] = __builtin_amdgcn_mfma_f32_16x16x32_bf16(pf[qh][0], v0, oacc[qh][db], 0, 0, 0);
                oacc[qh][db] = __builtin_amdgcn_mfma_f32_16x16x32_bf16(pf[qh][1], v1, oacc[qh][db], 0, 0, 0);
            }
        }
    }

    #pragma unroll
    for (int qh = 0; qh < 2; ++qh) {
        float rl[4];
        #pragma unroll
        for (int j = 0; j < 4; ++j) rl[j] = 1.f / lrun[qh][j];
        #pragma unroll
        for (int db = 0; db < 4; ++db) {
            #pragma unroll
            for (int j = 0; j < 4; ++j) {
                int qrj = q0 + w * 32 + qh * 16 + ((l >> 4) << 2) + j;
                obuf[(size_t)(b * SEQ + qrj) * DMODEL + h * 64 + db * 16 + (l & 15)] =
                    f2bf(oacc[qh][db][j] * rl[j]);
            }
        }
    }
}

// ------- residual add + fused split-K reduce (+bias) + LayerNorm, wave-per-row -------
__global__ __launch_bounds__(256) void add_ln_kernel(
    float* __restrict__ hbuf, u16* __restrict__ hbuf_bf,
    const float* __restrict__ p0, const float* __restrict__ p1,
    const float* __restrict__ p2, const float* __restrict__ bias,
    const float* __restrict__ g, const float* __restrict__ beta)
{
    int row = blockIdx.x * 4 + (threadIdx.x >> 6);
    int l = threadIdx.x & 63;
    int d0 = l * 8;
    size_t off = (size_t)row * DMODEL + d0;
    float* hp = hbuf + off;
    float4 a0 = *(const float4*)hp, a1 = *(const float4*)(hp + 4);
    float4 q0 = *(const float4*)(p0 + off), q1 = *(const float4*)(p0 + off + 4);
    float v[8] = {a0.x + q0.x, a0.y + q0.y, a0.z + q0.z, a0.w + q0.w,
                  a1.x + q1.x, a1.y + q1.y, a1.z + q1.z, a1.w + q1.w};
    if (p1) {
        float4 r0 = *(const float4*)(p1 + off), r1 = *(const float4*)(p1 + off + 4);
        v[0] += r0.x; v[1] += r0.y; v[2] += r0.z; v[3] += r0.w;
        v[4] += r1.x; v[5] += r1.y; v[6] += r1.z; v[7] += r1.w;
    }
    if (p2) {
        float4 r0 = *(const float4*)(p2 + off), r1 = *(const float4*)(p2 + off + 4);
        v[0] += r0.x; v[1] += r0.y; v[2] += r0.z; v[3] += r0.w;
        v[4] += r1.x; v[5] += r1.y; v[6] += r1.z; v[7] += r1.w;
    }
    {
        float4 b0 = *(const float4*)(bias + d0), b1 = *(const float4*)(bias + d0 + 4);
        v[0] += b0.x; v[1] += b0.y; v[2] += b0.z; v[3] += b0.w;
        v[4] += b1.x; v[5] += b1.y; v[6] += b1.z; v[7] += b1.w;
    }
    float s = 0.f;
    #pragma unroll
    for (int e = 0; e < 8; ++e) s += v[e];
    #pragma unroll
    for (int off2 = 32; off2 > 0; off2 >>= 1) s += __shfl_xor(s, off2);
    float mu = s * (1.f / DMODEL);
    float sq = 0.f;
    #pragma unroll
    for (int e = 0; e < 8; ++e) { v[e] -= mu; sq += v[e] * v[e]; }
    #pragma unroll
    for (int off2 = 32; off2 > 0; off2 >>= 1) sq += __shfl_xor(sq, off2);
    float inv = 1.f / sqrtf(sq * (1.f / DMODEL) + 1e-5f);
    float4 g0 = *(const float4*)(g + d0), g1 = *(const float4*)(g + d0 + 4);
    float4 be0 = *(const float4*)(beta + d0), be1 = *(const float4*)(beta + d0 + 4);
    float o[8];
    o[0] = v[0] * inv * g0.x + be0.x; o[1] = v[1] * inv * g0.y + be0.y;
    o[2] = v[2] * inv * g0.z + be0.z; o[3] = v[3] * inv * g0.w + be0.w;
    o[4] = v[4] * inv * g1.x + be1.x; o[5] = v[5] * inv * g1.y + be1.y;
    o[6] = v[6] * inv * g1.z + be1.z; o[7] = v[7] * inv * g1.w + be1.w;
    *(float4*)hp       = make_float4(o[0], o[1], o[2], o[3]);
    *(float4*)(hp + 4) = make_float4(o[4], o[5], o[6], o[7]);
    short8 sv;
    #pragma unroll
    for (int e = 0; e < 8; ++e) sv[e] = (short)f2bf(o[e]);
    *(short8*)(hbuf_bf + off) = sv;
}

// ---------------- compaction of masked rows ----------------
__global__ __launch_bounds__(256) void init_accum_kernel(float* accum) {
    if (threadIdx.x < 8) accum[threadIdx.x] = 0.f;
}

__global__ __launch_bounds__(256) void compact_kernel(
    const int* __restrict__ y_mask, int* __restrict__ cnt, int* __restrict__ cmap)
{
    int i = blockIdx.x * 256 + threadIdx.x;
    if (i < BATCH * YL && y_mask[i]) {
        int pos = atomicAdd(cnt, 1);
        cmap[pos] = i;
    }
}

__global__ __launch_bounds__(256) void copy_rows_kernel(
    const int* __restrict__ cnt, const int* __restrict__ cmap,
    const u16* __restrict__ hbuf_bf, const int* __restrict__ y,
    u16* __restrict__ cbuf, int* __restrict__ ctgt)
{
    int i = blockIdx.x;
    if (i >= *cnt) return;
    int g = cmap[i];
    int b = g >> 10, r = g & 1023;
    const u16* src = hbuf_bf + (size_t)(b * SEQ + XL + 1 + r) * DMODEL;
    u16* dst = cbuf + (size_t)i * DMODEL;
    int t = threadIdx.x;
    ((ushort2*)dst)[t] = ((const ushort2*)src)[t];
    if (t == 0) ctgt[i] = y[g];
}

// ---------------- CE + top-3 over compacted rows (sums 2 logits partials) ----------------
__global__ __launch_bounds__(256) void ce_kernel(
    const int* __restrict__ cnt,
    const float* __restrict__ lg0, const float* __restrict__ lg1,
    const int* __restrict__ ctgt, float* __restrict__ accum)
{
    int row = blockIdx.x;
    if (row >= *cnt) return;
    const float* lp0 = lg0 + (size_t)row * OV;
    const float* lp1 = lg1 + (size_t)row * OV;
    int tgt = ctgt[row];
    int t = threadIdx.x;
    __shared__ float red[4];

    float lmax = -INFINITY;
    for (int i = t; i < OV; i += 256) lmax = fmaxf(lmax, lp0[i] + lp1[i]);
    #pragma unroll
    for (int off = 32; off > 0; off >>= 1) lmax = fmaxf(lmax, __shfl_xor(lmax, off));
    if ((t & 63) == 0) red[t >> 6] = lmax;
    __syncthreads();
    lmax = fmaxf(fmaxf(red[0], red[1]), fmaxf(red[2], red[3]));
    __syncthreads();

    float lsum = 0.f;
    for (int i = t; i < OV; i += 256) lsum += expf(lp0[i] + lp1[i] - lmax);
    #pragma unroll
    for (int off = 32; off > 0; off >>= 1) lsum += __shfl_xor(lsum, off);
    if ((t & 63) == 0) red[t >> 6] = lsum;
    __syncthreads();
    lsum = red[0] + red[1] + red[2] + red[3];
    __syncthreads();

    float lt = lp0[tgt] + lp1[tgt];
    float cntr = 0.f;
    for (int i = t; i < OV; i += 256) {
        float v = lp0[i] + lp1[i];
        if (v > lt || (v == lt && i < tgt)) cntr += 1.f;
    }
    #pragma unroll
    for (int off = 32; off > 0; off >>= 1) cntr += __shfl_xor(cntr, off);
    if ((t & 63) == 0) red[t >> 6] = cntr;
    __syncthreads();
    cntr = red[0] + red[1] + red[2] + red[3];

    if (t == 0) {
        float ce = -(lt - lmax - logf(lsum));
        float inc = (tgt != EOS_TOK) ? 1.f : 0.f;
        float corr = (cntr < 2.5f) ? 1.f : 0.f;
        atomicAdd(&accum[0], ce);
        atomicAdd(&accum[1], 1.f);
        atomicAdd(&accum[2], corr * inc);
        atomicAdd(&accum[3], inc);
    }
}

// ---------------- duration head ----------------
__global__ __launch_bounds__(256) void dur1_kernel(
    const float* __restrict__ hbuf, const int* __restrict__ y1_lens,
    const float* __restrict__ dW1, const float* __restrict__ db1,
    float* __restrict__ h1buf)
{
    __shared__ float cls[DMODEL];
    int g = blockIdx.x;
    int b = g >> 3, c = g & 7;
    int t = threadIdx.x;
    const float* cp = hbuf + (size_t)(b * SEQ + XL + 1 + y1_lens[b]) * DMODEL;
    cls[t] = cp[t]; cls[t + 256] = cp[t + 256];
    __syncthreads();
    int row = c * 32 + (t >> 3);
    int ln = t & 7;
    const float* w = dW1 + (size_t)row * DMODEL + ln * 64;
    const float* cv = cls + ln * 64;
    float acc = 0.f;
    #pragma unroll 8
    for (int k = 0; k < 64; ++k) acc = fmaf(cv[k], w[k], acc);
    acc += __shfl_xor(acc, 1); acc += __shfl_xor(acc, 2); acc += __shfl_xor(acc, 4);
    if (ln == 0) h1buf[b * 256 + row] = fmaxf(acc + db1[row], 0.f);
}

__global__ __launch_bounds__(256) void dur2_kernel(
    const float* __restrict__ h1buf,
    const float* __restrict__ dW2, const float* __restrict__ db2,
    const float* __restrict__ dW3, const float* __restrict__ db3,
    float* __restrict__ preds)
{
    __shared__ float h1s[256];
    __shared__ float h2s[128];
    int b = blockIdx.x;
    int t = threadIdx.x;
    h1s[t] = h1buf[b * 256 + t];
    __syncthreads();
    if (t < 128) {
        float acc = db2[t];
        const float* w = dW2 + (size_t)t * 256;
        for (int k = 0; k < 256; ++k) acc = fmaf(h1s[k], w[k], acc);
        h2s[t] = fmaxf(acc, 0.f);
    }
    __syncthreads();
    if (t < 64) {
        float v = h2s[t] * dW3[t] + h2s[t + 64] * dW3[t + 64];
        #pragma unroll
        for (int off = 32; off > 0; off >>= 1) v += __shfl_xor(v, off);
        if (t == 0) preds[b] = v + db3[0];
    }
}

__global__ __launch_bounds__(64) void final_kernel(
    const float* __restrict__ accum, const float* __restrict__ preds,
    const int* __restrict__ y2_lens, const int* __restrict__ x2_lens,
    float* __restrict__ out)
{
    if (threadIdx.x == 0) {
        float dl = 0.f;
        for (int b = 0; b < BATCH; ++b) {
            float tgt = (float)y2_lens[b] / (float)x2_lens[b];
            float e = preds[b] - tgt;
            float ae = fabsf(e);
            dl += (ae <= 1.f) ? 0.5f * e * e : (ae - 0.5f);
        }
        dl *= (1.f / BATCH);
        float token_loss = accum[0] / accum[1];
        float acc_v = accum[2] / fmaxf(accum[3], 1.f);
        out[0] = token_loss + dl;
        out[1] = acc_v;
    }
}

// ---------------- orchestration ----------------
extern "C" void kernel_launch(void* const* d_in, const int* in_sizes, int n_in,
                              void* d_out, int out_size, void* d_ws, size_t ws_size,
                              hipStream_t stream)
{
    const int*   x           = (const int*)d_in[0];
    const int*   x1_lens     = (const int*)d_in[1];
    const int*   x2_lens     = (const int*)d_in[2];
    const int*   y           = (const int*)d_in[3];
    const int*   y1_lens     = (const int*)d_in[4];
    const int*   y2_lens     = (const int*)d_in[5];
    const int*   y_mask      = (const int*)d_in[6];
    const float* emo_feature = (const float*)d_in[7];
    const float* text_emb    = (const float*)d_in[8];
    const float* audio_emb   = (const float*)d_in[9];
    const float* type_emb    = (const float*)d_in[10];
    const float* emo_W       = (const float*)d_in[11];
    const float* emo_b       = (const float*)d_in[12];
    const float* alpha_text  = (const float*)d_in[13];
    const float* alpha_audio = (const float*)d_in[14];
    const float* Wqkv        = (const float*)d_in[15];
    const float* bqkv        = (const float*)d_in[16];
    const float* Wo          = (const float*)d_in[17];
    const float* bo          = (const float*)d_in[18];
    const float* ln1_g       = (const float*)d_in[19];
    const float* ln1_b       = (const float*)d_in[20];
    const float* ln2_g       = (const float*)d_in[21];
    const float* ln2_b       = (const float*)d_in[22];
    const float* W1          = (const float*)d_in[23];
    const float* b1          = (const float*)d_in[24];
    const float* W2          = (const float*)d_in[25];
    const float* b2          = (const float*)d_in[26];
    const float* predict_W   = (const float*)d_in[27];
    const float* dW1         = (const float*)d_in[28];
    const float* db1         = (const float*)d_in[29];
    const float* dW2         = (const float*)d_in[30];
    const float* db2         = (const float*)d_in[31];
    const float* dW3         = (const float*)d_in[32];
    const float* db3         = (const float*)d_in[33];

    const int M = BATCH * SEQ;                       // 4612
    char* p = (char*)d_ws;
    float* hbuf   = (float*)p; p += 9445376;         // M*512*4
    float* delta  = (float*)p; p += 9445376;
    char*  uni    = p;         p += 18909440;        // max(ff1_bf, logits partial0)
    u16*   hbuf_bf = (u16*)p;  p += 4722688;
    u16*   qkv_bf  = (u16*)p;  p += 14168064;        // also split-K partial region
    u16*   obuf_bf = (u16*)p;  p += 4722688;         // contiguous after qkv_bf
    u16*   wbf     = (u16*)p;  p += 19923968;
    u16*   cbuf    = (u16*)p;  p += (size_t)CCAP * DMODEL * 2;
    u16*   ff1_bf  = (u16*)uni;

    // split-K partials (regions dead at their point of use):
    float* partA = (float*)qkv_bf;                   // 9,445,376 B into qkv_bf
    float* partB = (float*)((char*)qkv_bf + 9445376); // spills into obuf_bf (dead during W2)
    float* lg0   = (float*)uni;                      // logits partial 0 (ff1 dead)
    float* lg1   = (float*)qkv_bf;                   // logits partial 1 (qkv dead)

    float* accum  = delta;
    int*   cnt    = (int*)(delta + 4);
    float* preds  = delta + 8;
    int*   cmap   = (int*)(delta + 16);
    int*   ctgt   = cmap + CCAP;
    float* h1buf  = (float*)(ctgt + CCAP);

    u16* wq_bf = wbf;                                // 3*1536*512
    u16* wo_bf = wq_bf + 2359296;                    // 3*512*512
    u16* w1_bf = wo_bf + 786432;                     // 3*2048*512
    u16* w2_bf = w1_bf + 3145728;                    // 3*512*2048
    u16* wp_bf = w2_bf + 3145728;                    // 1025*512

    cvt5_kernel<<<1024, 256, 0, stream>>>(
        Wqkv, wq_bf, 2359296 / 4,
        Wo, wo_bf, 786432 / 4,
        W1, w1_bf, 3145728 / 4,
        W2, w2_bf, 3145728 / 4,
        predict_W, wp_bf, 524800 / 4);

    emo_kernel<<<32, 256, 0, stream>>>(emo_feature, emo_W, emo_b, type_emb, hbuf, hbuf_bf);
    build_h_kernel<<<M / 4, 256, 0, stream>>>(
        x, y, y_mask, text_emb, audio_emb, type_emb,
        alpha_text, alpha_audio, hbuf, hbuf_bf);

    const int MG = (M + 127) / 128;   // 37
    for (int l = 0; l < NLAYER; ++l) {
        gemm_bf16_kernel<<<dim3(12, MG), 256, 0, stream>>>(
            hbuf_bf, wq_bf + (size_t)l * 1536 * 512, bqkv + l * 1536,
            nullptr, qkv_bf, M, 1536, 512, 0);
        attn_mfma_kernel<<<dim3((SEQ + QBLK - 1) / QBLK, BATCH * NH), 256, 0, stream>>>(
            qkv_bf, x1_lens, x2_lens, y1_lens, y2_lens, y_mask, obuf_bf);
        // Wo: split-K x2 (klen=256) -> delta, partA  (qkv dead after attn)
        gemm_bf16_splitk_kernel<<<dim3(4, MG, 2), 256, 0, stream>>>(
            obuf_bf, wo_bf + (size_t)l * 512 * 512,
            delta, partA, nullptr, M, 512, 512, 256);
        add_ln_kernel<<<M / 4, 256, 0, stream>>>(hbuf, hbuf_bf,
            delta, partA, nullptr, bo + l * 512,
            ln1_g + l * DMODEL, ln1_b + l * DMODEL);
        gemm_bf16_kernel<<<dim3(16, MG), 256, 0, stream>>>(
            hbuf_bf, w1_bf + (size_t)l * 2048 * 512, b1 + l * 2048,
            nullptr, ff1_bf, M, 2048, 512, 1);
        // W2: split-K x3 (klen=768: 768/768/512) -> delta, partA, partB
        gemm_bf16_splitk_kernel<<<dim3(4, MG, 3), 256, 0, stream>>>(
            ff1_bf, w2_bf + (size_t)l * 512 * 2048,
            delta, partA, partB, M, 512, 2048, 768);
        add_ln_kernel<<<M / 4, 256, 0, stream>>>(hbuf, hbuf_bf,
            delta, partA, partB, b2 + l * 512,
            ln2_g + l * DMODEL, ln2_b + l * DMODEL);
    }

    init_accum_kernel<<<1, 64, 0, stream>>>(accum);
    compact_kernel<<<(BATCH * YL) / 256, 256, 0, stream>>>(y_mask, cnt, cmap);
    copy_rows_kernel<<<CCAP, 256, 0, stream>>>(cnt, cmap, hbuf_bf, y, cbuf, ctgt);
    // logits: split-K x2 (klen=256) -> lg0, lg1; ce sums partials
    gemm_bf16_splitk_dynm_kernel<<<dim3((OV + 127) / 128, CCAP / 128, 2), 256, 0, stream>>>(
        cbuf, wp_bf, cnt, lg0, lg1, OV, 512, 256);
    ce_kernel<<<CCAP, 256, 0, stream>>>(cnt, lg0, lg1, ctgt, accum);

    dur1_kernel<<<32, 256, 0, stream>>>(hbuf, y1_lens, dW1, db1, h1buf);
    dur2_kernel<<<4, 256, 0, stream>>>(h1buf, dW2, db2, dW3, db3, preds);
    final_kernel<<<1, 64, 0, stream>>>(accum, preds, y2_lens, x2_lens, (float*)d_out);
}

// Round 7
// 598.152 us; speedup vs baseline: 9.7016x; 1.0212x over previous
//
#include <hip/hip_runtime.h>
#include <hip/hip_bf16.h>
#include <math.h>

#define BATCH 4
#define XL 128
#define YL 1024
#define DMODEL 512
#define NH 8
#define NLAYER 3
#define DFF 2048
#define MASK_ID 1024
#define EOS_TOK 1024
#define HD 64
#define SEQ 1153          // XL + 1 + YL
#define OV 1025
#define NEGBIG (-1e9f)
#define QBLK 128
#define CCAP 2432         // max compacted masked rows

typedef unsigned short u16;
typedef unsigned int u32;
typedef short short8 __attribute__((ext_vector_type(8)));
typedef float f32x4 __attribute__((ext_vector_type(4)));

__device__ __forceinline__ u16 f2bf(float f) {
    union { float f; unsigned u; } v; v.f = f;
    unsigned r = v.u + 0x7fffu + ((v.u >> 16) & 1u);   // RNE
    return (u16)(r >> 16);
}
__device__ __forceinline__ float bf2f(u16 b) {
    union { unsigned u; float f; } v; v.u = ((unsigned)b) << 16;
    return v.f;
}

// ---------------- fused f32 -> bf16 convert for all 5 weight tensors ----------------
__global__ __launch_bounds__(256) void cvt5_kernel(
    const float* __restrict__ s0, u16* __restrict__ d0, int n0,
    const float* __restrict__ s1, u16* __restrict__ d1, int n1,
    const float* __restrict__ s2, u16* __restrict__ d2, int n2,
    const float* __restrict__ s3, u16* __restrict__ d3, int n3,
    const float* __restrict__ s4, u16* __restrict__ d4, int n4)
{
    int c0 = n0, c1 = c0 + n1, c2 = c1 + n2, c3 = c2 + n3, c4 = c3 + n4;
    for (int i = blockIdx.x * 256 + threadIdx.x; i < c4; i += gridDim.x * 256) {
        const float* s; u16* d; int j;
        if (i < c0)      { s = s0; d = d0; j = i; }
        else if (i < c1) { s = s1; d = d1; j = i - c0; }
        else if (i < c2) { s = s2; d = d2; j = i - c1; }
        else if (i < c3) { s = s3; d = d3; j = i - c2; }
        else             { s = s4; d = d4; j = i - c3; }
        float4 v = ((const float4*)s)[j];
        ushort4 o;
        o.x = f2bf(v.x); o.y = f2bf(v.y); o.z = f2bf(v.z); o.w = f2bf(v.w);
        ((ushort4*)d)[j] = o;
    }
}

// ---------------- emo rows ----------------
__global__ __launch_bounds__(256) void emo_kernel(
    const float* __restrict__ emo_feature, const float* __restrict__ emo_W,
    const float* __restrict__ emo_b, const float* __restrict__ type_emb,
    float* __restrict__ hbuf, u16* __restrict__ hbuf_bf)
{
    int b = blockIdx.x >> 3, c = blockIdx.x & 7;
    int t = threadIdx.x;
    int osub = t >> 2, ln = t & 3;
    int d = c * 64 + osub;
    const float* f = emo_feature + b * 768 + ln * 192;
    const float* w = emo_W + (size_t)d * 768 + ln * 192;
    float acc = 0.f;
    #pragma unroll 4
    for (int k = 0; k < 192; ++k) acc = fmaf(f[k], w[k], acc);
    acc += __shfl_xor(acc, 1);
    acc += __shfl_xor(acc, 2);
    if (ln == 0) {
        float v = acc + emo_b[d] + type_emb[DMODEL + d];
        hbuf[(size_t)(b * SEQ + XL) * DMODEL + d] = v;
        hbuf_bf[(size_t)(b * SEQ + XL) * DMODEL + d] = f2bf(v);
    }
}

// ---------------- build h_input (x & y rows), wave-per-row ----------------
__global__ __launch_bounds__(256) void build_h_kernel(
    const int* __restrict__ x, const int* __restrict__ y, const int* __restrict__ y_mask,
    const float* __restrict__ text_emb, const float* __restrict__ audio_emb,
    const float* __restrict__ type_emb,
    const float* __restrict__ alpha_text, const float* __restrict__ alpha_audio,
    float* __restrict__ hbuf, u16* __restrict__ hbuf_bf)
{
    int row = blockIdx.x * 4 + (threadIdx.x >> 6);
    int l = threadIdx.x & 63;
    int b = row / SEQ, s = row % SEQ;
    if (s == XL) return;
    int d0 = l * 8;

    const float* emb; const float* te; float alpha; int pos;
    if (s < XL) {
        int tok = x[b * XL + s];
        emb = text_emb + (size_t)tok * DMODEL;
        te = type_emb; alpha = alpha_text[0]; pos = s;
    } else {
        int r = s - XL - 1;
        int tok = y_mask[b * YL + r] ? MASK_ID : y[b * YL + r];
        emb = audio_emb + (size_t)tok * DMODEL;
        te = type_emb + 2 * DMODEL; alpha = alpha_audio[0]; pos = r;
    }

    float4 e0 = *(const float4*)(emb + d0);
    float4 e1 = *(const float4*)(emb + d0 + 4);
    float4 t0 = *(const float4*)(te + d0);
    float4 t1 = *(const float4*)(te + d0 + 4);
    float v[8] = {e0.x + t0.x, e0.y + t0.y, e0.z + t0.z, e0.w + t0.w,
                  e1.x + t1.x, e1.y + t1.y, e1.z + t1.z, e1.w + t1.w};
    float fp = (float)pos;
    #pragma unroll
    for (int p = 0; p < 4; ++p) {
        int d = d0 + 2 * p;
        float div = __expf((float)d * (-9.210340371976184f / (float)DMODEL));
        float sn, cs;
        __sincosf(fp * div, &sn, &cs);
        v[2 * p]     += alpha * sn;
        v[2 * p + 1] += alpha * cs;
    }

    float* hp = hbuf + (size_t)row * DMODEL + d0;
    *(float4*)hp       = make_float4(v[0], v[1], v[2], v[3]);
    *(float4*)(hp + 4) = make_float4(v[4], v[5], v[6], v[7]);
    short8 sv;
    #pragma unroll
    for (int e = 0; e < 8; ++e) sv[e] = (short)f2bf(v[e]);
    *(short8*)(hbuf_bf + (size_t)row * DMODEL + d0) = sv;
}

// ---------------- bf16 MFMA NT GEMM (full-K) ----------
__global__ __launch_bounds__(256) void gemm_bf16_kernel(
    const u16* __restrict__ A, const u16* __restrict__ Bw,
    const float* __restrict__ bias,
    float* __restrict__ Cf, u16* __restrict__ Cb,
    int M, int N, int K, int relu)
{
    __shared__ u16 As[128 * 32];
    __shared__ u16 Bs[128 * 32];
    int tid = threadIdx.x;
    int w = tid >> 6, l = tid & 63;
    int m0 = blockIdx.y * 128, n0 = blockIdx.x * 128;
    int wm = (w >> 1) * 64, wn = (w & 1) * 64;

    f32x4 acc[4][4];
    #pragma unroll
    for (int i = 0; i < 4; ++i)
        #pragma unroll
        for (int j = 0; j < 4; ++j) acc[i][j] = (f32x4){0.f, 0.f, 0.f, 0.f};

    int srow0 = (w << 5) + (l >> 2);
    int skp = (l & 3) << 3;

    for (int k0 = 0; k0 < K; k0 += 32) {
        #pragma unroll
        for (int c = 0; c < 2; ++c) {
            int row = srow0 + c * 16;
            int am = m0 + row; if (am >= M) am = M - 1;
            int bn = n0 + row; if (bn >= N) bn = N - 1;
            __builtin_amdgcn_global_load_lds(
                (const __attribute__((address_space(1))) void*)(A + (size_t)am * K + k0 + skp),
                (__attribute__((address_space(3))) void*)(As + ((w * 2 + c) << 9)), 16, 0, 0);
            __builtin_amdgcn_global_load_lds(
                (const __attribute__((address_space(1))) void*)(Bw + (size_t)bn * K + k0 + skp),
                (__attribute__((address_space(3))) void*)(Bs + ((w * 2 + c) << 9)), 16, 0, 0);
        }
        __syncthreads();
        short8 af[4], bfr[4];
        #pragma unroll
        for (int i = 0; i < 4; ++i) {
            af[i]  = *(const short8*)(As + (wm + i * 16 + (l & 15)) * 32 + ((l >> 4) << 3));
            bfr[i] = *(const short8*)(Bs + (wn + i * 16 + (l & 15)) * 32 + ((l >> 4) << 3));
        }
        #pragma unroll
        for (int i = 0; i < 4; ++i)
            #pragma unroll
            for (int j = 0; j < 4; ++j)
                acc[i][j] = __builtin_amdgcn_mfma_f32_16x16x32_bf16(af[i], bfr[j], acc[i][j], 0, 0, 0);
        __syncthreads();
    }

    #pragma unroll
    for (int i = 0; i < 4; ++i) {
        #pragma unroll
        for (int j = 0; j < 4; ++j) {
            #pragma unroll
            for (int jj = 0; jj < 4; ++jj) {
                int row = m0 + wm + i * 16 + ((l >> 4) << 2) + jj;
                int col = n0 + wn + j * 16 + (l & 15);
                if (row < M && col < N) {
                    float v = acc[i][j][jj];
                    if (bias) v += bias[col];
                    if (relu) v = fmaxf(v, 0.f);
                    if (Cf) Cf[(size_t)row * N + col] = v;
                    if (Cb) Cb[(size_t)row * N + col] = f2bf(v);
                }
            }
        }
    }
}

// ---- split-K variant ----
__global__ __launch_bounds__(256) void gemm_bf16_splitk_kernel(
    const u16* __restrict__ A, const u16* __restrict__ Bw,
    float* __restrict__ P0, float* __restrict__ P1, float* __restrict__ P2,
    int M, int N, int K, int klen)
{
    __shared__ u16 As[128 * 32];
    __shared__ u16 Bs[128 * 32];
    int tid = threadIdx.x;
    int w = tid >> 6, l = tid & 63;
    int z = blockIdx.z;
    float* Cp = (z == 0) ? P0 : (z == 1) ? P1 : P2;
    int kbeg = z * klen;
    int kend = min(kbeg + klen, K);
    int m0 = blockIdx.y * 128, n0 = blockIdx.x * 128;
    int wm = (w >> 1) * 64, wn = (w & 1) * 64;

    f32x4 acc[4][4];
    #pragma unroll
    for (int i = 0; i < 4; ++i)
        #pragma unroll
        for (int j = 0; j < 4; ++j) acc[i][j] = (f32x4){0.f, 0.f, 0.f, 0.f};

    int srow0 = (w << 5) + (l >> 2);
    int skp = (l & 3) << 3;

    for (int k0 = kbeg; k0 < kend; k0 += 32) {
        #pragma unroll
        for (int c = 0; c < 2; ++c) {
            int row = srow0 + c * 16;
            int am = m0 + row; if (am >= M) am = M - 1;
            int bn = n0 + row; if (bn >= N) bn = N - 1;
            __builtin_amdgcn_global_load_lds(
                (const __attribute__((address_space(1))) void*)(A + (size_t)am * K + k0 + skp),
                (__attribute__((address_space(3))) void*)(As + ((w * 2 + c) << 9)), 16, 0, 0);
            __builtin_amdgcn_global_load_lds(
                (const __attribute__((address_space(1))) void*)(Bw + (size_t)bn * K + k0 + skp),
                (__attribute__((address_space(3))) void*)(Bs + ((w * 2 + c) << 9)), 16, 0, 0);
        }
        __syncthreads();
        short8 af[4], bfr[4];
        #pragma unroll
        for (int i = 0; i < 4; ++i) {
            af[i]  = *(const short8*)(As + (wm + i * 16 + (l & 15)) * 32 + ((l >> 4) << 3));
            bfr[i] = *(const short8*)(Bs + (wn + i * 16 + (l & 15)) * 32 + ((l >> 4) << 3));
        }
        #pragma unroll
        for (int i = 0; i < 4; ++i)
            #pragma unroll
            for (int j = 0; j < 4; ++j)
                acc[i][j] = __builtin_amdgcn_mfma_f32_16x16x32_bf16(af[i], bfr[j], acc[i][j], 0, 0, 0);
        __syncthreads();
    }

    #pragma unroll
    for (int i = 0; i < 4; ++i) {
        #pragma unroll
        for (int j = 0; j < 4; ++j) {
            #pragma unroll
            for (int jj = 0; jj < 4; ++jj) {
                int row = m0 + wm + i * 16 + ((l >> 4) << 2) + jj;
                int col = n0 + wn + j * 16 + (l & 15);
                if (row < M && col < N)
                    Cp[(size_t)row * N + col] = acc[i][j][jj];
            }
        }
    }
}

// ---- split-K + dynamic-M (logits) ----
__global__ __launch_bounds__(256) void gemm_bf16_splitk_dynm_kernel(
    const u16* __restrict__ A, const u16* __restrict__ Bw,
    const int* __restrict__ Mp,
    float* __restrict__ P0, float* __restrict__ P1,
    int N, int K, int klen)
{
    int M = *Mp;
    int m0 = blockIdx.y * 128;
    if (m0 >= M) return;
    __shared__ u16 As[128 * 32];
    __shared__ u16 Bs[128 * 32];
    int tid = threadIdx.x;
    int w = tid >> 6, l = tid & 63;
    int z = blockIdx.z;
    float* Cp = (z == 0) ? P0 : P1;
    int kbeg = z * klen;
    int kend = min(kbeg + klen, K);
    int n0 = blockIdx.x * 128;
    int wm = (w >> 1) * 64, wn = (w & 1) * 64;

    f32x4 acc[4][4];
    #pragma unroll
    for (int i = 0; i < 4; ++i)
        #pragma unroll
        for (int j = 0; j < 4; ++j) acc[i][j] = (f32x4){0.f, 0.f, 0.f, 0.f};

    int srow0 = (w << 5) + (l >> 2);
    int skp = (l & 3) << 3;

    for (int k0 = kbeg; k0 < kend; k0 += 32) {
        #pragma unroll
        for (int c = 0; c < 2; ++c) {
            int row = srow0 + c * 16;
            int am = m0 + row; if (am >= M) am = M - 1;
            int bn = n0 + row; if (bn >= N) bn = N - 1;
            __builtin_amdgcn_global_load_lds(
                (const __attribute__((address_space(1))) void*)(A + (size_t)am * K + k0 + skp),
                (__attribute__((address_space(3))) void*)(As + ((w * 2 + c) << 9)), 16, 0, 0);
            __builtin_amdgcn_global_load_lds(
                (const __attribute__((address_space(1))) void*)(Bw + (size_t)bn * K + k0 + skp),
                (__attribute__((address_space(3))) void*)(Bs + ((w * 2 + c) << 9)), 16, 0, 0);
        }
        __syncthreads();
        short8 af[4], bfr[4];
        #pragma unroll
        for (int i = 0; i < 4; ++i) {
            af[i]  = *(const short8*)(As + (wm + i * 16 + (l & 15)) * 32 + ((l >> 4) << 3));
            bfr[i] = *(const short8*)(Bs + (wn + i * 16 + (l & 15)) * 32 + ((l >> 4) << 3));
        }
        #pragma unroll
        for (int i = 0; i < 4; ++i)
            #pragma unroll
            for (int j = 0; j < 4; ++j)
                acc[i][j] = __builtin_amdgcn_mfma_f32_16x16x32_bf16(af[i], bfr[j], acc[i][j], 0, 0, 0);
        __syncthreads();
    }

    #pragma unroll
    for (int i = 0; i < 4; ++i) {
        #pragma unroll
        for (int j = 0; j < 4; ++j) {
            #pragma unroll
            for (int jj = 0; jj < 4; ++jj) {
                int row = m0 + wm + i * 16 + ((l >> 4) << 2) + jj;
                int col = n0 + wn + j * 16 + (l & 15);
                if (row < M && col < N)
                    Cp[(size_t)row * N + col] = acc[i][j][jj];
            }
        }
    }
}

// ============== MFMA flash attention: swapped QK^T, in-register softmax ==============
// grid (10, 32), 512 thr = 8 waves; wave w owns q rows [q0+16w, q0+16w+16).
// Swapped S^T = mfma(K,Q): lane holds q = l&15, k-values at 16*cb + 4*(l>>4) + reg.
__global__ __launch_bounds__(512) void attn_mfma_kernel(
    const u16* __restrict__ qkv,
    const int* __restrict__ x1_lens, const int* __restrict__ x2_lens,
    const int* __restrict__ y1_lens, const int* __restrict__ y2_lens,
    const int* __restrict__ y_mask,
    u16* __restrict__ obuf)
{
    __shared__ u16 Ks[64 * 64];                 // [k][d] XOR-swizzled
    __shared__ u16 Vt[64 * 64];                 // [d][k] XOR-swizzled
    __shared__ unsigned long long Bits[7][19];  // per-rowtype per-tile allow bitmap

    int tid = threadIdx.x;
    int w = tid >> 6, l = tid & 63;
    int g = l >> 4;                 // lane group 0..3
    int bh = blockIdx.y;
    int b = bh >> 3, h = bh & 7;
    int q0 = blockIdx.x * QBLK;

    int x1 = x1_lens[b], xlen = x1 + 1 + x2_lens[b];
    int y1 = y1_lens[b], ylen = y1 + 1 + y2_lens[b];

    // ---- block-level kmax over alive rows; early-exit fully-dead blocks ----
    int kmax = -1;
    if (q0 < XL) kmax = max(kmax, xlen - 1);
    if (XL >= q0 && XL < q0 + QBLK) kmax = max(kmax, XL);
    {
        int ry0 = max(0, q0 - XL - 1);
        int ry1 = min(YL - 1, q0 + QBLK - 2 - XL);
        if (ry0 <= ry1) {
            if (ry0 <= y1 - 1) kmax = max(kmax, XL + y1);
            if (y1 >= ry0 && y1 <= ry1) kmax = max(kmax, XL + y1 + 1);
            int a = max(ry0, y1 + 1), bb = min(ry1, ylen - 1);
            if (a <= bb) kmax = max(kmax, XL + ylen);
        }
    }
    if (kmax < 0) return;
    int NKT = (kmax >> 6) + 1;

    // ---- allow bitmaps via wave ballot: Bits[type][tile] bit i = col tile*64+i allowed ----
    for (int pp = w; pp < 7 * 19; pp += 8) {
        int ty = pp / 19, tile = pp - ty * 19;
        int c = tile * 64 + l;
        bool allow = false;
        if (c < SEQ && ty < 6) {
            bool a2c = (c == XL), ygt = (c > XL);
            if (ty == 0) allow = (c < x1);
            else if (ty == 1) allow = (c >= x1) && (c < xlen);
            else if (ty == 2) allow = a2c;
            else if (ty == 3) allow = (c < x1) || (ygt && c <= XL + y1);
            else if (ty == 4) allow = (c < xlen) || a2c || (ygt && c <= XL + y1 + 1);
            else {
                int ym = ygt ? y_mask[b * YL + c - XL - 1] : 0;
                allow = (((c < xlen) || a2c || (ygt && c <= XL + ylen)) && !ym);
            }
        }
        unsigned long long mk = __ballot(allow);
        if (l == 0) Bits[ty][tile] = mk;
    }

    // ---- Q fragment (q = l&15), scale 1/8 folded in ----
    int qr = q0 + w * 16 + (l & 15);
    int qrc = min(qr, SEQ - 1);
    short8 qf0, qf1;
    {
        const u16* qp = qkv + (size_t)(b * SEQ + qrc) * 1536 + h * 64 + (g << 3);
        short8 r0 = *(const short8*)qp;
        short8 r1 = *(const short8*)(qp + 32);
        #pragma unroll
        for (int e = 0; e < 8; ++e) {
            qf0[e] = (short)f2bf(bf2f((u16)r0[e]) * 0.125f);
            qf1[e] = (short)f2bf(bf2f((u16)r1[e]) * 0.125f);
        }
    }

    // ---- row type of this lane's q: 0..5, 6 = dead ----
    int rt;
    {
        if (qr >= SEQ) rt = 6;
        else if (qr < XL) rt = (qr < x1) ? 0 : 1;
        else if (qr == XL) rt = 2;
        else {
            int ry = qr - XL - 1;
            rt = (ry < y1) ? 3 : (ry == y1) ? 4 : (ry < ylen) ? 5 : 6;
        }
    }

    f32x4 oacc[4];
    #pragma unroll
    for (int db = 0; db < 4; ++db) oacc[db] = (f32x4){0.f, 0.f, 0.f, 0.f};
    float mrun = -INFINITY, lrun = 0.f;

    int srcA = (l & 15) + ((g & 1) << 5);   // exchange sources for P-frag assembly
    int srcB = srcA + 16;
    bool hi = (g >> 1) & 1;

    for (int kt = 0; kt < NKT; ++kt) {
        __syncthreads();
        {   // stage K rows: 512 thr, one b128 each
            int r = tid >> 3, d0k = (tid & 7) << 3;
            int krc = min(kt * 64 + r, SEQ - 1);
            short8 ka = *(const short8*)(qkv + (size_t)(b * SEQ + krc) * 1536 + 512 + h * 64 + d0k);
            *(short8*)&Ks[r * 64 + (d0k ^ ((r & 7) << 3))] = ka;
        }
        {   // stage V^T: 2 k-rows x 4 d per thread, paired u32 writes
            int rp = tid >> 4, o = tid & 15;
            int d0v = o * 4;
            int k0r = min(kt * 64 + 2 * rp, SEQ - 1);
            int k1r = min(kt * 64 + 2 * rp + 1, SEQ - 1);
            ushort4 va = *(const ushort4*)(qkv + (size_t)(b * SEQ + k0r) * 1536 + 1024 + h * 64 + d0v);
            ushort4 vb = *(const ushort4*)(qkv + (size_t)(b * SEQ + k1r) * 1536 + 1024 + h * 64 + d0v);
            u32 pv[4] = {(u32)va.x | ((u32)vb.x << 16), (u32)va.y | ((u32)vb.y << 16),
                         (u32)va.z | ((u32)vb.z << 16), (u32)va.w | ((u32)vb.w << 16)};
            #pragma unroll
            for (int e = 0; e < 4; ++e) {
                int d = d0v + e;
                *(u32*)&Vt[d * 64 + ((2 * rp) ^ ((d & 7) << 3))] = pv[e];
            }
        }
        __syncthreads();

        // ---- QK^T swapped: sc[cb][reg] = S^T[k = 16cb+4g+reg][q = l&15] ----
        f32x4 sc[4];
        #pragma unroll
        for (int cb = 0; cb < 4; ++cb) {
            int krw = cb * 16 + (l & 15);
            int ksw = (krw & 7) << 3;
            short8 k0 = *(const short8*)&Ks[krw * 64 + ((g << 3) ^ ksw)];
            short8 k1 = *(const short8*)&Ks[krw * 64 + ((32 + (g << 3)) ^ ksw)];
            f32x4 z = (f32x4){0.f, 0.f, 0.f, 0.f};
            z = __builtin_amdgcn_mfma_f32_16x16x32_bf16(k0, qf0, z, 0, 0, 0);
            sc[cb] = __builtin_amdgcn_mfma_f32_16x16x32_bf16(k1, qf1, z, 0, 0, 0);
        }

        // ---- mask via bitmap ----
        unsigned long long mb = Bits[rt][kt];
        #pragma unroll
        for (int cb = 0; cb < 4; ++cb) {
            unsigned nib = (unsigned)(mb >> (16 * cb + 4 * g)) & 0xFu;
            #pragma unroll
            for (int r = 0; r < 4; ++r)
                sc[cb][r] = ((nib >> r) & 1u) ? sc[cb][r] : NEGBIG;
        }

        // ---- in-register online softmax (one q-row per lane) ----
        float tmax = sc[0][0];
        #pragma unroll
        for (int cb = 0; cb < 4; ++cb)
            #pragma unroll
            for (int r = 0; r < 4; ++r) tmax = fmaxf(tmax, sc[cb][r]);
        tmax = fmaxf(tmax, __shfl_xor(tmax, 16));
        tmax = fmaxf(tmax, __shfl_xor(tmax, 32));
        float newm = fmaxf(mrun, tmax);
        float corr = __expf(mrun - newm);
        float p[4][4];
        float ps = 0.f;
        #pragma unroll
        for (int cb = 0; cb < 4; ++cb)
            #pragma unroll
            for (int r = 0; r < 4; ++r) {
                p[cb][r] = __expf(sc[cb][r] - newm);
                ps += p[cb][r];
            }
        ps += __shfl_xor(ps, 16);
        ps += __shfl_xor(ps, 32);
        lrun = lrun * corr + ps;
        mrun = newm;

        // ---- rescale O (lane holds O rows 4g+r) ----
        float cr[4];
        #pragma unroll
        for (int r = 0; r < 4; ++r) cr[r] = __shfl(corr, (g << 2) + r);
        #pragma unroll
        for (int db = 0; db < 4; ++db)
            #pragma unroll
            for (int r = 0; r < 4; ++r) oacc[db][r] *= cr[r];

        // ---- pack P to bf16 pairs ----
        u32 P0[4], P1[4];
        #pragma unroll
        for (int cb = 0; cb < 4; ++cb) {
            P0[cb] = (u32)f2bf(p[cb][0]) | ((u32)f2bf(p[cb][1]) << 16);
            P1[cb] = (u32)f2bf(p[cb][2]) | ((u32)f2bf(p[cb][3]) << 16);
        }

        // ---- exchange -> A-fragments for PV (k 0..31 and 32..63) ----
        union { u32 u[4]; short8 s; } f1, f2;
        {
            u32 a0 = __shfl(P0[0], srcA), a1 = __shfl(P1[0], srcA);
            u32 a2 = __shfl(P0[0], srcB), a3 = __shfl(P1[0], srcB);
            u32 b0 = __shfl(P0[1], srcA), b1 = __shfl(P1[1], srcA);
            u32 b2 = __shfl(P0[1], srcB), b3 = __shfl(P1[1], srcB);
            f1.u[0] = hi ? b0 : a0; f1.u[1] = hi ? b1 : a1;
            f1.u[2] = hi ? b2 : a2; f1.u[3] = hi ? b3 : a3;
            u32 c0 = __shfl(P0[2], srcA), c1 = __shfl(P1[2], srcA);
            u32 c2 = __shfl(P0[2], srcB), c3 = __shfl(P1[2], srcB);
            u32 d0 = __shfl(P0[3], srcA), d1 = __shfl(P1[3], srcA);
            u32 d2 = __shfl(P0[3], srcB), d3 = __shfl(P1[3], srcB);
            f2.u[0] = hi ? d0 : c0; f2.u[1] = hi ? d1 : c1;
            f2.u[2] = hi ? d2 : c2; f2.u[3] = hi ? d3 : c3;
        }

        // ---- PV: O[q=4g+r][d] += P V ----
        #pragma unroll
        for (int db = 0; db < 4; ++db) {
            int vr = db * 16 + (l & 15);
            int vsw = (vr & 7) << 3;
            short8 v0 = *(const short8*)&Vt[vr * 64 + ((g << 3) ^ vsw)];
            short8 v1 = *(const short8*)&Vt[vr * 64 + ((32 + (g << 3)) ^ vsw)];
            oacc[db] = __builtin_amdgcn_mfma_f32_16x16x32_bf16(f1.s, v0, oacc[db], 0, 0, 0);
            oacc[db] = __builtin_amdgcn_mfma_f32_16x16x32_bf16(f2.s, v1, oacc[db], 0, 0, 0);
        }
    }

    // ---- normalize + write ----
    float rinv = 1.f / lrun;
    float rl[4];
    #pragma unroll
    for (int r = 0; r < 4; ++r) rl[r] = __shfl(rinv, (g << 2) + r);
    #pragma unroll
    for (int db = 0; db < 4; ++db) {
        #pragma unroll
        for (int r = 0; r < 4; ++r) {
            int qrj = q0 + w * 16 + (g << 2) + r;
            if (qrj < SEQ)
                obuf[(size_t)(b * SEQ + qrj) * DMODEL + h * 64 + db * 16 + (l & 15)] =
                    f2bf(oacc[db][r] * rl[r]);
        }
    }
}

// ------- residual add + fused split-K reduce (+bias) + LayerNorm, wave-per-row -------
__global__ __launch_bounds__(256) void add_ln_kernel(
    float* __restrict__ hbuf, u16* __restrict__ hbuf_bf,
    const float* __restrict__ p0, const float* __restrict__ p1,
    const float* __restrict__ p2, const float* __restrict__ bias,
    const float* __restrict__ g, const float* __restrict__ beta)
{
    int row = blockIdx.x * 4 + (threadIdx.x >> 6);
    int l = threadIdx.x & 63;
    int d0 = l * 8;
    size_t off = (size_t)row * DMODEL + d0;
    float* hp = hbuf + off;
    float4 a0 = *(const float4*)hp, a1 = *(const float4*)(hp + 4);
    float4 q0 = *(const float4*)(p0 + off), q1 = *(const float4*)(p0 + off + 4);
    float v[8] = {a0.x + q0.x, a0.y + q0.y, a0.z + q0.z, a0.w + q0.w,
                  a1.x + q1.x, a1.y + q1.y, a1.z + q1.z, a1.w + q1.w};
    if (p1) {
        float4 r0 = *(const float4*)(p1 + off), r1 = *(const float4*)(p1 + off + 4);
        v[0] += r0.x; v[1] += r0.y; v[2] += r0.z; v[3] += r0.w;
        v[4] += r1.x; v[5] += r1.y; v[6] += r1.z; v[7] += r1.w;
    }
    if (p2) {
        float4 r0 = *(const float4*)(p2 + off), r1 = *(const float4*)(p2 + off + 4);
        v[0] += r0.x; v[1] += r0.y; v[2] += r0.z; v[3] += r0.w;
        v[4] += r1.x; v[5] += r1.y; v[6] += r1.z; v[7] += r1.w;
    }
    {
        float4 b0 = *(const float4*)(bias + d0), b1 = *(const float4*)(bias + d0 + 4);
        v[0] += b0.x; v[1] += b0.y; v[2] += b0.z; v[3] += b0.w;
        v[4] += b1.x; v[5] += b1.y; v[6] += b1.z; v[7] += b1.w;
    }
    float s = 0.f;
    #pragma unroll
    for (int e = 0; e < 8; ++e) s += v[e];
    #pragma unroll
    for (int off2 = 32; off2 > 0; off2 >>= 1) s += __shfl_xor(s, off2);
    float mu = s * (1.f / DMODEL);
    float sq = 0.f;
    #pragma unroll
    for (int e = 0; e < 8; ++e) { v[e] -= mu; sq += v[e] * v[e]; }
    #pragma unroll
    for (int off2 = 32; off2 > 0; off2 >>= 1) sq += __shfl_xor(sq, off2);
    float inv = 1.f / sqrtf(sq * (1.f / DMODEL) + 1e-5f);
    float4 g0 = *(const float4*)(g + d0), g1 = *(const float4*)(g + d0 + 4);
    float4 be0 = *(const float4*)(beta + d0), be1 = *(const float4*)(beta + d0 + 4);
    float o[8];
    o[0] = v[0] * inv * g0.x + be0.x; o[1] = v[1] * inv * g0.y + be0.y;
    o[2] = v[2] * inv * g0.z + be0.z; o[3] = v[3] * inv * g0.w + be0.w;
    o[4] = v[4] * inv * g1.x + be1.x; o[5] = v[5] * inv * g1.y + be1.y;
    o[6] = v[6] * inv * g1.z + be1.z; o[7] = v[7] * inv * g1.w + be1.w;
    *(float4*)hp       = make_float4(o[0], o[1], o[2], o[3]);
    *(float4*)(hp + 4) = make_float4(o[4], o[5], o[6], o[7]);
    short8 sv;
    #pragma unroll
    for (int e = 0; e < 8; ++e) sv[e] = (short)f2bf(o[e]);
    *(short8*)(hbuf_bf + off) = sv;
}

// ---------------- compaction of masked rows ----------------
__global__ __launch_bounds__(256) void init_accum_kernel(float* accum) {
    if (threadIdx.x < 8) accum[threadIdx.x] = 0.f;
}

__global__ __launch_bounds__(256) void compact_kernel(
    const int* __restrict__ y_mask, int* __restrict__ cnt, int* __restrict__ cmap)
{
    int i = blockIdx.x * 256 + threadIdx.x;
    if (i < BATCH * YL && y_mask[i]) {
        int pos = atomicAdd(cnt, 1);
        cmap[pos] = i;
    }
}

__global__ __launch_bounds__(256) void copy_rows_kernel(
    const int* __restrict__ cnt, const int* __restrict__ cmap,
    const u16* __restrict__ hbuf_bf, const int* __restrict__ y,
    u16* __restrict__ cbuf, int* __restrict__ ctgt)
{
    int i = blockIdx.x;
    if (i >= *cnt) return;
    int g = cmap[i];
    int b = g >> 10, r = g & 1023;
    const u16* src = hbuf_bf + (size_t)(b * SEQ + XL + 1 + r) * DMODEL;
    u16* dst = cbuf + (size_t)i * DMODEL;
    int t = threadIdx.x;
    ((ushort2*)dst)[t] = ((const ushort2*)src)[t];
    if (t == 0) ctgt[i] = y[g];
}

// ---------------- CE + top-3 over compacted rows (sums 2 logits partials) ----------------
__global__ __launch_bounds__(256) void ce_kernel(
    const int* __restrict__ cnt,
    const float* __restrict__ lg0, const float* __restrict__ lg1,
    const int* __restrict__ ctgt, float* __restrict__ accum)
{
    int row = blockIdx.x;
    if (row >= *cnt) return;
    const float* lp0 = lg0 + (size_t)row * OV;
    const float* lp1 = lg1 + (size_t)row * OV;
    int tgt = ctgt[row];
    int t = threadIdx.x;
    __shared__ float red[4];

    float lmax = -INFINITY;
    for (int i = t; i < OV; i += 256) lmax = fmaxf(lmax, lp0[i] + lp1[i]);
    #pragma unroll
    for (int off = 32; off > 0; off >>= 1) lmax = fmaxf(lmax, __shfl_xor(lmax, off));
    if ((t & 63) == 0) red[t >> 6] = lmax;
    __syncthreads();
    lmax = fmaxf(fmaxf(red[0], red[1]), fmaxf(red[2], red[3]));
    __syncthreads();

    float lsum = 0.f;
    for (int i = t; i < OV; i += 256) lsum += expf(lp0[i] + lp1[i] - lmax);
    #pragma unroll
    for (int off = 32; off > 0; off >>= 1) lsum += __shfl_xor(lsum, off);
    if ((t & 63) == 0) red[t >> 6] = lsum;
    __syncthreads();
    lsum = red[0] + red[1] + red[2] + red[3];
    __syncthreads();

    float lt = lp0[tgt] + lp1[tgt];
    float cntr = 0.f;
    for (int i = t; i < OV; i += 256) {
        float v = lp0[i] + lp1[i];
        if (v > lt || (v == lt && i < tgt)) cntr += 1.f;
    }
    #pragma unroll
    for (int off = 32; off > 0; off >>= 1) cntr += __shfl_xor(cntr, off);
    if ((t & 63) == 0) red[t >> 6] = cntr;
    __syncthreads();
    cntr = red[0] + red[1] + red[2] + red[3];

    if (t == 0) {
        float ce = -(lt - lmax - logf(lsum));
        float inc = (tgt != EOS_TOK) ? 1.f : 0.f;
        float corr = (cntr < 2.5f) ? 1.f : 0.f;
        atomicAdd(&accum[0], ce);
        atomicAdd(&accum[1], 1.f);
        atomicAdd(&accum[2], corr * inc);
        atomicAdd(&accum[3], inc);
    }
}

// ---------------- duration head ----------------
__global__ __launch_bounds__(256) void dur1_kernel(
    const float* __restrict__ hbuf, const int* __restrict__ y1_lens,
    const float* __restrict__ dW1, const float* __restrict__ db1,
    float* __restrict__ h1buf)
{
    __shared__ float cls[DMODEL];
    int g = blockIdx.x;
    int b = g >> 3, c = g & 7;
    int t = threadIdx.x;
    const float* cp = hbuf + (size_t)(b * SEQ + XL + 1 + y1_lens[b]) * DMODEL;
    cls[t] = cp[t]; cls[t + 256] = cp[t + 256];
    __syncthreads();
    int row = c * 32 + (t >> 3);
    int ln = t & 7;
    const float* w = dW1 + (size_t)row * DMODEL + ln * 64;
    const float* cv = cls + ln * 64;
    float acc = 0.f;
    #pragma unroll 8
    for (int k = 0; k < 64; ++k) acc = fmaf(cv[k], w[k], acc);
    acc += __shfl_xor(acc, 1); acc += __shfl_xor(acc, 2); acc += __shfl_xor(acc, 4);
    if (ln == 0) h1buf[b * 256 + row] = fmaxf(acc + db1[row], 0.f);
}

__global__ __launch_bounds__(256) void dur2_kernel(
    const float* __restrict__ h1buf,
    const float* __restrict__ dW2, const float* __restrict__ db2,
    const float* __restrict__ dW3, const float* __restrict__ db3,
    float* __restrict__ preds)
{
    __shared__ float h1s[256];
    __shared__ float h2s[128];
    int b = blockIdx.x;
    int t = threadIdx.x;
    h1s[t] = h1buf[b * 256 + t];
    __syncthreads();
    if (t < 128) {
        float acc = db2[t];
        const float* w = dW2 + (size_t)t * 256;
        for (int k = 0; k < 256; ++k) acc = fmaf(h1s[k], w[k], acc);
        h2s[t] = fmaxf(acc, 0.f);
    }
    __syncthreads();
    if (t < 64) {
        float v = h2s[t] * dW3[t] + h2s[t + 64] * dW3[t + 64];
        #pragma unroll
        for (int off = 32; off > 0; off >>= 1) v += __shfl_xor(v, off);
        if (t == 0) preds[b] = v + db3[0];
    }
}

__global__ __launch_bounds__(64) void final_kernel(
    const float* __restrict__ accum, const float* __restrict__ preds,
    const int* __restrict__ y2_lens, const int* __restrict__ x2_lens,
    float* __restrict__ out)
{
    if (threadIdx.x == 0) {
        float dl = 0.f;
        for (int b = 0; b < BATCH; ++b) {
            float tgt = (float)y2_lens[b] / (float)x2_lens[b];
            float e = preds[b] - tgt;
            float ae = fabsf(e);
            dl += (ae <= 1.f) ? 0.5f * e * e : (ae - 0.5f);
        }
        dl *= (1.f / BATCH);
        float token_loss = accum[0] / accum[1];
        float acc_v = accum[2] / fmaxf(accum[3], 1.f);
        out[0] = token_loss + dl;
        out[1] = acc_v;
    }
}

// ---------------- orchestration ----------------
extern "C" void kernel_launch(void* const* d_in, const int* in_sizes, int n_in,
                              void* d_out, int out_size, void* d_ws, size_t ws_size,
                              hipStream_t stream)
{
    const int*   x           = (const int*)d_in[0];
    const int*   x1_lens     = (const int*)d_in[1];
    const int*   x2_lens     = (const int*)d_in[2];
    const int*   y           = (const int*)d_in[3];
    const int*   y1_lens     = (const int*)d_in[4];
    const int*   y2_lens     = (const int*)d_in[5];
    const int*   y_mask      = (const int*)d_in[6];
    const float* emo_feature = (const float*)d_in[7];
    const float* text_emb    = (const float*)d_in[8];
    const float* audio_emb   = (const float*)d_in[9];
    const float* type_emb    = (const float*)d_in[10];
    const float* emo_W       = (const float*)d_in[11];
    const float* emo_b       = (const float*)d_in[12];
    const float* alpha_text  = (const float*)d_in[13];
    const float* alpha_audio = (const float*)d_in[14];
    const float* Wqkv        = (const float*)d_in[15];
    const float* bqkv        = (const float*)d_in[16];
    const float* Wo          = (const float*)d_in[17];
    const float* bo          = (const float*)d_in[18];
    const float* ln1_g       = (const float*)d_in[19];
    const float* ln1_b       = (const float*)d_in[20];
    const float* ln2_g       = (const float*)d_in[21];
    const float* ln2_b       = (const float*)d_in[22];
    const float* W1          = (const float*)d_in[23];
    const float* b1          = (const float*)d_in[24];
    const float* W2          = (const float*)d_in[25];
    const float* b2          = (const float*)d_in[26];
    const float* predict_W   = (const float*)d_in[27];
    const float* dW1         = (const float*)d_in[28];
    const float* db1         = (const float*)d_in[29];
    const float* dW2         = (const float*)d_in[30];
    const float* db2         = (const float*)d_in[31];
    const float* dW3         = (const float*)d_in[32];
    const float* db3         = (const float*)d_in[33];

    const int M = BATCH * SEQ;                       // 4612
    char* p = (char*)d_ws;
    float* hbuf   = (float*)p; p += 9445376;         // M*512*4
    float* delta  = (float*)p; p += 9445376;
    char*  uni    = p;         p += 18909440;        // max(ff1_bf, logits partial0)
    u16*   hbuf_bf = (u16*)p;  p += 4722688;
    u16*   qkv_bf  = (u16*)p;  p += 14168064;        // also split-K partial region
    u16*   obuf_bf = (u16*)p;  p += 4722688;         // contiguous after qkv_bf
    u16*   wbf     = (u16*)p;  p += 19923968;
    u16*   cbuf    = (u16*)p;  p += (size_t)CCAP * DMODEL * 2;
    u16*   ff1_bf  = (u16*)uni;

    float* partA = (float*)qkv_bf;
    float* partB = (float*)((char*)qkv_bf + 9445376);
    float* lg0   = (float*)uni;
    float* lg1   = (float*)qkv_bf;

    float* accum  = delta;
    int*   cnt    = (int*)(delta + 4);
    float* preds  = delta + 8;
    int*   cmap   = (int*)(delta + 16);
    int*   ctgt   = cmap + CCAP;
    float* h1buf  = (float*)(ctgt + CCAP);

    u16* wq_bf = wbf;                                // 3*1536*512
    u16* wo_bf = wq_bf + 2359296;                    // 3*512*512
    u16* w1_bf = wo_bf + 786432;                     // 3*2048*512
    u16* w2_bf = w1_bf + 3145728;                    // 3*512*2048
    u16* wp_bf = w2_bf + 3145728;                    // 1025*512

    cvt5_kernel<<<1024, 256, 0, stream>>>(
        Wqkv, wq_bf, 2359296 / 4,
        Wo, wo_bf, 786432 / 4,
        W1, w1_bf, 3145728 / 4,
        W2, w2_bf, 3145728 / 4,
        predict_W, wp_bf, 524800 / 4);

    emo_kernel<<<32, 256, 0, stream>>>(emo_feature, emo_W, emo_b, type_emb, hbuf, hbuf_bf);
    build_h_kernel<<<M / 4, 256, 0, stream>>>(
        x, y, y_mask, text_emb, audio_emb, type_emb,
        alpha_text, alpha_audio, hbuf, hbuf_bf);

    const int MG = (M + 127) / 128;   // 37
    for (int l = 0; l < NLAYER; ++l) {
        gemm_bf16_kernel<<<dim3(12, MG), 256, 0, stream>>>(
            hbuf_bf, wq_bf + (size_t)l * 1536 * 512, bqkv + l * 1536,
            nullptr, qkv_bf, M, 1536, 512, 0);
        attn_mfma_kernel<<<dim3((SEQ + QBLK - 1) / QBLK, BATCH * NH), 512, 0, stream>>>(
            qkv_bf, x1_lens, x2_lens, y1_lens, y2_lens, y_mask, obuf_bf);
        gemm_bf16_splitk_kernel<<<dim3(4, MG, 2), 256, 0, stream>>>(
            obuf_bf, wo_bf + (size_t)l * 512 * 512,
            delta, partA, nullptr, M, 512, 512, 256);
        add_ln_kernel<<<M / 4, 256, 0, stream>>>(hbuf, hbuf_bf,
            delta, partA, nullptr, bo + l * 512,
            ln1_g + l * DMODEL, ln1_b + l * DMODEL);
        gemm_bf16_kernel<<<dim3(16, MG), 256, 0, stream>>>(
            hbuf_bf, w1_bf + (size_t)l * 2048 * 512, b1 + l * 2048,
            nullptr, ff1_bf, M, 2048, 512, 1);
        gemm_bf16_splitk_kernel<<<dim3(4, MG, 3), 256, 0, stream>>>(
            ff1_bf, w2_bf + (size_t)l * 512 * 2048,
            delta, partA, partB, M, 512, 2048, 768);
        add_ln_kernel<<<M / 4, 256, 0, stream>>>(hbuf, hbuf_bf,
            delta, partA, partB, b2 + l * 512,
            ln2_g + l * DMODEL, ln2_b + l * DMODEL);
    }

    init_accum_kernel<<<1, 64, 0, stream>>>(accum);
    compact_kernel<<<(BATCH * YL) / 256, 256, 0, stream>>>(y_mask, cnt, cmap);
    copy_rows_kernel<<<CCAP, 256, 0, stream>>>(cnt, cmap, hbuf_bf, y, cbuf, ctgt);
    gemm_bf16_splitk_dynm_kernel<<<dim3((OV + 127) / 128, CCAP / 128, 2), 256, 0, stream>>>(
        cbuf, wp_bf, cnt, lg0, lg1, OV, 512, 256);
    ce_kernel<<<CCAP, 256, 0, stream>>>(cnt, lg0, lg1, ctgt, accum);

    dur1_kernel<<<32, 256, 0, stream>>>(hbuf, y1_lens, dW1, db1, h1buf);
    dur2_kernel<<<4, 256, 0, stream>>>(h1buf, dW2, db2, dW3, db3, preds);
    final_kernel<<<1, 64, 0, stream>>>(accum, preds, y2_lens, x2_lens, (float*)d_out);
}